// Round 6
// baseline (1390.878 us; speedup 1.0000x reference)
//
#include <hip/hip_runtime.h>
#include <hip/hip_bf16.h>

namespace {
constexpr int B = 8;
constexpr int N = 4096;
constexpr int KNN = 20;
constexpr int NSEG = 4;
constexpr int SEGLEN = N / NSEG;   // 1024
constexpr int HSEG = SEGLEN / 2;   // 512: half-segment per thread
constexpr int CAP = 24;
constexpr int SLOTS = NSEG * CAP;  // 96

// workspace layout (bytes)
constexpr size_t OFF_IDX  = 0;                          // int [B][N][KNN]
constexpr size_t SZ_IDX   = (size_t)B * N * KNN * 4;
constexpr size_t OFF_T    = OFF_IDX + SZ_IDX;           // knn scratch region
constexpr size_t SZ_T     = (size_t)B * N * 128 * 4;
constexpr size_t OFF_CAT  = OFF_T + SZ_T;               // float [B][N][320]
constexpr size_t SZ_CAT   = (size_t)B * N * 320 * 4;
constexpr size_t OFF_PV   = OFF_CAT + SZ_CAT;           // float [B][1024][32]
constexpr size_t SZ_PV    = (size_t)B * 1024 * 32 * 4;
constexpr size_t OFF_PI   = OFF_PV + SZ_PV;             // int   [B][1024][32]
constexpr size_t OFF_GLOB = OFF_PI + SZ_PV;             // float [B][1024]
constexpr size_t OFF_H    = OFF_GLOB + (size_t)B * 1024 * 4;  // float [B][512]
// knn scratch overlaid on T + head of CAT (dead once merge completes):
constexpr size_t OFF_LD   = OFF_T;                      // float [B*N][SLOTS]
constexpr size_t SZ_LD    = (size_t)B * N * SLOTS * 4;
constexpr size_t OFF_LJ   = OFF_LD + SZ_LD;             // int   [B*N][SLOTS]
constexpr size_t OFF_CNT  = OFF_LJ + SZ_LD;             // int   [B*N][NSEG]
}  // namespace

typedef float v2f __attribute__((ext_vector_type(2)));

// Non-contractable fp32 ops: bit-exact match to np's mul-then-add serial loops.
__device__ __forceinline__ float mulrn(float a, float b) {
#pragma clang fp contract(off)
  return a * b;
}
__device__ __forceinline__ float addrn(float a, float b) {
#pragma clang fp contract(off)
  return a + b;
}
__device__ __forceinline__ float subrn(float a, float b) {
#pragma clang fp contract(off)
  return a - b;
}
// Packed (v_pk_mul_f32 / v_pk_add_f32): per-element IEEE rn == scalar ops.
__device__ __forceinline__ v2f mulrn2(v2f a, v2f b) {
#pragma clang fp contract(off)
  return a * b;
}
__device__ __forceinline__ v2f addrn2(v2f a, v2f b) {
#pragma clang fp contract(off)
  return a + b;
}

// Fused packed MAC, VOP3P with op_sel broadcast of the x-half (semantics
// hardware-validated: per-element IEEE rn mul + rn add, same as scalar).
// acc tied "+v" (no result copy), scratch early-clobber, inputs are aligned
// v2f pairs loaded directly from LDS (no repack movs).
__device__ __forceinline__ void pkmac_lo(v2f& acc, v2f w, v2f x) {
  v2f t;
  asm("v_pk_mul_f32 %1, %2, %3 op_sel:[0,0] op_sel_hi:[1,0]\n\t"
      "v_pk_add_f32 %0, %0, %1"
      : "+v"(acc), "=&v"(t) : "v"(w), "v"(x));
}
__device__ __forceinline__ void pkmac_hi(v2f& acc, v2f w, v2f x) {
  v2f t;
  asm("v_pk_mul_f32 %1, %2, %3 op_sel:[0,1] op_sel_hi:[1,1]\n\t"
      "v_pk_add_f32 %0, %0, %1"
      : "+v"(acc), "=&v"(t) : "v"(w), "v"(x));
}

// ---------------------------------------------------------------------------
// kNN, half-segment split for occupancy: wave = (seg_local, row-group); within
// the wave lanes l / l^32 scan the two 512-candidate halves of the same
// (2 rows, seg). 2048 waves total (2/SIMD) vs 1024 before. Sorted-20 bubble
// per (row, half); exact segment 20th = Batcher merge of the two sorted
// half-lists: theta = max_i min(a_i, b_{19-i}) with b via shfl_xor(.,32)
// (pure selection -> bit-identical to single-scan da[19]). Recovery appends
// front (half 0) / back (half 1) into the shared CAP-slot region; slot order
// is irrelevant (merge selects by (d,j) lex keys). counts = front | back<<16.
// ---------------------------------------------------------------------------
__global__ __launch_bounds__(256) void knn_scan(
    const float* __restrict__ pts,
    float* __restrict__ listd, int* __restrict__ listj, int* __restrict__ counts) {
  __shared__ float4 sp[2 * SEGLEN];  // 32 KB: (x, y, z, sq) for 2 segments
  const int b = blockIdx.z;
  const int tid = threadIdx.x;
  const float* px = pts + (size_t)b * 3 * N;
  const int cb0 = blockIdx.y * 2 * SEGLEN;  // candidate base (2 segs/block)
  for (int i = tid; i < 2 * SEGLEN; i += 256) {
    const float x = px[cb0 + i];
    const float y = px[N + cb0 + i];
    const float z = px[2 * N + cb0 + i];
    const float sq = addrn(addrn(mulrn(x, x), mulrn(y, y)), mulrn(z, z));
    sp[i] = make_float4(x, y, z, sq);
  }
  __syncthreads();
  const int lane = tid & 63;
  const int rl = lane & 31;            // row lane
  const int h2 = lane >> 5;            // half of the segment
  const int segl = (tid >> 6) & 1;     // segment within the block's pair
  const int rg = tid >> 7;             // row group
  const int seg = blockIdx.y * 2 + segl;
  const int row0 = blockIdx.x * 128 + rg * 64 + rl;
  const int row1 = row0 + 32;
  // queries from global (identical arithmetic to staging -> bit-same sq)
  const float ax = px[row0], ay = px[N + row0], az = px[2 * N + row0];
  const float bx = px[row1], by = px[N + row1], bz = px[2 * N + row1];
  const float4 qa = make_float4(ax, ay, az,
      addrn(addrn(mulrn(ax, ax), mulrn(ay, ay)), mulrn(az, az)));
  const float4 qb = make_float4(bx, by, bz,
      addrn(addrn(mulrn(bx, bx), mulrn(by, by)), mulrn(bz, bz)));
  float da[KNN], db[KNN];
#pragma unroll
  for (int t = 0; t < KNN; ++t) { da[t] = 3.0e38f; db[t] = 3.0e38f; }
  const int j0 = segl * SEGLEN + h2 * HSEG;  // LDS-local candidate base
#pragma unroll 2
  for (int jj = 0; jj < HSEG; ++jj) {
    const float4 c = sp[j0 + jj];
    v2f t0 = mulrn2((v2f){qa.x, qb.x}, (v2f){c.x, c.x});
    t0 = addrn2(t0, mulrn2((v2f){qa.y, qb.y}, (v2f){c.y, c.y}));
    t0 = addrn2(t0, mulrn2((v2f){qa.z, qb.z}, (v2f){c.z, c.z}));
    v2f d2 = addrn2((v2f){qa.w, qb.w}, (v2f){c.w, c.w});
    d2 = d2 - mulrn2((v2f){2.0f, 2.0f}, t0);
    if (d2.x < da[KNN - 1]) {
      float cur = d2.x;
#pragma unroll
      for (int t = 0; t < KNN; ++t) {
        const float lo = fminf(cur, da[t]);
        cur = fmaxf(cur, da[t]);
        da[t] = lo;
      }
    }
    if (d2.y < db[KNN - 1]) {
      float cur = d2.y;
#pragma unroll
      for (int t = 0; t < KNN; ++t) {
        const float lo = fminf(cur, db[t]);
        cur = fmaxf(cur, db[t]);
        db[t] = lo;
      }
    }
  }
  // exact segment 20th via bitonic cross-half merge (partner = lane ^ 32);
  // pure min/max selection over the same multiset -> both lanes get the same
  // bit pattern, equal to the single-scan 20th.
  float tha = -3.0e38f, thb = -3.0e38f;
#pragma unroll
  for (int i = 0; i < KNN; ++i) {
    tha = fmaxf(tha, fminf(da[i], __shfl_xor(da[KNN - 1 - i], 32)));
    thb = fmaxf(thb, fminf(db[i], __shfl_xor(db[KNN - 1 - i], 32)));
  }
  float* lda = listd + (size_t)(b * N + row0) * SLOTS + seg * CAP;
  int* lja = listj + (size_t)(b * N + row0) * SLOTS + seg * CAP;
  float* ldb = listd + (size_t)(b * N + row1) * SLOTS + seg * CAP;
  int* ljb = listj + (size_t)(b * N + row1) * SLOTS + seg * CAP;
  const int jg0 = cb0 + j0;  // global candidate index base
  int ca = 0, cb = 0;
#pragma unroll 2
  for (int jj = 0; jj < HSEG; ++jj) {
    const float4 c = sp[j0 + jj];
    v2f t0 = mulrn2((v2f){qa.x, qb.x}, (v2f){c.x, c.x});
    t0 = addrn2(t0, mulrn2((v2f){qa.y, qb.y}, (v2f){c.y, c.y}));
    t0 = addrn2(t0, mulrn2((v2f){qa.z, qb.z}, (v2f){c.z, c.z}));
    v2f d2 = addrn2((v2f){qa.w, qb.w}, (v2f){c.w, c.w});
    d2 = d2 - mulrn2((v2f){2.0f, 2.0f}, t0);
    if (d2.x <= tha && ca < CAP) {
      const int sl = h2 ? (CAP - 1 - ca) : ca;
      lda[sl] = d2.x; lja[sl] = jg0 + jj; ++ca;
    }
    if (d2.y <= thb && cb < CAP) {
      const int sl = h2 ? (CAP - 1 - cb) : cb;
      ldb[sl] = d2.y; ljb[sl] = jg0 + jj; ++cb;
    }
  }
  const int oa = __shfl_xor(ca, 32);
  const int ob = __shfl_xor(cb, 32);
  if (h2 == 0) {  // pack: front count | back count << 16
    counts[(b * N + row0) * NSEG + seg] = ca | (oa << 16);
    counts[(b * N + row1) * NSEG + seg] = cb | (ob << 16);
  }
}

// Merge: per row, select 20 lexicographically-smallest (dist, j) from <=96
// candidates via monotone uint64 keys. counts packed front|back<<16; valid
// slots are [0, front) u [CAP-back, CAP).
__global__ __launch_bounds__(64) void knn_merge(
    const float* __restrict__ listd, const int* __restrict__ listj,
    const int* __restrict__ counts, int* __restrict__ idxout) {
  __shared__ unsigned long long keys[64][SLOTS + 1];  // 49,664 B
  const int r0 = blockIdx.x * 64;
  const int t = threadIdx.x;
  for (int i = t; i < 64 * SLOTS; i += 64) {
    const int rr = i / SLOTS;
    const int sl = i % SLOTS;
    const int seg = sl / CAP;
    const int e = sl % CAP;
    const int row = r0 + rr;
    unsigned long long key = 0xFFFFFFFE00000000ULL | (unsigned)row;  // fallback: self
    const int cp = counts[row * NSEG + seg];
    if (e < (cp & 0xFFFF) || e >= CAP - (cp >> 16)) {
      const float d = listd[(size_t)row * SLOTS + sl];
      unsigned ub = __float_as_uint(d);
      ub ^= (ub & 0x80000000u) ? 0xFFFFFFFFu : 0x80000000u;
      key = ((unsigned long long)ub << 32) | (unsigned)listj[(size_t)row * SLOTS + sl];
    }
    keys[rr][sl] = key;
  }
  __syncthreads();
  int* outp = idxout + (size_t)(r0 + t) * KNN;
  for (int sel = 0; sel < KNN; ++sel) {
    unsigned long long best = ~0ULL;
    int bs = 0;
#pragma unroll 8
    for (int sl = 0; sl < SLOTS; ++sl) {
      const unsigned long long k2 = keys[t][sl];
      if (k2 < best) { best = k2; bs = sl; }
    }
    keys[t][bs] = ~0ULL;
    outp[sel] = (int)(best & 0xFFFFFFFFu);
  }
}

// ---------------------------------------------------------------------------
// EdgeConv, BIT-EXACT serial semantics per (o, n, k):
//   y = sum_c W1[o,c]*x_i[c]  (prefix P)  then  += W2[o,c]*(x_j[c]-x_i[c]).
// ---------------------------------------------------------------------------

// Layer 1 (cin=3): wave per point, lane = output o.
__global__ __launch_bounds__(256) void ec_layer1(
    const float* __restrict__ pts, const int* __restrict__ idx,
    const float* __restrict__ w, const float* __restrict__ s,
    const float* __restrict__ bi, float* __restrict__ cat) {
  const int b = blockIdx.y;
  const int n = blockIdx.x * 4 + (threadIdx.x >> 6);
  const int o = threadIdx.x & 63;
  const float* p = pts + (size_t)b * 3 * N;
  const float xix = p[n], xiy = p[N + n], xiz = p[2 * N + n];
  const float* wr = w + o * 6;
  const float w0 = wr[0], w1 = wr[1], w2 = wr[2], w3 = wr[3], w4 = wr[4], w5 = wr[5];
  float P = mulrn(w0, xix);
  P = addrn(P, mulrn(w1, xiy));
  P = addrn(P, mulrn(w2, xiz));
  const float so = s[o], bo = bi[o];
  const int* ip = idx + ((size_t)b * N + n) * KNN;
  float m = 0.0f;
#pragma unroll 4
  for (int k = 0; k < KNN; ++k) {
    int j = ip[k];
    if ((unsigned)j >= (unsigned)N) j = n;
    const float ex = subrn(p[j], xix);
    const float ey = subrn(p[N + j], xiy);
    const float ez = subrn(p[2 * N + j], xiz);
    float acc = addrn(P, mulrn(w3, ex));
    acc = addrn(acc, mulrn(w4, ey));
    acc = addrn(acc, mulrn(w5, ez));
    m = fmaxf(m, addrn(mulrn(so, acc), bo));
  }
  cat[((size_t)b * N + n) * 320 + o] = m;
}

// 64-in EdgeConv as edge-GEMM: 8 points x 20 slots = 160 edges (no dups),
// OH output halves (1 -> 64 outs; 2 -> fused 128 outs, e staged ONCE).
// Edge frags: i=0,1 quads (edge=64i+4g+e) + i=2 pairs (edge=128+2g+e).
// gmax epilogue at pair granularity: row = edge>>1 (80 rows), point p owns
// rows 10p..10p+9.
template <int OH>
__global__ __launch_bounds__(256) void ec_edge(
    const float* __restrict__ cat, int inoff, const int* __restrict__ idx,
    const float* __restrict__ w, const float* __restrict__ s,
    const float* __restrict__ bi, float* __restrict__ catout, int outoff) {
  constexpr int EST = 164;         // e-chunk row stride
  constexpr int RS = 68;           // gmax row stride
  constexpr int PS = 64 * OH + 4;  // Pt row stride
  constexpr int WS = 64 * OH + 4;  // Wl2 row stride
  __shared__ float U[80 * RS];     // 21.76 KB multi-purpose (W1 / e-chunk / gmax)
  __shared__ float xis[8][64];     // 2 KB
  __shared__ float Pt[8 * PS];
  __shared__ float Wl2[16 * WS];
  __shared__ int jl[160];
  const int t = threadIdx.x;
  const int b = blockIdx.y;
  const int n0 = blockIdx.x * 8;
  const size_t bN = (size_t)b * N;

  // stage xis + jl
#pragma unroll
  for (int q = 0; q < 2; ++q) {
    const int p = (t >> 6) + 4 * q;
    const int c = t & 63;
    xis[p][c] = cat[(bN + n0 + p) * 320 + inoff + c];
  }
  if (t < 160) {
    const int p = t / 20;
    const int k = t % 20;
    int j = idx[(bN + n0 + p) * KNN + k];
    if ((unsigned)j >= (unsigned)N) j = n0 + p;  // firewall
    jl[t] = j;
  }
  __syncthreads();

  // prefix P per output-half (W1 staged through U, stride 66 -> float2 reads)
#pragma unroll
  for (int ho = 0; ho < OH; ++ho) {
#pragma unroll
    for (int q = 0; q < 16; ++q) {
      const int l = t + 256 * q;
      U[(l >> 6) * 66 + (l & 63)] = w[(ho * 64 + (l >> 6)) * 128 + (l & 63)];
    }
    __syncthreads();
    {
      const int o = t & 63;
      const int p0 = t >> 6;
      const float2* wq = (const float2*)&U[o * 66];
      const float2* x0 = (const float2*)&xis[p0][0];
      const float2* x1 = (const float2*)&xis[p0 + 4][0];
      float2 wv = wq[0];
      float2 a0 = x0[0];
      float2 a1 = x1[0];
      float P0 = mulrn(wv.x, a0.x);
      float P1 = mulrn(wv.x, a1.x);
      P0 = addrn(P0, mulrn(wv.y, a0.y));
      P1 = addrn(P1, mulrn(wv.y, a1.y));
#pragma unroll
      for (int c2 = 1; c2 < 32; ++c2) {
        wv = wq[c2];
        a0 = x0[c2];
        a1 = x1[c2];
        P0 = addrn(P0, mulrn(wv.x, a0.x));
        P1 = addrn(P1, mulrn(wv.x, a1.x));
        P0 = addrn(P0, mulrn(wv.y, a0.y));
        P1 = addrn(P1, mulrn(wv.y, a1.y));
      }
      Pt[p0 * PS + ho * 64 + o] = P0;
      Pt[(p0 + 4) * PS + ho * 64 + o] = P1;
    }
    __syncthreads();
  }

  const int g = t & 15;  // edge-frag lane
  const int h = t >> 4;  // output-frag lane: outputs 64*ho + 4h + u
  v2f a4[2][4][2 * OH];  // quad frags (i=0,1)
  v2f a2p[2][2 * OH];    // pair frag (i=2)
#pragma unroll
  for (int i = 0; i < 2; ++i) {
    const int p = (64 * i + 4 * g) / 20;
#pragma unroll
    for (int ho = 0; ho < OH; ++ho) {
      const float4 Pv = *(const float4*)&Pt[p * PS + ho * 64 + 4 * h];
#pragma unroll
      for (int e = 0; e < 4; ++e) {
        a4[i][e][2 * ho] = (v2f){Pv.x, Pv.y};
        a4[i][e][2 * ho + 1] = (v2f){Pv.z, Pv.w};
      }
    }
  }
  {
    const int p = (128 + 2 * g) / 20;
#pragma unroll
    for (int ho = 0; ho < OH; ++ho) {
      const float4 Pv = *(const float4*)&Pt[p * PS + ho * 64 + 4 * h];
#pragma unroll
      for (int e = 0; e < 2; ++e) {
        a2p[e][2 * ho] = (v2f){Pv.x, Pv.y};
        a2p[e][2 * ho + 1] = (v2f){Pv.z, Pv.w};
      }
    }
  }

  // K chunks: stage Wl2 + e-chunk, then pure MAC phase (ascending c)
  for (int kc = 0; kc < 64; kc += 16) {
#pragma unroll
    for (int ho = 0; ho < OH; ++ho) {
      const int o = t >> 2;
      const int cq = t & 3;
      const float4 wv = *(const float4*)&w[(ho * 64 + o) * 128 + 64 + kc + 4 * cq];
      Wl2[(4 * cq + 0) * WS + ho * 64 + o] = wv.x;
      Wl2[(4 * cq + 1) * WS + ho * 64 + o] = wv.y;
      Wl2[(4 * cq + 2) * WS + ho * 64 + o] = wv.z;
      Wl2[(4 * cq + 3) * WS + ho * 64 + o] = wv.w;
    }
#pragma unroll
    for (int q = 0; q < 3; ++q) {
      const int sl = 64 * q + (t >> 2);
      const int cq = t & 3;
      if (sl < 160) {
        const int p = sl / 20;
        const int j = jl[sl];
        const float4 xj = *(const float4*)&cat[(bN + j) * 320 + inoff + kc + 4 * cq];
        const float4 xv = *(const float4*)&xis[p][kc + 4 * cq];
        U[(4 * cq + 0) * EST + sl] = subrn(xj.x, xv.x);
        U[(4 * cq + 1) * EST + sl] = subrn(xj.y, xv.y);
        U[(4 * cq + 2) * EST + sl] = subrn(xj.z, xv.z);
        U[(4 * cq + 3) * EST + sl] = subrn(xj.w, xv.w);
      }
    }
    __syncthreads();
#pragma unroll
    for (int k = 0; k < 16; ++k) {
      const float4 ef0 = *(const float4*)&U[k * EST + 4 * g];
      const float4 ef1 = *(const float4*)&U[k * EST + 64 + 4 * g];
      const v2f ef2 = *(const v2f*)&U[k * EST + 128 + 2 * g];
      const float e0[4] = {ef0.x, ef0.y, ef0.z, ef0.w};
      const float e1[4] = {ef1.x, ef1.y, ef1.z, ef1.w};
      const float e2[2] = {ef2.x, ef2.y};
#pragma unroll
      for (int ho = 0; ho < OH; ++ho) {
        const float4 wf = *(const float4*)&Wl2[k * WS + ho * 64 + 4 * h];
        const v2f w01 = (v2f){wf.x, wf.y};
        const v2f w23 = (v2f){wf.z, wf.w};
#pragma unroll
        for (int e = 0; e < 4; ++e) {
          const v2f x0 = (v2f){e0[e], e0[e]};
          a4[0][e][2 * ho] = addrn2(a4[0][e][2 * ho], mulrn2(w01, x0));
          a4[0][e][2 * ho + 1] = addrn2(a4[0][e][2 * ho + 1], mulrn2(w23, x0));
          const v2f x1 = (v2f){e1[e], e1[e]};
          a4[1][e][2 * ho] = addrn2(a4[1][e][2 * ho], mulrn2(w01, x1));
          a4[1][e][2 * ho + 1] = addrn2(a4[1][e][2 * ho + 1], mulrn2(w23, x1));
        }
#pragma unroll
        for (int e = 0; e < 2; ++e) {
          const v2f x2 = (v2f){e2[e], e2[e]};
          a2p[e][2 * ho] = addrn2(a2p[e][2 * ho], mulrn2(w01, x2));
          a2p[e][2 * ho + 1] = addrn2(a2p[e][2 * ho + 1], mulrn2(w23, x2));
        }
      }
    }
    __syncthreads();  // U readers done before restage / gmax
  }

  // epilogue per half: relu(s*acc+b) per edge, pair-max rows, point reduce
#pragma unroll
  for (int ho = 0; ho < OH; ++ho) {
    const float4 sv = *(const float4*)&s[ho * 64 + 4 * h];
    const float4 bv = *(const float4*)&bi[ho * 64 + 4 * h];
    const float sc[4] = {sv.x, sv.y, sv.z, sv.w};
    const float bc[4] = {bv.x, bv.y, bv.z, bv.w};
#pragma unroll
    for (int i = 0; i < 2; ++i) {
#pragma unroll
      for (int ep = 0; ep < 2; ++ep) {
        const int row = 32 * i + 2 * g + ep;
        float gm[4] = {0.f, 0.f, 0.f, 0.f};
#pragma unroll
        for (int ee = 0; ee < 2; ++ee) {
          const int e = 2 * ep + ee;
#pragma unroll
          for (int u = 0; u < 4; ++u) {
            const v2f a = a4[i][e][2 * ho + (u >> 1)];
            const float av = (u & 1) ? a.y : a.x;
            gm[u] = fmaxf(gm[u], fmaxf(addrn(mulrn(sc[u], av), bc[u]), 0.f));
          }
        }
        *(float4*)&U[row * RS + 4 * h] = make_float4(gm[0], gm[1], gm[2], gm[3]);
      }
    }
    {
      const int row = 64 + g;
      float gm[4] = {0.f, 0.f, 0.f, 0.f};
#pragma unroll
      for (int e = 0; e < 2; ++e) {
#pragma unroll
        for (int u = 0; u < 4; ++u) {
          const v2f a = a2p[e][2 * ho + (u >> 1)];
          const float av = (u & 1) ? a.y : a.x;
          gm[u] = fmaxf(gm[u], fmaxf(addrn(mulrn(sc[u], av), bc[u]), 0.f));
        }
      }
      *(float4*)&U[row * RS + 4 * h] = make_float4(gm[0], gm[1], gm[2], gm[3]);
    }
    __syncthreads();
#pragma unroll
    for (int q = 0; q < 2; ++q) {
      const int o = t & 63;
      const int p = (t >> 6) + 4 * q;
      const float* ur = &U[(10 * p) * RS + o];
      float m = ur[0];
#pragma unroll
      for (int r = 1; r < 10; ++r) m = fmaxf(m, ur[r * RS]);
      catout[(bN + n0 + p) * 320 + outoff + ho * 64 + o] = m;
    }
    if (ho + 1 < OH) __syncthreads();  // pass 2 rewrites U
  }
}

// ---------------------------------------------------------------------------
// Local layer: loc[o][n] = relu(s*<W[o,:],cat[n,:]>+b), serial ascending c.
// KC=16, DOUBLE-BUFFERED LDS (1 barrier/chunk; stage-write overlapped after
// MAC) + fused-asm packed MACs (tied acc, op_sel broadcast) + direct v2f LDS
// loads at pm-unswizzled offsets. Grid transposed (ptile fastest) so the 8
// q-tile readers of each cat ptile land on the same XCD L2.
// ---------------------------------------------------------------------------
__global__ __launch_bounds__(256) void local_gemm(
    const float* __restrict__ cat, const float* __restrict__ w,
    const float* __restrict__ s, const float* __restrict__ bi,
    float* __restrict__ pval, int* __restrict__ pidx) {
  constexpr int KC = 16;
  constexpr int XS = 132;
  constexpr int BUF = KC * XS * 2;     // floats per buffer (xs + wsd)
  __shared__ float smem[2 * BUF];      // 33,792 B (double-buffered)
  const int t = threadIdx.x;
  const int q0 = blockIdx.y * 128;     // transposed grid: y = q-tile
  const int ptile = blockIdx.x;        //                  x = point tile
  const size_t pt0 = (size_t)ptile * 128;
  const int g = t & 15;
  const int h = t >> 4;
  v2f acc2[2][2][4][2];
#pragma unroll
  for (int ep = 0; ep < 2; ++ep)
#pragma unroll
    for (int fp = 0; fp < 2; ++fp)
#pragma unroll
      for (int pi = 0; pi < 4; ++pi)
#pragma unroll
        for (int u = 0; u < 2; ++u) acc2[ep][fp][pi][u] = (v2f){0.f, 0.f};

  const int lk = t & 15;               // k-row within chunk
  const int lp = t >> 4;               // column group 0..15
  const int px = ((lk >> 3) & 1) << 1;  // store swizzle: 0 or 2
  const float* catp = cat + pt0 * 320 + lk;
  const float* wp = w + (size_t)q0 * 320 + lk;
  float rx[8], rw[8];
#pragma unroll
  for (int i = 0; i < 8; ++i) rx[i] = catp[(size_t)(lp + 16 * i) * 320];
#pragma unroll
  for (int i = 0; i < 8; ++i) rw[i] = wp[(size_t)(lp + 16 * i) * 320];
  // prologue: stage chunk 0 into buffer 0
  {
    float* xs0 = smem;
    float* ws0 = smem + KC * XS;
#pragma unroll
    for (int i = 0; i < 8; ++i) xs0[lk * XS + ((lp + 16 * i) ^ px)] = rx[i];
#pragma unroll
    for (int i = 0; i < 8; ++i) ws0[lk * XS + ((lp + 16 * i) ^ px)] = rw[i];
  }

#pragma unroll 2
  for (int ch = 0; ch < 20; ++ch) {
    const int par = ch & 1;
    const float* xsr = smem + par * BUF;
    const float* wsr = xsr + KC * XS;
    if (ch + 1 < 20) {  // issue next-chunk global loads (land during MAC)
      const int ko = (ch + 1) * KC;
#pragma unroll
      for (int i = 0; i < 8; ++i) rx[i] = catp[(size_t)(lp + 16 * i) * 320 + ko];
#pragma unroll
      for (int i = 0; i < 8; ++i) rw[i] = wp[(size_t)(lp + 16 * i) * 320 + ko];
    }
    __syncthreads();  // buf[par] writes (prev iter / prologue) visible
#pragma unroll
    for (int k = 0; k < KC; ++k) {
      const int pm2 = ((k >> 3) & 1) << 1;  // 0 or 2, compile-time under unroll
      const float* wrow = &wsr[k * XS];
      const float* xrow = &xsr[k * XS];
      // logical pairs at pm-unswizzled physical offsets (aligned v2f loads)
      v2f wA[2], wB[2];  // wA -> acc u=0 (logical cols 4h,4h+1), wB -> u=1
#pragma unroll
      for (int fp = 0; fp < 2; ++fp) {
        wA[fp] = *(const v2f*)&wrow[64 * fp + 4 * h + pm2];
        wB[fp] = *(const v2f*)&wrow[64 * fp + 4 * h + (2 - pm2)];
      }
#pragma unroll
      for (int ep = 0; ep < 2; ++ep) {
        const v2f xq0 = *(const v2f*)&xrow[64 * ep + 4 * g + pm2];        // pts 0,1
        const v2f xq1 = *(const v2f*)&xrow[64 * ep + 4 * g + (2 - pm2)];  // pts 2,3
#pragma unroll
        for (int fp = 0; fp < 2; ++fp) {
          pkmac_lo(acc2[ep][fp][0][0], wA[fp], xq0);
          pkmac_lo(acc2[ep][fp][0][1], wB[fp], xq0);
          pkmac_hi(acc2[ep][fp][1][0], wA[fp], xq0);
          pkmac_hi(acc2[ep][fp][1][1], wB[fp], xq0);
          pkmac_lo(acc2[ep][fp][2][0], wA[fp], xq1);
          pkmac_lo(acc2[ep][fp][2][1], wB[fp], xq1);
          pkmac_hi(acc2[ep][fp][3][0], wA[fp], xq1);
          pkmac_hi(acc2[ep][fp][3][1], wB[fp], xq1);
        }
      }
    }
    if (ch + 1 < 20) {  // stage next chunk into the other buffer (no barrier:
      float* xsw = smem + (par ^ 1) * BUF;  // readers of buf[par^1] finished
      float* wsw = xsw + KC * XS;           // before barrier at top of ch)
#pragma unroll
      for (int i = 0; i < 8; ++i) xsw[lk * XS + ((lp + 16 * i) ^ px)] = rx[i];
#pragma unroll
      for (int i = 0; i < 8; ++i) wsw[lk * XS + ((lp + 16 * i) ^ px)] = rw[i];
    }
  }
  // epilogue: relu(s*acc+b), per-thread argmax over 8 points ascending
  const int bb = ptile >> 5;
  const int blk = ptile & 31;
  float mv[8];
  int mi[8];
#pragma unroll
  for (int fp = 0; fp < 2; ++fp)
#pragma unroll
    for (int c = 0; c < 4; ++c) {
      const int f = fp * 4 + c;
      const int cl = 64 * fp + 4 * h + c;
      const float sc = s[q0 + cl];
      const float bc = bi[q0 + cl];
      mv[f] = -1.f;
      mi[f] = 0;
#pragma unroll
      for (int ep = 0; ep < 2; ++ep)
#pragma unroll
        for (int pi = 0; pi < 4; ++pi) {
          const v2f a2 = acc2[ep][fp][pi][c >> 1];
          const float a = (c & 1) ? a2.y : a2.x;
          const float v = fmaxf(addrn(mulrn(sc, a), bc), 0.f);
          if (v > mv[f]) { mv[f] = v; mi[f] = 64 * ep + 4 * g + pi; }
        }
    }
  __syncthreads();
  float* smv = smem;                       // 2112 floats
  int* smi = (int*)(smem + 16 * 132);      // next 2112 ints
#pragma unroll
  for (int fp = 0; fp < 2; ++fp)
#pragma unroll
    for (int c = 0; c < 4; ++c) {
      const int cl = 64 * fp + 4 * h + c;
      smv[g * 132 + cl] = mv[fp * 4 + c];
      smi[g * 132 + cl] = mi[fp * 4 + c];
    }
  __syncthreads();
  if (t < 128) {
    float best = smv[t];
    int bidx = smi[t];
    for (int gg = 1; gg < 16; ++gg) {
      const float v = smv[gg * 132 + t];
      const int vi = smi[gg * 132 + t];
      // candidates g-interleaved: ties resolve to SMALLEST point idx
      if (v > best || (v == best && vi < bidx)) { best = v; bidx = vi; }
    }
    const int n_l = blk * 128 + bidx;
    const size_t po = ((size_t)bb * 1024 + q0 + t) * 32 + blk;
    pval[po] = best;
    pidx[po] = n_l;
  }
}

__global__ __launch_bounds__(256) void final_reduce(
    const float* __restrict__ pval, const int* __restrict__ pidx,
    float* __restrict__ glob, float* __restrict__ oidx) {
  const int o = blockIdx.x * 256 + threadIdx.x;  // 8192 = B*1024
  const float* pv = pval + (size_t)o * 32;
  const int* pi = pidx + (size_t)o * 32;
  float best = pv[0];
  int bi = pi[0];
  for (int k = 1; k < 32; ++k) {
    const float v = pv[k];
    // tiles are ascending disjoint point ranges: strict > = first occurrence
    if (v > best) { best = v; bi = pi[k]; }
  }
  glob[o] = best;
  oidx[o] = (float)bi;
}

template <int KIN, int OUTS>
__global__ __launch_bounds__(256) void dense_wave(
    const float* __restrict__ in, const float* __restrict__ w,
    const float* __restrict__ s, const float* __restrict__ bi,
    float* __restrict__ out) {
  const int wid = (blockIdx.x * 256 + threadIdx.x) >> 6;
  const int lane = threadIdx.x & 63;
  const int b = wid / OUTS;
  const int o = wid % OUTS;
  const float* ip = in + (size_t)b * KIN;
  const float* wr = w + (size_t)o * KIN;
  float acc = 0.f;
  for (int k = lane; k < KIN; k += 64) acc = fmaf(wr[k], ip[k], acc);
#pragma unroll
  for (int off = 32; off; off >>= 1) acc += __shfl_down(acc, off);
  if (lane == 0) out[(size_t)b * OUTS + o] = fmaxf(fmaf(s[o], acc, bi[o]), 0.f);
}

extern "C" void kernel_launch(void* const* d_in, const int* in_sizes, int n_in,
                              void* d_out, int out_size, void* d_ws, size_t ws_size,
                              hipStream_t stream) {
  (void)in_sizes; (void)n_in; (void)out_size; (void)ws_size;
  const float* pts = (const float*)d_in[0];
  const float* ec_w[4] = {(const float*)d_in[1], (const float*)d_in[4],
                          (const float*)d_in[7], (const float*)d_in[10]};
  const float* ec_s[4] = {(const float*)d_in[2], (const float*)d_in[5],
                          (const float*)d_in[8], (const float*)d_in[11]};
  const float* ec_b[4] = {(const float*)d_in[3], (const float*)d_in[6],
                          (const float*)d_in[9], (const float*)d_in[12]};
  const float* local_w = (const float*)d_in[13];
  const float* local_s = (const float*)d_in[14];
  const float* local_b = (const float*)d_in[15];
  const float* g_w0 = (const float*)d_in[16];
  const float* g_s0 = (const float*)d_in[17];
  const float* g_b0 = (const float*)d_in[18];
  const float* g_w1 = (const float*)d_in[19];
  const float* g_s1 = (const float*)d_in[20];
  const float* g_b1 = (const float*)d_in[21];

  char* ws = (char*)d_ws;
  int* idxbuf = (int*)(ws + OFF_IDX);
  float* cat = (float*)(ws + OFF_CAT);
  float* pv = (float*)(ws + OFF_PV);
  int* pi = (int*)(ws + OFF_PI);
  float* glob = (float*)(ws + OFF_GLOB);
  float* hbuf = (float*)(ws + OFF_H);
  float* listd = (float*)(ws + OFF_LD);
  int* listj = (int*)(ws + OFF_LJ);
  int* counts = (int*)(ws + OFF_CNT);
  float* outv = (float*)d_out;   // [8][256]  fp32
  float* oidx = outv + 2048;     // [8][1024] fp32 (indices as floats)

  knn_scan<<<dim3(32, 2, 8), 256, 0, stream>>>(pts, listd, listj, counts);
  knn_merge<<<dim3(512), 64, 0, stream>>>(listd, listj, counts, idxbuf);

  // layer 1 (3 -> 64)
  ec_layer1<<<dim3(1024, 8), 256, 0, stream>>>(pts, idxbuf, ec_w[0], ec_s[0], ec_b[0], cat);
  // layer 2 (64 -> 64)
  ec_edge<1><<<dim3(512, 8), 256, 0, stream>>>(cat, 0, idxbuf, ec_w[1], ec_s[1], ec_b[1], cat, 64);
  // layer 3 (64 -> 64)
  ec_edge<1><<<dim3(512, 8), 256, 0, stream>>>(cat, 64, idxbuf, ec_w[2], ec_s[2], ec_b[2], cat, 128);
  // layer 4 (64 -> 128), fused both output halves, e staged once
  ec_edge<2><<<dim3(512, 8), 256, 0, stream>>>(cat, 128, idxbuf, ec_w[3], ec_s[3], ec_b[3], cat, 192);

  // transposed grid: ptile fastest -> same-ptile q-tiles co-located per XCD
  local_gemm<<<dim3(256, 8), 256, 0, stream>>>(cat, local_w, local_s, local_b, pv, pi);
  final_reduce<<<dim3(32), 256, 0, stream>>>(pv, pi, glob, oidx);
  dense_wave<1024, 512><<<dim3(1024), 256, 0, stream>>>(glob, g_w0, g_s0, g_b0, hbuf);
  dense_wave<512, 256><<<dim3(512), 256, 0, stream>>>(hbuf, g_w1, g_s1, g_b1, outv);
}

// Round 7
// 1356.382 us; speedup vs baseline: 1.0254x; 1.0254x over previous
//
#include <hip/hip_runtime.h>
#include <hip/hip_bf16.h>

namespace {
constexpr int B = 8;
constexpr int N = 4096;
constexpr int KNN = 20;
constexpr int NSEG = 4;
constexpr int SEGLEN = N / NSEG;   // 1024
constexpr int HSEG = SEGLEN / 2;   // 512: half-segment per thread
constexpr int CAP = 24;
constexpr int SLOTS = NSEG * CAP;  // 96

// workspace layout (bytes)
constexpr size_t OFF_IDX  = 0;                          // int [B][N][KNN]
constexpr size_t SZ_IDX   = (size_t)B * N * KNN * 4;
constexpr size_t OFF_T    = OFF_IDX + SZ_IDX;           // knn scratch region
constexpr size_t SZ_T     = (size_t)B * N * 128 * 4;
constexpr size_t OFF_CAT  = OFF_T + SZ_T;               // float [B][N][320]
constexpr size_t SZ_CAT   = (size_t)B * N * 320 * 4;
constexpr size_t OFF_PV   = OFF_CAT + SZ_CAT;           // float [B][1024][32]
constexpr size_t SZ_PV    = (size_t)B * 1024 * 32 * 4;
constexpr size_t OFF_PI   = OFF_PV + SZ_PV;             // int   [B][1024][32]
constexpr size_t OFF_GLOB = OFF_PI + SZ_PV;             // float [B][1024]
constexpr size_t OFF_H    = OFF_GLOB + (size_t)B * 1024 * 4;  // float [B][512]
// knn scratch overlaid on T + head of CAT (dead once merge completes):
constexpr size_t OFF_LD   = OFF_T;                      // float [B*N][SLOTS]
constexpr size_t SZ_LD    = (size_t)B * N * SLOTS * 4;
constexpr size_t OFF_LJ   = OFF_LD + SZ_LD;             // int   [B*N][SLOTS]
constexpr size_t OFF_CNT  = OFF_LJ + SZ_LD;             // int   [B*N][NSEG]
}  // namespace

typedef float v2f __attribute__((ext_vector_type(2)));

// Non-contractable fp32 ops: bit-exact match to np's mul-then-add serial loops.
__device__ __forceinline__ float mulrn(float a, float b) {
#pragma clang fp contract(off)
  return a * b;
}
__device__ __forceinline__ float addrn(float a, float b) {
#pragma clang fp contract(off)
  return a + b;
}
__device__ __forceinline__ float subrn(float a, float b) {
#pragma clang fp contract(off)
  return a - b;
}
// Packed (v_pk_mul_f32 / v_pk_add_f32): per-element IEEE rn == scalar ops.
__device__ __forceinline__ v2f mulrn2(v2f a, v2f b) {
#pragma clang fp contract(off)
  return a * b;
}
__device__ __forceinline__ v2f addrn2(v2f a, v2f b) {
#pragma clang fp contract(off)
  return a + b;
}

// Fused packed MAC, VOP3P with op_sel broadcast of the x-half (semantics
// hardware-validated: per-element IEEE rn mul + rn add, same as scalar).
// acc tied "+v" (no result copy), scratch early-clobber, inputs are aligned
// v2f pairs loaded directly from LDS (no repack movs).
__device__ __forceinline__ void pkmac_lo(v2f& acc, v2f w, v2f x) {
  v2f t;
  asm("v_pk_mul_f32 %1, %2, %3 op_sel:[0,0] op_sel_hi:[1,0]\n\t"
      "v_pk_add_f32 %0, %0, %1"
      : "+v"(acc), "=&v"(t) : "v"(w), "v"(x));
}
__device__ __forceinline__ void pkmac_hi(v2f& acc, v2f w, v2f x) {
  v2f t;
  asm("v_pk_mul_f32 %1, %2, %3 op_sel:[0,1] op_sel_hi:[1,1]\n\t"
      "v_pk_add_f32 %0, %0, %1"
      : "+v"(acc), "=&v"(t) : "v"(w), "v"(x));
}

// ---------------------------------------------------------------------------
// kNN, half-segment split for occupancy: wave = (seg_local, row-group); within
// the wave lanes l / l^32 scan the two 512-candidate halves of the same
// (2 rows, seg). 2048 waves total (2/SIMD) vs 1024 before. Sorted-20 bubble
// per (row, half); exact segment 20th = Batcher merge of the two sorted
// half-lists: theta = max_i min(a_i, b_{19-i}) with b via shfl_xor(.,32)
// (pure selection -> bit-identical to single-scan da[19]). Recovery appends
// front (half 0) / back (half 1) into the shared CAP-slot region; slot order
// is irrelevant (merge selects by (d,j) lex keys). counts = front | back<<16.
// ---------------------------------------------------------------------------
__global__ __launch_bounds__(256) void knn_scan(
    const float* __restrict__ pts,
    float* __restrict__ listd, int* __restrict__ listj, int* __restrict__ counts) {
  __shared__ float4 sp[2 * SEGLEN];  // 32 KB: (x, y, z, sq) for 2 segments
  const int b = blockIdx.z;
  const int tid = threadIdx.x;
  const float* px = pts + (size_t)b * 3 * N;
  const int cb0 = blockIdx.y * 2 * SEGLEN;  // candidate base (2 segs/block)
  for (int i = tid; i < 2 * SEGLEN; i += 256) {
    const float x = px[cb0 + i];
    const float y = px[N + cb0 + i];
    const float z = px[2 * N + cb0 + i];
    const float sq = addrn(addrn(mulrn(x, x), mulrn(y, y)), mulrn(z, z));
    sp[i] = make_float4(x, y, z, sq);
  }
  __syncthreads();
  const int lane = tid & 63;
  const int rl = lane & 31;            // row lane
  const int h2 = lane >> 5;            // half of the segment
  const int segl = (tid >> 6) & 1;     // segment within the block's pair
  const int rg = tid >> 7;             // row group
  const int seg = blockIdx.y * 2 + segl;
  const int row0 = blockIdx.x * 128 + rg * 64 + rl;
  const int row1 = row0 + 32;
  // queries from global (identical arithmetic to staging -> bit-same sq)
  const float ax = px[row0], ay = px[N + row0], az = px[2 * N + row0];
  const float bx = px[row1], by = px[N + row1], bz = px[2 * N + row1];
  const float4 qa = make_float4(ax, ay, az,
      addrn(addrn(mulrn(ax, ax), mulrn(ay, ay)), mulrn(az, az)));
  const float4 qb = make_float4(bx, by, bz,
      addrn(addrn(mulrn(bx, bx), mulrn(by, by)), mulrn(bz, bz)));
  float da[KNN], db[KNN];
#pragma unroll
  for (int t = 0; t < KNN; ++t) { da[t] = 3.0e38f; db[t] = 3.0e38f; }
  const int j0 = segl * SEGLEN + h2 * HSEG;  // LDS-local candidate base
#pragma unroll 2
  for (int jj = 0; jj < HSEG; ++jj) {
    const float4 c = sp[j0 + jj];
    v2f t0 = mulrn2((v2f){qa.x, qb.x}, (v2f){c.x, c.x});
    t0 = addrn2(t0, mulrn2((v2f){qa.y, qb.y}, (v2f){c.y, c.y}));
    t0 = addrn2(t0, mulrn2((v2f){qa.z, qb.z}, (v2f){c.z, c.z}));
    v2f d2 = addrn2((v2f){qa.w, qb.w}, (v2f){c.w, c.w});
    d2 = d2 - mulrn2((v2f){2.0f, 2.0f}, t0);
    if (d2.x < da[KNN - 1]) {
      float cur = d2.x;
#pragma unroll
      for (int t = 0; t < KNN; ++t) {
        const float lo = fminf(cur, da[t]);
        cur = fmaxf(cur, da[t]);
        da[t] = lo;
      }
    }
    if (d2.y < db[KNN - 1]) {
      float cur = d2.y;
#pragma unroll
      for (int t = 0; t < KNN; ++t) {
        const float lo = fminf(cur, db[t]);
        cur = fmaxf(cur, db[t]);
        db[t] = lo;
      }
    }
  }
  // exact segment 20th via bitonic cross-half merge (partner = lane ^ 32);
  // pure min/max selection over the same multiset -> both lanes get the same
  // bit pattern, equal to the single-scan 20th.
  float tha = -3.0e38f, thb = -3.0e38f;
#pragma unroll
  for (int i = 0; i < KNN; ++i) {
    tha = fmaxf(tha, fminf(da[i], __shfl_xor(da[KNN - 1 - i], 32)));
    thb = fmaxf(thb, fminf(db[i], __shfl_xor(db[KNN - 1 - i], 32)));
  }
  float* lda = listd + (size_t)(b * N + row0) * SLOTS + seg * CAP;
  int* lja = listj + (size_t)(b * N + row0) * SLOTS + seg * CAP;
  float* ldb = listd + (size_t)(b * N + row1) * SLOTS + seg * CAP;
  int* ljb = listj + (size_t)(b * N + row1) * SLOTS + seg * CAP;
  const int jg0 = cb0 + j0;  // global candidate index base
  int ca = 0, cb = 0;
#pragma unroll 2
  for (int jj = 0; jj < HSEG; ++jj) {
    const float4 c = sp[j0 + jj];
    v2f t0 = mulrn2((v2f){qa.x, qb.x}, (v2f){c.x, c.x});
    t0 = addrn2(t0, mulrn2((v2f){qa.y, qb.y}, (v2f){c.y, c.y}));
    t0 = addrn2(t0, mulrn2((v2f){qa.z, qb.z}, (v2f){c.z, c.z}));
    v2f d2 = addrn2((v2f){qa.w, qb.w}, (v2f){c.w, c.w});
    d2 = d2 - mulrn2((v2f){2.0f, 2.0f}, t0);
    if (d2.x <= tha && ca < CAP) {
      const int sl = h2 ? (CAP - 1 - ca) : ca;
      lda[sl] = d2.x; lja[sl] = jg0 + jj; ++ca;
    }
    if (d2.y <= thb && cb < CAP) {
      const int sl = h2 ? (CAP - 1 - cb) : cb;
      ldb[sl] = d2.y; ljb[sl] = jg0 + jj; ++cb;
    }
  }
  const int oa = __shfl_xor(ca, 32);
  const int ob = __shfl_xor(cb, 32);
  if (h2 == 0) {  // pack: front count | back count << 16
    counts[(b * N + row0) * NSEG + seg] = ca | (oa << 16);
    counts[(b * N + row1) * NSEG + seg] = cb | (ob << 16);
  }
}

// Merge: per row, select 20 lexicographically-smallest (dist, j) from <=96
// candidates via monotone uint64 keys. counts packed front|back<<16; valid
// slots are [0, front) u [CAP-back, CAP).
__global__ __launch_bounds__(64) void knn_merge(
    const float* __restrict__ listd, const int* __restrict__ listj,
    const int* __restrict__ counts, int* __restrict__ idxout) {
  __shared__ unsigned long long keys[64][SLOTS + 1];  // 49,664 B
  const int r0 = blockIdx.x * 64;
  const int t = threadIdx.x;
  for (int i = t; i < 64 * SLOTS; i += 64) {
    const int rr = i / SLOTS;
    const int sl = i % SLOTS;
    const int seg = sl / CAP;
    const int e = sl % CAP;
    const int row = r0 + rr;
    unsigned long long key = 0xFFFFFFFE00000000ULL | (unsigned)row;  // fallback: self
    const int cp = counts[row * NSEG + seg];
    if (e < (cp & 0xFFFF) || e >= CAP - (cp >> 16)) {
      const float d = listd[(size_t)row * SLOTS + sl];
      unsigned ub = __float_as_uint(d);
      ub ^= (ub & 0x80000000u) ? 0xFFFFFFFFu : 0x80000000u;
      key = ((unsigned long long)ub << 32) | (unsigned)listj[(size_t)row * SLOTS + sl];
    }
    keys[rr][sl] = key;
  }
  __syncthreads();
  int* outp = idxout + (size_t)(r0 + t) * KNN;
  for (int sel = 0; sel < KNN; ++sel) {
    unsigned long long best = ~0ULL;
    int bs = 0;
#pragma unroll 8
    for (int sl = 0; sl < SLOTS; ++sl) {
      const unsigned long long k2 = keys[t][sl];
      if (k2 < best) { best = k2; bs = sl; }
    }
    keys[t][bs] = ~0ULL;
    outp[sel] = (int)(best & 0xFFFFFFFFu);
  }
}

// ---------------------------------------------------------------------------
// EdgeConv, BIT-EXACT serial semantics per (o, n, k):
//   y = sum_c W1[o,c]*x_i[c]  (prefix P)  then  += W2[o,c]*(x_j[c]-x_i[c]).
// ---------------------------------------------------------------------------

// Layer 1 (cin=3): wave per point, lane = output o.
__global__ __launch_bounds__(256) void ec_layer1(
    const float* __restrict__ pts, const int* __restrict__ idx,
    const float* __restrict__ w, const float* __restrict__ s,
    const float* __restrict__ bi, float* __restrict__ cat) {
  const int b = blockIdx.y;
  const int n = blockIdx.x * 4 + (threadIdx.x >> 6);
  const int o = threadIdx.x & 63;
  const float* p = pts + (size_t)b * 3 * N;
  const float xix = p[n], xiy = p[N + n], xiz = p[2 * N + n];
  const float* wr = w + o * 6;
  const float w0 = wr[0], w1 = wr[1], w2 = wr[2], w3 = wr[3], w4 = wr[4], w5 = wr[5];
  float P = mulrn(w0, xix);
  P = addrn(P, mulrn(w1, xiy));
  P = addrn(P, mulrn(w2, xiz));
  const float so = s[o], bo = bi[o];
  const int* ip = idx + ((size_t)b * N + n) * KNN;
  float m = 0.0f;
#pragma unroll 4
  for (int k = 0; k < KNN; ++k) {
    int j = ip[k];
    if ((unsigned)j >= (unsigned)N) j = n;
    const float ex = subrn(p[j], xix);
    const float ey = subrn(p[N + j], xiy);
    const float ez = subrn(p[2 * N + j], xiz);
    float acc = addrn(P, mulrn(w3, ex));
    acc = addrn(acc, mulrn(w4, ey));
    acc = addrn(acc, mulrn(w5, ez));
    m = fmaxf(m, addrn(mulrn(so, acc), bo));
  }
  cat[((size_t)b * N + n) * 320 + o] = m;
}

// 64-in EdgeConv as edge-GEMM: 8 points x 20 slots = 160 edges (no dups),
// OH output halves (1 -> 64 outs; 2 -> fused 128 outs, e staged ONCE).
// Edge frags: i=0,1 quads (edge=64i+4g+e) + i=2 pairs (edge=128+2g+e).
// MAC loop: fused-asm pkmac with op_sel broadcast; e-frags and W read as
// aligned v2f pairs (no broadcast-construction movs). Per-accumulator op
// order unchanged (ascending kc, k; mul-then-add) -> bit-exact.
// gmax epilogue at pair granularity: row = edge>>1 (80 rows), point p owns
// rows 10p..10p+9.
template <int OH>
__global__ __launch_bounds__(256) void ec_edge(
    const float* __restrict__ cat, int inoff, const int* __restrict__ idx,
    const float* __restrict__ w, const float* __restrict__ s,
    const float* __restrict__ bi, float* __restrict__ catout, int outoff) {
  constexpr int EST = 164;         // e-chunk row stride
  constexpr int RS = 68;           // gmax row stride
  constexpr int PS = 64 * OH + 4;  // Pt row stride
  constexpr int WS = 64 * OH + 4;  // Wl2 row stride
  __shared__ float U[80 * RS];     // 21.76 KB multi-purpose (W1 / e-chunk / gmax)
  __shared__ float xis[8][64];     // 2 KB
  __shared__ float Pt[8 * PS];
  __shared__ float Wl2[16 * WS];
  __shared__ int jl[160];
  const int t = threadIdx.x;
  const int b = blockIdx.y;
  const int n0 = blockIdx.x * 8;
  const size_t bN = (size_t)b * N;

  // stage xis + jl
#pragma unroll
  for (int q = 0; q < 2; ++q) {
    const int p = (t >> 6) + 4 * q;
    const int c = t & 63;
    xis[p][c] = cat[(bN + n0 + p) * 320 + inoff + c];
  }
  if (t < 160) {
    const int p = t / 20;
    const int k = t % 20;
    int j = idx[(bN + n0 + p) * KNN + k];
    if ((unsigned)j >= (unsigned)N) j = n0 + p;  // firewall
    jl[t] = j;
  }
  __syncthreads();

  // prefix P per output-half (W1 staged through U, stride 66 -> float2 reads)
#pragma unroll
  for (int ho = 0; ho < OH; ++ho) {
#pragma unroll
    for (int q = 0; q < 16; ++q) {
      const int l = t + 256 * q;
      U[(l >> 6) * 66 + (l & 63)] = w[(ho * 64 + (l >> 6)) * 128 + (l & 63)];
    }
    __syncthreads();
    {
      const int o = t & 63;
      const int p0 = t >> 6;
      const float2* wq = (const float2*)&U[o * 66];
      const float2* x0 = (const float2*)&xis[p0][0];
      const float2* x1 = (const float2*)&xis[p0 + 4][0];
      float2 wv = wq[0];
      float2 a0 = x0[0];
      float2 a1 = x1[0];
      float P0 = mulrn(wv.x, a0.x);
      float P1 = mulrn(wv.x, a1.x);
      P0 = addrn(P0, mulrn(wv.y, a0.y));
      P1 = addrn(P1, mulrn(wv.y, a1.y));
#pragma unroll
      for (int c2 = 1; c2 < 32; ++c2) {
        wv = wq[c2];
        a0 = x0[c2];
        a1 = x1[c2];
        P0 = addrn(P0, mulrn(wv.x, a0.x));
        P1 = addrn(P1, mulrn(wv.x, a1.x));
        P0 = addrn(P0, mulrn(wv.y, a0.y));
        P1 = addrn(P1, mulrn(wv.y, a1.y));
      }
      Pt[p0 * PS + ho * 64 + o] = P0;
      Pt[(p0 + 4) * PS + ho * 64 + o] = P1;
    }
    __syncthreads();
  }

  const int g = t & 15;  // edge-frag lane
  const int h = t >> 4;  // output-frag lane: outputs 64*ho + 4h + u
  v2f a4[2][4][2 * OH];  // quad frags (i=0,1)
  v2f a2p[2][2 * OH];    // pair frag (i=2)
#pragma unroll
  for (int i = 0; i < 2; ++i) {
    const int p = (64 * i + 4 * g) / 20;
#pragma unroll
    for (int ho = 0; ho < OH; ++ho) {
      const float4 Pv = *(const float4*)&Pt[p * PS + ho * 64 + 4 * h];
#pragma unroll
      for (int e = 0; e < 4; ++e) {
        a4[i][e][2 * ho] = (v2f){Pv.x, Pv.y};
        a4[i][e][2 * ho + 1] = (v2f){Pv.z, Pv.w};
      }
    }
  }
  {
    const int p = (128 + 2 * g) / 20;
#pragma unroll
    for (int ho = 0; ho < OH; ++ho) {
      const float4 Pv = *(const float4*)&Pt[p * PS + ho * 64 + 4 * h];
#pragma unroll
      for (int e = 0; e < 2; ++e) {
        a2p[e][2 * ho] = (v2f){Pv.x, Pv.y};
        a2p[e][2 * ho + 1] = (v2f){Pv.z, Pv.w};
      }
    }
  }

  // K chunks: stage Wl2 + e-chunk, then pure MAC phase (ascending c)
  for (int kc = 0; kc < 64; kc += 16) {
#pragma unroll
    for (int ho = 0; ho < OH; ++ho) {
      const int o = t >> 2;
      const int cq = t & 3;
      const float4 wv = *(const float4*)&w[(ho * 64 + o) * 128 + 64 + kc + 4 * cq];
      Wl2[(4 * cq + 0) * WS + ho * 64 + o] = wv.x;
      Wl2[(4 * cq + 1) * WS + ho * 64 + o] = wv.y;
      Wl2[(4 * cq + 2) * WS + ho * 64 + o] = wv.z;
      Wl2[(4 * cq + 3) * WS + ho * 64 + o] = wv.w;
    }
#pragma unroll
    for (int q = 0; q < 3; ++q) {
      const int sl = 64 * q + (t >> 2);
      const int cq = t & 3;
      if (sl < 160) {
        const int p = sl / 20;
        const int j = jl[sl];
        const float4 xj = *(const float4*)&cat[(bN + j) * 320 + inoff + kc + 4 * cq];
        const float4 xv = *(const float4*)&xis[p][kc + 4 * cq];
        U[(4 * cq + 0) * EST + sl] = subrn(xj.x, xv.x);
        U[(4 * cq + 1) * EST + sl] = subrn(xj.y, xv.y);
        U[(4 * cq + 2) * EST + sl] = subrn(xj.z, xv.z);
        U[(4 * cq + 3) * EST + sl] = subrn(xj.w, xv.w);
      }
    }
    __syncthreads();
#pragma unroll
    for (int k = 0; k < 16; ++k) {
      // e-fragments as aligned v2f pairs (edge pairs {4g,4g+1} / {4g+2,4g+3})
      const v2f e0lo = *(const v2f*)&U[k * EST + 4 * g];
      const v2f e0hi = *(const v2f*)&U[k * EST + 4 * g + 2];
      const v2f e1lo = *(const v2f*)&U[k * EST + 64 + 4 * g];
      const v2f e1hi = *(const v2f*)&U[k * EST + 64 + 4 * g + 2];
      const v2f e2 = *(const v2f*)&U[k * EST + 128 + 2 * g];
#pragma unroll
      for (int ho = 0; ho < OH; ++ho) {
        const v2f w01 = *(const v2f*)&Wl2[k * WS + ho * 64 + 4 * h];
        const v2f w23 = *(const v2f*)&Wl2[k * WS + ho * 64 + 4 * h + 2];
        // i=0: edges 4g..4g+3 -> lo/hi broadcasts of e0lo, e0hi
        pkmac_lo(a4[0][0][2 * ho], w01, e0lo);
        pkmac_lo(a4[0][0][2 * ho + 1], w23, e0lo);
        pkmac_hi(a4[0][1][2 * ho], w01, e0lo);
        pkmac_hi(a4[0][1][2 * ho + 1], w23, e0lo);
        pkmac_lo(a4[0][2][2 * ho], w01, e0hi);
        pkmac_lo(a4[0][2][2 * ho + 1], w23, e0hi);
        pkmac_hi(a4[0][3][2 * ho], w01, e0hi);
        pkmac_hi(a4[0][3][2 * ho + 1], w23, e0hi);
        // i=1: edges 64+4g..64+4g+3
        pkmac_lo(a4[1][0][2 * ho], w01, e1lo);
        pkmac_lo(a4[1][0][2 * ho + 1], w23, e1lo);
        pkmac_hi(a4[1][1][2 * ho], w01, e1lo);
        pkmac_hi(a4[1][1][2 * ho + 1], w23, e1lo);
        pkmac_lo(a4[1][2][2 * ho], w01, e1hi);
        pkmac_lo(a4[1][2][2 * ho + 1], w23, e1hi);
        pkmac_hi(a4[1][3][2 * ho], w01, e1hi);
        pkmac_hi(a4[1][3][2 * ho + 1], w23, e1hi);
        // i=2: edges 128+2g, 128+2g+1
        pkmac_lo(a2p[0][2 * ho], w01, e2);
        pkmac_lo(a2p[0][2 * ho + 1], w23, e2);
        pkmac_hi(a2p[1][2 * ho], w01, e2);
        pkmac_hi(a2p[1][2 * ho + 1], w23, e2);
      }
    }
    __syncthreads();  // U readers done before restage / gmax
  }

  // epilogue per half: relu(s*acc+b) per edge, pair-max rows, point reduce
#pragma unroll
  for (int ho = 0; ho < OH; ++ho) {
    const float4 sv = *(const float4*)&s[ho * 64 + 4 * h];
    const float4 bv = *(const float4*)&bi[ho * 64 + 4 * h];
    const float sc[4] = {sv.x, sv.y, sv.z, sv.w};
    const float bc[4] = {bv.x, bv.y, bv.z, bv.w};
#pragma unroll
    for (int i = 0; i < 2; ++i) {
#pragma unroll
      for (int ep = 0; ep < 2; ++ep) {
        const int row = 32 * i + 2 * g + ep;
        float gm[4] = {0.f, 0.f, 0.f, 0.f};
#pragma unroll
        for (int ee = 0; ee < 2; ++ee) {
          const int e = 2 * ep + ee;
#pragma unroll
          for (int u = 0; u < 4; ++u) {
            const v2f a = a4[i][e][2 * ho + (u >> 1)];
            const float av = (u & 1) ? a.y : a.x;
            gm[u] = fmaxf(gm[u], fmaxf(addrn(mulrn(sc[u], av), bc[u]), 0.f));
          }
        }
        *(float4*)&U[row * RS + 4 * h] = make_float4(gm[0], gm[1], gm[2], gm[3]);
      }
    }
    {
      const int row = 64 + g;
      float gm[4] = {0.f, 0.f, 0.f, 0.f};
#pragma unroll
      for (int e = 0; e < 2; ++e) {
#pragma unroll
        for (int u = 0; u < 4; ++u) {
          const v2f a = a2p[e][2 * ho + (u >> 1)];
          const float av = (u & 1) ? a.y : a.x;
          gm[u] = fmaxf(gm[u], fmaxf(addrn(mulrn(sc[u], av), bc[u]), 0.f));
        }
      }
      *(float4*)&U[row * RS + 4 * h] = make_float4(gm[0], gm[1], gm[2], gm[3]);
    }
    __syncthreads();
#pragma unroll
    for (int q = 0; q < 2; ++q) {
      const int o = t & 63;
      const int p = (t >> 6) + 4 * q;
      const float* ur = &U[(10 * p) * RS + o];
      float m = ur[0];
#pragma unroll
      for (int r = 1; r < 10; ++r) m = fmaxf(m, ur[r * RS]);
      catout[(bN + n0 + p) * 320 + outoff + ho * 64 + o] = m;
    }
    if (ho + 1 < OH) __syncthreads();  // pass 2 rewrites U
  }
}

// ---------------------------------------------------------------------------
// Local layer: loc[o][n] = relu(s*<W[o,:],cat[n,:]>+b), serial ascending c.
// KC=16, DOUBLE-BUFFERED LDS (1 barrier/chunk; stage-write overlapped after
// MAC) + fused-asm packed MACs (tied acc, op_sel broadcast) + direct v2f LDS
// loads at pm-unswizzled offsets. Grid transposed (ptile fastest) so the 8
// q-tile readers of each cat ptile land on the same XCD L2.
// ---------------------------------------------------------------------------
__global__ __launch_bounds__(256) void local_gemm(
    const float* __restrict__ cat, const float* __restrict__ w,
    const float* __restrict__ s, const float* __restrict__ bi,
    float* __restrict__ pval, int* __restrict__ pidx) {
  constexpr int KC = 16;
  constexpr int XS = 132;
  constexpr int BUF = KC * XS * 2;     // floats per buffer (xs + wsd)
  __shared__ float smem[2 * BUF];      // 33,792 B (double-buffered)
  const int t = threadIdx.x;
  const int q0 = blockIdx.y * 128;     // transposed grid: y = q-tile
  const int ptile = blockIdx.x;        //                  x = point tile
  const size_t pt0 = (size_t)ptile * 128;
  const int g = t & 15;
  const int h = t >> 4;
  v2f acc2[2][2][4][2];
#pragma unroll
  for (int ep = 0; ep < 2; ++ep)
#pragma unroll
    for (int fp = 0; fp < 2; ++fp)
#pragma unroll
      for (int pi = 0; pi < 4; ++pi)
#pragma unroll
        for (int u = 0; u < 2; ++u) acc2[ep][fp][pi][u] = (v2f){0.f, 0.f};

  const int lk = t & 15;               // k-row within chunk
  const int lp = t >> 4;               // column group 0..15
  const int px = ((lk >> 3) & 1) << 1;  // store swizzle: 0 or 2
  const float* catp = cat + pt0 * 320 + lk;
  const float* wp = w + (size_t)q0 * 320 + lk;
  float rx[8], rw[8];
#pragma unroll
  for (int i = 0; i < 8; ++i) rx[i] = catp[(size_t)(lp + 16 * i) * 320];
#pragma unroll
  for (int i = 0; i < 8; ++i) rw[i] = wp[(size_t)(lp + 16 * i) * 320];
  // prologue: stage chunk 0 into buffer 0
  {
    float* xs0 = smem;
    float* ws0 = smem + KC * XS;
#pragma unroll
    for (int i = 0; i < 8; ++i) xs0[lk * XS + ((lp + 16 * i) ^ px)] = rx[i];
#pragma unroll
    for (int i = 0; i < 8; ++i) ws0[lk * XS + ((lp + 16 * i) ^ px)] = rw[i];
  }

#pragma unroll 2
  for (int ch = 0; ch < 20; ++ch) {
    const int par = ch & 1;
    const float* xsr = smem + par * BUF;
    const float* wsr = xsr + KC * XS;
    if (ch + 1 < 20) {  // issue next-chunk global loads (land during MAC)
      const int ko = (ch + 1) * KC;
#pragma unroll
      for (int i = 0; i < 8; ++i) rx[i] = catp[(size_t)(lp + 16 * i) * 320 + ko];
#pragma unroll
      for (int i = 0; i < 8; ++i) rw[i] = wp[(size_t)(lp + 16 * i) * 320 + ko];
    }
    __syncthreads();  // buf[par] writes (prev iter / prologue) visible
#pragma unroll
    for (int k = 0; k < KC; ++k) {
      const int pm2 = ((k >> 3) & 1) << 1;  // 0 or 2, compile-time under unroll
      const float* wrow = &wsr[k * XS];
      const float* xrow = &xsr[k * XS];
      // logical pairs at pm-unswizzled physical offsets (aligned v2f loads)
      v2f wA[2], wB[2];  // wA -> acc u=0 (logical cols 4h,4h+1), wB -> u=1
#pragma unroll
      for (int fp = 0; fp < 2; ++fp) {
        wA[fp] = *(const v2f*)&wrow[64 * fp + 4 * h + pm2];
        wB[fp] = *(const v2f*)&wrow[64 * fp + 4 * h + (2 - pm2)];
      }
#pragma unroll
      for (int ep = 0; ep < 2; ++ep) {
        const v2f xq0 = *(const v2f*)&xrow[64 * ep + 4 * g + pm2];        // pts 0,1
        const v2f xq1 = *(const v2f*)&xrow[64 * ep + 4 * g + (2 - pm2)];  // pts 2,3
#pragma unroll
        for (int fp = 0; fp < 2; ++fp) {
          pkmac_lo(acc2[ep][fp][0][0], wA[fp], xq0);
          pkmac_lo(acc2[ep][fp][0][1], wB[fp], xq0);
          pkmac_hi(acc2[ep][fp][1][0], wA[fp], xq0);
          pkmac_hi(acc2[ep][fp][1][1], wB[fp], xq0);
          pkmac_lo(acc2[ep][fp][2][0], wA[fp], xq1);
          pkmac_lo(acc2[ep][fp][2][1], wB[fp], xq1);
          pkmac_hi(acc2[ep][fp][3][0], wA[fp], xq1);
          pkmac_hi(acc2[ep][fp][3][1], wB[fp], xq1);
        }
      }
    }
    if (ch + 1 < 20) {  // stage next chunk into the other buffer (no barrier:
      float* xsw = smem + (par ^ 1) * BUF;  // readers of buf[par^1] finished
      float* wsw = xsw + KC * XS;           // before barrier at top of ch)
#pragma unroll
      for (int i = 0; i < 8; ++i) xsw[lk * XS + ((lp + 16 * i) ^ px)] = rx[i];
#pragma unroll
      for (int i = 0; i < 8; ++i) wsw[lk * XS + ((lp + 16 * i) ^ px)] = rw[i];
    }
  }
  // epilogue: relu(s*acc+b), per-thread argmax over 8 points ascending
  const int bb = ptile >> 5;
  const int blk = ptile & 31;
  float mv[8];
  int mi[8];
#pragma unroll
  for (int fp = 0; fp < 2; ++fp)
#pragma unroll
    for (int c = 0; c < 4; ++c) {
      const int f = fp * 4 + c;
      const int cl = 64 * fp + 4 * h + c;
      const float sc = s[q0 + cl];
      const float bc = bi[q0 + cl];
      mv[f] = -1.f;
      mi[f] = 0;
#pragma unroll
      for (int ep = 0; ep < 2; ++ep)
#pragma unroll
        for (int pi = 0; pi < 4; ++pi) {
          const v2f a2 = acc2[ep][fp][pi][c >> 1];
          const float a = (c & 1) ? a2.y : a2.x;
          const float v = fmaxf(addrn(mulrn(sc, a), bc), 0.f);
          if (v > mv[f]) { mv[f] = v; mi[f] = 64 * ep + 4 * g + pi; }
        }
    }
  __syncthreads();
  float* smv = smem;                       // 2112 floats
  int* smi = (int*)(smem + 16 * 132);      // next 2112 ints
#pragma unroll
  for (int fp = 0; fp < 2; ++fp)
#pragma unroll
    for (int c = 0; c < 4; ++c) {
      const int cl = 64 * fp + 4 * h + c;
      smv[g * 132 + cl] = mv[fp * 4 + c];
      smi[g * 132 + cl] = mi[fp * 4 + c];
    }
  __syncthreads();
  if (t < 128) {
    float best = smv[t];
    int bidx = smi[t];
    for (int gg = 1; gg < 16; ++gg) {
      const float v = smv[gg * 132 + t];
      const int vi = smi[gg * 132 + t];
      // candidates g-interleaved: ties resolve to SMALLEST point idx
      if (v > best || (v == best && vi < bidx)) { best = v; bidx = vi; }
    }
    const int n_l = blk * 128 + bidx;
    const size_t po = ((size_t)bb * 1024 + q0 + t) * 32 + blk;
    pval[po] = best;
    pidx[po] = n_l;
  }
}

__global__ __launch_bounds__(256) void final_reduce(
    const float* __restrict__ pval, const int* __restrict__ pidx,
    float* __restrict__ glob, float* __restrict__ oidx) {
  const int o = blockIdx.x * 256 + threadIdx.x;  // 8192 = B*1024
  const float* pv = pval + (size_t)o * 32;
  const int* pi = pidx + (size_t)o * 32;
  float best = pv[0];
  int bi = pi[0];
  for (int k = 1; k < 32; ++k) {
    const float v = pv[k];
    // tiles are ascending disjoint point ranges: strict > = first occurrence
    if (v > best) { best = v; bi = pi[k]; }
  }
  glob[o] = best;
  oidx[o] = (float)bi;
}

template <int KIN, int OUTS>
__global__ __launch_bounds__(256) void dense_wave(
    const float* __restrict__ in, const float* __restrict__ w,
    const float* __restrict__ s, const float* __restrict__ bi,
    float* __restrict__ out) {
  const int wid = (blockIdx.x * 256 + threadIdx.x) >> 6;
  const int lane = threadIdx.x & 63;
  const int b = wid / OUTS;
  const int o = wid % OUTS;
  const float* ip = in + (size_t)b * KIN;
  const float* wr = w + (size_t)o * KIN;
  float acc = 0.f;
  for (int k = lane; k < KIN; k += 64) acc = fmaf(wr[k], ip[k], acc);
#pragma unroll
  for (int off = 32; off; off >>= 1) acc += __shfl_down(acc, off);
  if (lane == 0) out[(size_t)b * OUTS + o] = fmaxf(fmaf(s[o], acc, bi[o]), 0.f);
}

extern "C" void kernel_launch(void* const* d_in, const int* in_sizes, int n_in,
                              void* d_out, int out_size, void* d_ws, size_t ws_size,
                              hipStream_t stream) {
  (void)in_sizes; (void)n_in; (void)out_size; (void)ws_size;
  const float* pts = (const float*)d_in[0];
  const float* ec_w[4] = {(const float*)d_in[1], (const float*)d_in[4],
                          (const float*)d_in[7], (const float*)d_in[10]};
  const float* ec_s[4] = {(const float*)d_in[2], (const float*)d_in[5],
                          (const float*)d_in[8], (const float*)d_in[11]};
  const float* ec_b[4] = {(const float*)d_in[3], (const float*)d_in[6],
                          (const float*)d_in[9], (const float*)d_in[12]};
  const float* local_w = (const float*)d_in[13];
  const float* local_s = (const float*)d_in[14];
  const float* local_b = (const float*)d_in[15];
  const float* g_w0 = (const float*)d_in[16];
  const float* g_s0 = (const float*)d_in[17];
  const float* g_b0 = (const float*)d_in[18];
  const float* g_w1 = (const float*)d_in[19];
  const float* g_s1 = (const float*)d_in[20];
  const float* g_b1 = (const float*)d_in[21];

  char* ws = (char*)d_ws;
  int* idxbuf = (int*)(ws + OFF_IDX);
  float* cat = (float*)(ws + OFF_CAT);
  float* pv = (float*)(ws + OFF_PV);
  int* pi = (int*)(ws + OFF_PI);
  float* glob = (float*)(ws + OFF_GLOB);
  float* hbuf = (float*)(ws + OFF_H);
  float* listd = (float*)(ws + OFF_LD);
  int* listj = (int*)(ws + OFF_LJ);
  int* counts = (int*)(ws + OFF_CNT);
  float* outv = (float*)d_out;   // [8][256]  fp32
  float* oidx = outv + 2048;     // [8][1024] fp32 (indices as floats)

  knn_scan<<<dim3(32, 2, 8), 256, 0, stream>>>(pts, listd, listj, counts);
  knn_merge<<<dim3(512), 64, 0, stream>>>(listd, listj, counts, idxbuf);

  // layer 1 (3 -> 64)
  ec_layer1<<<dim3(1024, 8), 256, 0, stream>>>(pts, idxbuf, ec_w[0], ec_s[0], ec_b[0], cat);
  // layer 2 (64 -> 64)
  ec_edge<1><<<dim3(512, 8), 256, 0, stream>>>(cat, 0, idxbuf, ec_w[1], ec_s[1], ec_b[1], cat, 64);
  // layer 3 (64 -> 64)
  ec_edge<1><<<dim3(512, 8), 256, 0, stream>>>(cat, 64, idxbuf, ec_w[2], ec_s[2], ec_b[2], cat, 128);
  // layer 4 (64 -> 128), fused both output halves, e staged once
  ec_edge<2><<<dim3(512, 8), 256, 0, stream>>>(cat, 128, idxbuf, ec_w[3], ec_s[3], ec_b[3], cat, 192);

  // transposed grid: ptile fastest -> same-ptile q-tiles co-located per XCD
  local_gemm<<<dim3(256, 8), 256, 0, stream>>>(cat, local_w, local_s, local_b, pv, pi);
  final_reduce<<<dim3(32), 256, 0, stream>>>(pv, pi, glob, oidx);
  dense_wave<1024, 512><<<dim3(1024), 256, 0, stream>>>(glob, g_w0, g_s0, g_b0, hbuf);
  dense_wave<512, 256><<<dim3(512), 256, 0, stream>>>(hbuf, g_w1, g_s1, g_b1, outv);
}

// Round 8
// 1314.201 us; speedup vs baseline: 1.0583x; 1.0321x over previous
//
#include <hip/hip_runtime.h>
#include <hip/hip_bf16.h>

namespace {
constexpr int B = 8;
constexpr int N = 4096;
constexpr int KNN = 20;
constexpr int NSEG = 4;
constexpr int SEGLEN = N / NSEG;   // 1024
constexpr int HSEG = SEGLEN / 2;   // 512: half-segment per thread
constexpr int CAP = 24;
constexpr int SLOTS = NSEG * CAP;  // 96

// workspace layout (bytes)
constexpr size_t OFF_IDX  = 0;                          // int [B][N][KNN]
constexpr size_t SZ_IDX   = (size_t)B * N * KNN * 4;
constexpr size_t OFF_T    = OFF_IDX + SZ_IDX;           // knn scratch region
constexpr size_t SZ_T     = (size_t)B * N * 128 * 4;
constexpr size_t OFF_CAT  = OFF_T + SZ_T;               // float [B][N][320]
constexpr size_t SZ_CAT   = (size_t)B * N * 320 * 4;
constexpr size_t OFF_PV   = OFF_CAT + SZ_CAT;           // float [B][1024][32]
constexpr size_t SZ_PV    = (size_t)B * 1024 * 32 * 4;
constexpr size_t OFF_PI   = OFF_PV + SZ_PV;             // int   [B][1024][32]
constexpr size_t OFF_GLOB = OFF_PI + SZ_PV;             // float [B][1024]
constexpr size_t OFF_H    = OFF_GLOB + (size_t)B * 1024 * 4;  // float [B][512]
// knn scratch overlaid on T + head of CAT (dead once merge completes):
constexpr size_t OFF_LD   = OFF_T;                      // float [B*N][SLOTS]
constexpr size_t SZ_LD    = (size_t)B * N * SLOTS * 4;
constexpr size_t OFF_LJ   = OFF_LD + SZ_LD;             // int   [B*N][SLOTS]
constexpr size_t OFF_CNT  = OFF_LJ + SZ_LD;             // int   [B*N][NSEG]
}  // namespace

typedef float v2f __attribute__((ext_vector_type(2)));

// Non-contractable fp32 ops: bit-exact match to np's mul-then-add serial loops.
__device__ __forceinline__ float mulrn(float a, float b) {
#pragma clang fp contract(off)
  return a * b;
}
__device__ __forceinline__ float addrn(float a, float b) {
#pragma clang fp contract(off)
  return a + b;
}
__device__ __forceinline__ float subrn(float a, float b) {
#pragma clang fp contract(off)
  return a - b;
}
// Packed (v_pk_mul_f32 / v_pk_add_f32): per-element IEEE rn == scalar ops.
__device__ __forceinline__ v2f mulrn2(v2f a, v2f b) {
#pragma clang fp contract(off)
  return a * b;
}
__device__ __forceinline__ v2f addrn2(v2f a, v2f b) {
#pragma clang fp contract(off)
  return a + b;
}

// Fused packed MAC, VOP3P with op_sel broadcast of the x-half (semantics
// hardware-validated: per-element IEEE rn mul + rn add, same as scalar).
// acc tied "+v" (no result copy), scratch early-clobber, inputs are aligned
// v2f pairs loaded directly from LDS (no repack movs).
__device__ __forceinline__ void pkmac_lo(v2f& acc, v2f w, v2f x) {
  v2f t;
  asm("v_pk_mul_f32 %1, %2, %3 op_sel:[0,0] op_sel_hi:[1,0]\n\t"
      "v_pk_add_f32 %0, %0, %1"
      : "+v"(acc), "=&v"(t) : "v"(w), "v"(x));
}
__device__ __forceinline__ void pkmac_hi(v2f& acc, v2f w, v2f x) {
  v2f t;
  asm("v_pk_mul_f32 %1, %2, %3 op_sel:[0,1] op_sel_hi:[1,1]\n\t"
      "v_pk_add_f32 %0, %0, %1"
      : "+v"(acc), "=&v"(t) : "v"(w), "v"(x));
}

// ---------------------------------------------------------------------------
// kNN, half-segment split for occupancy: wave = (seg_local, row-group); within
// the wave lanes l / l^32 scan the two 512-candidate halves of the same
// (2 rows, seg). 2048 waves total (2/SIMD) vs 1024 before. Sorted-20 bubble
// per (row, half); exact segment 20th = Batcher merge of the two sorted
// half-lists: theta = max_i min(a_i, b_{19-i}) with b via shfl_xor(.,32)
// (pure selection -> bit-identical to single-scan da[19]). Recovery appends
// front (half 0) / back (half 1) into the shared CAP-slot region; slot order
// is irrelevant (merge selects by (d,j) lex keys). counts = front | back<<16.
// ---------------------------------------------------------------------------
__global__ __launch_bounds__(256) void knn_scan(
    const float* __restrict__ pts,
    float* __restrict__ listd, int* __restrict__ listj, int* __restrict__ counts) {
  __shared__ float4 sp[2 * SEGLEN];  // 32 KB: (x, y, z, sq) for 2 segments
  const int b = blockIdx.z;
  const int tid = threadIdx.x;
  const float* px = pts + (size_t)b * 3 * N;
  const int cb0 = blockIdx.y * 2 * SEGLEN;  // candidate base (2 segs/block)
  for (int i = tid; i < 2 * SEGLEN; i += 256) {
    const float x = px[cb0 + i];
    const float y = px[N + cb0 + i];
    const float z = px[2 * N + cb0 + i];
    const float sq = addrn(addrn(mulrn(x, x), mulrn(y, y)), mulrn(z, z));
    sp[i] = make_float4(x, y, z, sq);
  }
  __syncthreads();
  const int lane = tid & 63;
  const int rl = lane & 31;            // row lane
  const int h2 = lane >> 5;            // half of the segment
  const int segl = (tid >> 6) & 1;     // segment within the block's pair
  const int rg = tid >> 7;             // row group
  const int seg = blockIdx.y * 2 + segl;
  const int row0 = blockIdx.x * 128 + rg * 64 + rl;
  const int row1 = row0 + 32;
  // queries from global (identical arithmetic to staging -> bit-same sq)
  const float ax = px[row0], ay = px[N + row0], az = px[2 * N + row0];
  const float bx = px[row1], by = px[N + row1], bz = px[2 * N + row1];
  const float4 qa = make_float4(ax, ay, az,
      addrn(addrn(mulrn(ax, ax), mulrn(ay, ay)), mulrn(az, az)));
  const float4 qb = make_float4(bx, by, bz,
      addrn(addrn(mulrn(bx, bx), mulrn(by, by)), mulrn(bz, bz)));
  float da[KNN], db[KNN];
#pragma unroll
  for (int t = 0; t < KNN; ++t) { da[t] = 3.0e38f; db[t] = 3.0e38f; }
  const int j0 = segl * SEGLEN + h2 * HSEG;  // LDS-local candidate base
#pragma unroll 2
  for (int jj = 0; jj < HSEG; ++jj) {
    const float4 c = sp[j0 + jj];
    v2f t0 = mulrn2((v2f){qa.x, qb.x}, (v2f){c.x, c.x});
    t0 = addrn2(t0, mulrn2((v2f){qa.y, qb.y}, (v2f){c.y, c.y}));
    t0 = addrn2(t0, mulrn2((v2f){qa.z, qb.z}, (v2f){c.z, c.z}));
    v2f d2 = addrn2((v2f){qa.w, qb.w}, (v2f){c.w, c.w});
    d2 = d2 - mulrn2((v2f){2.0f, 2.0f}, t0);
    if (d2.x < da[KNN - 1]) {
      float cur = d2.x;
#pragma unroll
      for (int t = 0; t < KNN; ++t) {
        const float lo = fminf(cur, da[t]);
        cur = fmaxf(cur, da[t]);
        da[t] = lo;
      }
    }
    if (d2.y < db[KNN - 1]) {
      float cur = d2.y;
#pragma unroll
      for (int t = 0; t < KNN; ++t) {
        const float lo = fminf(cur, db[t]);
        cur = fmaxf(cur, db[t]);
        db[t] = lo;
      }
    }
  }
  // exact segment 20th via bitonic cross-half merge (partner = lane ^ 32);
  // pure min/max selection over the same multiset -> both lanes get the same
  // bit pattern, equal to the single-scan 20th.
  float tha = -3.0e38f, thb = -3.0e38f;
#pragma unroll
  for (int i = 0; i < KNN; ++i) {
    tha = fmaxf(tha, fminf(da[i], __shfl_xor(da[KNN - 1 - i], 32)));
    thb = fmaxf(thb, fminf(db[i], __shfl_xor(db[KNN - 1 - i], 32)));
  }
  float* lda = listd + (size_t)(b * N + row0) * SLOTS + seg * CAP;
  int* lja = listj + (size_t)(b * N + row0) * SLOTS + seg * CAP;
  float* ldb = listd + (size_t)(b * N + row1) * SLOTS + seg * CAP;
  int* ljb = listj + (size_t)(b * N + row1) * SLOTS + seg * CAP;
  const int jg0 = cb0 + j0;  // global candidate index base
  int ca = 0, cb = 0;
#pragma unroll 2
  for (int jj = 0; jj < HSEG; ++jj) {
    const float4 c = sp[j0 + jj];
    v2f t0 = mulrn2((v2f){qa.x, qb.x}, (v2f){c.x, c.x});
    t0 = addrn2(t0, mulrn2((v2f){qa.y, qb.y}, (v2f){c.y, c.y}));
    t0 = addrn2(t0, mulrn2((v2f){qa.z, qb.z}, (v2f){c.z, c.z}));
    v2f d2 = addrn2((v2f){qa.w, qb.w}, (v2f){c.w, c.w});
    d2 = d2 - mulrn2((v2f){2.0f, 2.0f}, t0);
    if (d2.x <= tha && ca < CAP) {
      const int sl = h2 ? (CAP - 1 - ca) : ca;
      lda[sl] = d2.x; lja[sl] = jg0 + jj; ++ca;
    }
    if (d2.y <= thb && cb < CAP) {
      const int sl = h2 ? (CAP - 1 - cb) : cb;
      ldb[sl] = d2.y; ljb[sl] = jg0 + jj; ++cb;
    }
  }
  const int oa = __shfl_xor(ca, 32);
  const int ob = __shfl_xor(cb, 32);
  if (h2 == 0) {  // pack: front count | back count << 16
    counts[(b * N + row0) * NSEG + seg] = ca | (oa << 16);
    counts[(b * N + row1) * NSEG + seg] = cb | (ob << 16);
  }
}

// Merge: per row, select 20 lexicographically-smallest (dist, j) from <=96
// candidates via monotone uint64 keys. counts packed front|back<<16; valid
// slots are [0, front) u [CAP-back, CAP).
// 4-thread-per-row cooperative selection: threads 4rr..4rr+3 (same wave) each
// scan a 24-slot strip; global min via 2x shfl_xor u64-min (associative, keys
// unique -> identical selection sequence to the serial scan); unique owner
// marks its slot (in-wave DS program order makes the mark visible to the next
// iteration without barriers). 256-thread blocks: 2 waves/SIMD vs 0.5 before.
__global__ __launch_bounds__(256) void knn_merge(
    const float* __restrict__ listd, const int* __restrict__ listj,
    const int* __restrict__ counts, int* __restrict__ idxout) {
  __shared__ unsigned long long keys[64][SLOTS + 1];  // 49,664 B
  const int r0 = blockIdx.x * 64;
  const int t = threadIdx.x;
  for (int i = t; i < 64 * SLOTS; i += 256) {
    const int rr = i / SLOTS;
    const int sl = i % SLOTS;
    const int seg = sl / CAP;
    const int e = sl % CAP;
    const int row = r0 + rr;
    unsigned long long key = 0xFFFFFFFE00000000ULL | (unsigned)row;  // fallback: self
    const int cp = counts[row * NSEG + seg];
    if (e < (cp & 0xFFFF) || e >= CAP - (cp >> 16)) {
      const float d = listd[(size_t)row * SLOTS + sl];
      unsigned ub = __float_as_uint(d);
      ub ^= (ub & 0x80000000u) ? 0xFFFFFFFFu : 0x80000000u;
      key = ((unsigned long long)ub << 32) | (unsigned)listj[(size_t)row * SLOTS + sl];
    }
    keys[rr][sl] = key;
  }
  __syncthreads();
  const int g4 = t & 3;        // strip within row
  const int rr = t >> 2;       // row slot 0..63
  const int sbase = g4 * 24;   // 4 strips x 24 = 96 slots
  int* outp = idxout + (size_t)(r0 + rr) * KNN;
  for (int sel = 0; sel < KNN; ++sel) {
    unsigned long long best = ~0ULL;
    int bs = sbase;
#pragma unroll
    for (int e = 0; e < 24; ++e) {
      const unsigned long long k2 = keys[rr][sbase + e];
      if (k2 < best) { best = k2; bs = sbase + e; }
    }
    unsigned long long m = best;
    {
      const unsigned long long o1 = __shfl_xor(m, 1);
      m = (o1 < m) ? o1 : m;
      const unsigned long long o2 = __shfl_xor(m, 2);
      m = (o2 < m) ? o2 : m;
    }
    if (best == m) keys[rr][bs] = ~0ULL;  // keys unique -> single owner
    if (g4 == 0) outp[sel] = (int)(m & 0xFFFFFFFFu);
  }
}

// ---------------------------------------------------------------------------
// EdgeConv, BIT-EXACT serial semantics per (o, n, k):
//   y = sum_c W1[o,c]*x_i[c]  (prefix P)  then  += W2[o,c]*(x_j[c]-x_i[c]).
// ---------------------------------------------------------------------------

// Layer 1 (cin=3): wave per point, lane = output o.
__global__ __launch_bounds__(256) void ec_layer1(
    const float* __restrict__ pts, const int* __restrict__ idx,
    const float* __restrict__ w, const float* __restrict__ s,
    const float* __restrict__ bi, float* __restrict__ cat) {
  const int b = blockIdx.y;
  const int n = blockIdx.x * 4 + (threadIdx.x >> 6);
  const int o = threadIdx.x & 63;
  const float* p = pts + (size_t)b * 3 * N;
  const float xix = p[n], xiy = p[N + n], xiz = p[2 * N + n];
  const float* wr = w + o * 6;
  const float w0 = wr[0], w1 = wr[1], w2 = wr[2], w3 = wr[3], w4 = wr[4], w5 = wr[5];
  float P = mulrn(w0, xix);
  P = addrn(P, mulrn(w1, xiy));
  P = addrn(P, mulrn(w2, xiz));
  const float so = s[o], bo = bi[o];
  const int* ip = idx + ((size_t)b * N + n) * KNN;
  float m = 0.0f;
#pragma unroll 4
  for (int k = 0; k < KNN; ++k) {
    int j = ip[k];
    if ((unsigned)j >= (unsigned)N) j = n;
    const float ex = subrn(p[j], xix);
    const float ey = subrn(p[N + j], xiy);
    const float ez = subrn(p[2 * N + j], xiz);
    float acc = addrn(P, mulrn(w3, ex));
    acc = addrn(acc, mulrn(w4, ey));
    acc = addrn(acc, mulrn(w5, ez));
    m = fmaxf(m, addrn(mulrn(so, acc), bo));
  }
  cat[((size_t)b * N + n) * 320 + o] = m;
}

// 64-in EdgeConv as edge-GEMM: 8 points x 20 slots = 160 edges (no dups),
// OH output halves (1 -> 64 outs; 2 -> fused 128 outs, e staged ONCE).
// Edge frags: i=0,1 quads (edge=64i+4g+e) + i=2 pairs (edge=128+2g+e).
// MAC loop: fused-asm pkmac with op_sel broadcast; e-frags and W read as
// aligned v2f pairs (no broadcast-construction movs). Per-accumulator op
// order unchanged (ascending kc, k; mul-then-add) -> bit-exact.
// gmax epilogue at pair granularity: row = edge>>1 (80 rows), point p owns
// rows 10p..10p+9.
template <int OH>
__global__ __launch_bounds__(256) void ec_edge(
    const float* __restrict__ cat, int inoff, const int* __restrict__ idx,
    const float* __restrict__ w, const float* __restrict__ s,
    const float* __restrict__ bi, float* __restrict__ catout, int outoff) {
  constexpr int EST = 164;         // e-chunk row stride
  constexpr int RS = 68;           // gmax row stride
  constexpr int PS = 64 * OH + 4;  // Pt row stride
  constexpr int WS = 64 * OH + 4;  // Wl2 row stride
  __shared__ float U[80 * RS];     // 21.76 KB multi-purpose (W1 / e-chunk / gmax)
  __shared__ float xis[8][64];     // 2 KB
  __shared__ float Pt[8 * PS];
  __shared__ float Wl2[16 * WS];
  __shared__ int jl[160];
  const int t = threadIdx.x;
  const int b = blockIdx.y;
  const int n0 = blockIdx.x * 8;
  const size_t bN = (size_t)b * N;

  // stage xis + jl
#pragma unroll
  for (int q = 0; q < 2; ++q) {
    const int p = (t >> 6) + 4 * q;
    const int c = t & 63;
    xis[p][c] = cat[(bN + n0 + p) * 320 + inoff + c];
  }
  if (t < 160) {
    const int p = t / 20;
    const int k = t % 20;
    int j = idx[(bN + n0 + p) * KNN + k];
    if ((unsigned)j >= (unsigned)N) j = n0 + p;  // firewall
    jl[t] = j;
  }
  __syncthreads();

  // prefix P per output-half (W1 staged through U, stride 66 -> float2 reads)
#pragma unroll
  for (int ho = 0; ho < OH; ++ho) {
#pragma unroll
    for (int q = 0; q < 16; ++q) {
      const int l = t + 256 * q;
      U[(l >> 6) * 66 + (l & 63)] = w[(ho * 64 + (l >> 6)) * 128 + (l & 63)];
    }
    __syncthreads();
    {
      const int o = t & 63;
      const int p0 = t >> 6;
      const float2* wq = (const float2*)&U[o * 66];
      const float2* x0 = (const float2*)&xis[p0][0];
      const float2* x1 = (const float2*)&xis[p0 + 4][0];
      float2 wv = wq[0];
      float2 a0 = x0[0];
      float2 a1 = x1[0];
      float P0 = mulrn(wv.x, a0.x);
      float P1 = mulrn(wv.x, a1.x);
      P0 = addrn(P0, mulrn(wv.y, a0.y));
      P1 = addrn(P1, mulrn(wv.y, a1.y));
#pragma unroll
      for (int c2 = 1; c2 < 32; ++c2) {
        wv = wq[c2];
        a0 = x0[c2];
        a1 = x1[c2];
        P0 = addrn(P0, mulrn(wv.x, a0.x));
        P1 = addrn(P1, mulrn(wv.x, a1.x));
        P0 = addrn(P0, mulrn(wv.y, a0.y));
        P1 = addrn(P1, mulrn(wv.y, a1.y));
      }
      Pt[p0 * PS + ho * 64 + o] = P0;
      Pt[(p0 + 4) * PS + ho * 64 + o] = P1;
    }
    __syncthreads();
  }

  const int g = t & 15;  // edge-frag lane
  const int h = t >> 4;  // output-frag lane: outputs 64*ho + 4h + u
  v2f a4[2][4][2 * OH];  // quad frags (i=0,1)
  v2f a2p[2][2 * OH];    // pair frag (i=2)
#pragma unroll
  for (int i = 0; i < 2; ++i) {
    const int p = (64 * i + 4 * g) / 20;
#pragma unroll
    for (int ho = 0; ho < OH; ++ho) {
      const float4 Pv = *(const float4*)&Pt[p * PS + ho * 64 + 4 * h];
#pragma unroll
      for (int e = 0; e < 4; ++e) {
        a4[i][e][2 * ho] = (v2f){Pv.x, Pv.y};
        a4[i][e][2 * ho + 1] = (v2f){Pv.z, Pv.w};
      }
    }
  }
  {
    const int p = (128 + 2 * g) / 20;
#pragma unroll
    for (int ho = 0; ho < OH; ++ho) {
      const float4 Pv = *(const float4*)&Pt[p * PS + ho * 64 + 4 * h];
#pragma unroll
      for (int e = 0; e < 2; ++e) {
        a2p[e][2 * ho] = (v2f){Pv.x, Pv.y};
        a2p[e][2 * ho + 1] = (v2f){Pv.z, Pv.w};
      }
    }
  }

  // K chunks: stage Wl2 + e-chunk, then pure MAC phase (ascending c)
  for (int kc = 0; kc < 64; kc += 16) {
#pragma unroll
    for (int ho = 0; ho < OH; ++ho) {
      const int o = t >> 2;
      const int cq = t & 3;
      const float4 wv = *(const float4*)&w[(ho * 64 + o) * 128 + 64 + kc + 4 * cq];
      Wl2[(4 * cq + 0) * WS + ho * 64 + o] = wv.x;
      Wl2[(4 * cq + 1) * WS + ho * 64 + o] = wv.y;
      Wl2[(4 * cq + 2) * WS + ho * 64 + o] = wv.z;
      Wl2[(4 * cq + 3) * WS + ho * 64 + o] = wv.w;
    }
#pragma unroll
    for (int q = 0; q < 3; ++q) {
      const int sl = 64 * q + (t >> 2);
      const int cq = t & 3;
      if (sl < 160) {
        const int p = sl / 20;
        const int j = jl[sl];
        const float4 xj = *(const float4*)&cat[(bN + j) * 320 + inoff + kc + 4 * cq];
        const float4 xv = *(const float4*)&xis[p][kc + 4 * cq];
        U[(4 * cq + 0) * EST + sl] = subrn(xj.x, xv.x);
        U[(4 * cq + 1) * EST + sl] = subrn(xj.y, xv.y);
        U[(4 * cq + 2) * EST + sl] = subrn(xj.z, xv.z);
        U[(4 * cq + 3) * EST + sl] = subrn(xj.w, xv.w);
      }
    }
    __syncthreads();
#pragma unroll
    for (int k = 0; k < 16; ++k) {
      // e-fragments as aligned v2f pairs (edge pairs {4g,4g+1} / {4g+2,4g+3})
      const v2f e0lo = *(const v2f*)&U[k * EST + 4 * g];
      const v2f e0hi = *(const v2f*)&U[k * EST + 4 * g + 2];
      const v2f e1lo = *(const v2f*)&U[k * EST + 64 + 4 * g];
      const v2f e1hi = *(const v2f*)&U[k * EST + 64 + 4 * g + 2];
      const v2f e2 = *(const v2f*)&U[k * EST + 128 + 2 * g];
#pragma unroll
      for (int ho = 0; ho < OH; ++ho) {
        const v2f w01 = *(const v2f*)&Wl2[k * WS + ho * 64 + 4 * h];
        const v2f w23 = *(const v2f*)&Wl2[k * WS + ho * 64 + 4 * h + 2];
        // i=0: edges 4g..4g+3 -> lo/hi broadcasts of e0lo, e0hi
        pkmac_lo(a4[0][0][2 * ho], w01, e0lo);
        pkmac_lo(a4[0][0][2 * ho + 1], w23, e0lo);
        pkmac_hi(a4[0][1][2 * ho], w01, e0lo);
        pkmac_hi(a4[0][1][2 * ho + 1], w23, e0lo);
        pkmac_lo(a4[0][2][2 * ho], w01, e0hi);
        pkmac_lo(a4[0][2][2 * ho + 1], w23, e0hi);
        pkmac_hi(a4[0][3][2 * ho], w01, e0hi);
        pkmac_hi(a4[0][3][2 * ho + 1], w23, e0hi);
        // i=1: edges 64+4g..64+4g+3
        pkmac_lo(a4[1][0][2 * ho], w01, e1lo);
        pkmac_lo(a4[1][0][2 * ho + 1], w23, e1lo);
        pkmac_hi(a4[1][1][2 * ho], w01, e1lo);
        pkmac_hi(a4[1][1][2 * ho + 1], w23, e1lo);
        pkmac_lo(a4[1][2][2 * ho], w01, e1hi);
        pkmac_lo(a4[1][2][2 * ho + 1], w23, e1hi);
        pkmac_hi(a4[1][3][2 * ho], w01, e1hi);
        pkmac_hi(a4[1][3][2 * ho + 1], w23, e1hi);
        // i=2: edges 128+2g, 128+2g+1
        pkmac_lo(a2p[0][2 * ho], w01, e2);
        pkmac_lo(a2p[0][2 * ho + 1], w23, e2);
        pkmac_hi(a2p[1][2 * ho], w01, e2);
        pkmac_hi(a2p[1][2 * ho + 1], w23, e2);
      }
    }
    __syncthreads();  // U readers done before restage / gmax
  }

  // epilogue per half: relu(s*acc+b) per edge, pair-max rows, point reduce
#pragma unroll
  for (int ho = 0; ho < OH; ++ho) {
    const float4 sv = *(const float4*)&s[ho * 64 + 4 * h];
    const float4 bv = *(const float4*)&bi[ho * 64 + 4 * h];
    const float sc[4] = {sv.x, sv.y, sv.z, sv.w};
    const float bc[4] = {bv.x, bv.y, bv.z, bv.w};
#pragma unroll
    for (int i = 0; i < 2; ++i) {
#pragma unroll
      for (int ep = 0; ep < 2; ++ep) {
        const int row = 32 * i + 2 * g + ep;
        float gm[4] = {0.f, 0.f, 0.f, 0.f};
#pragma unroll
        for (int ee = 0; ee < 2; ++ee) {
          const int e = 2 * ep + ee;
#pragma unroll
          for (int u = 0; u < 4; ++u) {
            const v2f a = a4[i][e][2 * ho + (u >> 1)];
            const float av = (u & 1) ? a.y : a.x;
            gm[u] = fmaxf(gm[u], fmaxf(addrn(mulrn(sc[u], av), bc[u]), 0.f));
          }
        }
        *(float4*)&U[row * RS + 4 * h] = make_float4(gm[0], gm[1], gm[2], gm[3]);
      }
    }
    {
      const int row = 64 + g;
      float gm[4] = {0.f, 0.f, 0.f, 0.f};
#pragma unroll
      for (int e = 0; e < 2; ++e) {
#pragma unroll
        for (int u = 0; u < 4; ++u) {
          const v2f a = a2p[e][2 * ho + (u >> 1)];
          const float av = (u & 1) ? a.y : a.x;
          gm[u] = fmaxf(gm[u], fmaxf(addrn(mulrn(sc[u], av), bc[u]), 0.f));
        }
      }
      *(float4*)&U[row * RS + 4 * h] = make_float4(gm[0], gm[1], gm[2], gm[3]);
    }
    __syncthreads();
#pragma unroll
    for (int q = 0; q < 2; ++q) {
      const int o = t & 63;
      const int p = (t >> 6) + 4 * q;
      const float* ur = &U[(10 * p) * RS + o];
      float m = ur[0];
#pragma unroll
      for (int r = 1; r < 10; ++r) m = fmaxf(m, ur[r * RS]);
      catout[(bN + n0 + p) * 320 + outoff + ho * 64 + o] = m;
    }
    if (ho + 1 < OH) __syncthreads();  // pass 2 rewrites U
  }
}

// ---------------------------------------------------------------------------
// Local layer: loc[o][n] = relu(s*<W[o,:],cat[n,:]>+b), serial ascending c.
// KC=16, DOUBLE-BUFFERED LDS (1 barrier/chunk; stage-write overlapped after
// MAC) + fused-asm packed MACs (tied acc, op_sel broadcast) + direct v2f LDS
// loads at pm-unswizzled offsets. Grid transposed (ptile fastest) so the 8
// q-tile readers of each cat ptile land on the same XCD L2.
// ---------------------------------------------------------------------------
__global__ __launch_bounds__(256) void local_gemm(
    const float* __restrict__ cat, const float* __restrict__ w,
    const float* __restrict__ s, const float* __restrict__ bi,
    float* __restrict__ pval, int* __restrict__ pidx) {
  constexpr int KC = 16;
  constexpr int XS = 132;
  constexpr int BUF = KC * XS * 2;     // floats per buffer (xs + wsd)
  __shared__ float smem[2 * BUF];      // 33,792 B (double-buffered)
  const int t = threadIdx.x;
  const int q0 = blockIdx.y * 128;     // transposed grid: y = q-tile
  const int ptile = blockIdx.x;        //                  x = point tile
  const size_t pt0 = (size_t)ptile * 128;
  const int g = t & 15;
  const int h = t >> 4;
  v2f acc2[2][2][4][2];
#pragma unroll
  for (int ep = 0; ep < 2; ++ep)
#pragma unroll
    for (int fp = 0; fp < 2; ++fp)
#pragma unroll
      for (int pi = 0; pi < 4; ++pi)
#pragma unroll
        for (int u = 0; u < 2; ++u) acc2[ep][fp][pi][u] = (v2f){0.f, 0.f};

  const int lk = t & 15;               // k-row within chunk
  const int lp = t >> 4;               // column group 0..15
  const int px = ((lk >> 3) & 1) << 1;  // store swizzle: 0 or 2
  const float* catp = cat + pt0 * 320 + lk;
  const float* wp = w + (size_t)q0 * 320 + lk;
  float rx[8], rw[8];
#pragma unroll
  for (int i = 0; i < 8; ++i) rx[i] = catp[(size_t)(lp + 16 * i) * 320];
#pragma unroll
  for (int i = 0; i < 8; ++i) rw[i] = wp[(size_t)(lp + 16 * i) * 320];
  // prologue: stage chunk 0 into buffer 0
  {
    float* xs0 = smem;
    float* ws0 = smem + KC * XS;
#pragma unroll
    for (int i = 0; i < 8; ++i) xs0[lk * XS + ((lp + 16 * i) ^ px)] = rx[i];
#pragma unroll
    for (int i = 0; i < 8; ++i) ws0[lk * XS + ((lp + 16 * i) ^ px)] = rw[i];
  }

#pragma unroll 2
  for (int ch = 0; ch < 20; ++ch) {
    const int par = ch & 1;
    const float* xsr = smem + par * BUF;
    const float* wsr = xsr + KC * XS;
    if (ch + 1 < 20) {  // issue next-chunk global loads (land during MAC)
      const int ko = (ch + 1) * KC;
#pragma unroll
      for (int i = 0; i < 8; ++i) rx[i] = catp[(size_t)(lp + 16 * i) * 320 + ko];
#pragma unroll
      for (int i = 0; i < 8; ++i) rw[i] = wp[(size_t)(lp + 16 * i) * 320 + ko];
    }
    __syncthreads();  // buf[par] writes (prev iter / prologue) visible
#pragma unroll
    for (int k = 0; k < KC; ++k) {
      const int pm2 = ((k >> 3) & 1) << 1;  // 0 or 2, compile-time under unroll
      const float* wrow = &wsr[k * XS];
      const float* xrow = &xsr[k * XS];
      // logical pairs at pm-unswizzled physical offsets (aligned v2f loads)
      v2f wA[2], wB[2];  // wA -> acc u=0 (logical cols 4h,4h+1), wB -> u=1
#pragma unroll
      for (int fp = 0; fp < 2; ++fp) {
        wA[fp] = *(const v2f*)&wrow[64 * fp + 4 * h + pm2];
        wB[fp] = *(const v2f*)&wrow[64 * fp + 4 * h + (2 - pm2)];
      }
#pragma unroll
      for (int ep = 0; ep < 2; ++ep) {
        const v2f xq0 = *(const v2f*)&xrow[64 * ep + 4 * g + pm2];        // pts 0,1
        const v2f xq1 = *(const v2f*)&xrow[64 * ep + 4 * g + (2 - pm2)];  // pts 2,3
#pragma unroll
        for (int fp = 0; fp < 2; ++fp) {
          pkmac_lo(acc2[ep][fp][0][0], wA[fp], xq0);
          pkmac_lo(acc2[ep][fp][0][1], wB[fp], xq0);
          pkmac_hi(acc2[ep][fp][1][0], wA[fp], xq0);
          pkmac_hi(acc2[ep][fp][1][1], wB[fp], xq0);
          pkmac_lo(acc2[ep][fp][2][0], wA[fp], xq1);
          pkmac_lo(acc2[ep][fp][2][1], wB[fp], xq1);
          pkmac_hi(acc2[ep][fp][3][0], wA[fp], xq1);
          pkmac_hi(acc2[ep][fp][3][1], wB[fp], xq1);
        }
      }
    }
    if (ch + 1 < 20) {  // stage next chunk into the other buffer (no barrier:
      float* xsw = smem + (par ^ 1) * BUF;  // readers of buf[par^1] finished
      float* wsw = xsw + KC * XS;           // before barrier at top of ch)
#pragma unroll
      for (int i = 0; i < 8; ++i) xsw[lk * XS + ((lp + 16 * i) ^ px)] = rx[i];
#pragma unroll
      for (int i = 0; i < 8; ++i) wsw[lk * XS + ((lp + 16 * i) ^ px)] = rw[i];
    }
  }
  // epilogue: relu(s*acc+b), per-thread argmax over 8 points ascending
  const int bb = ptile >> 5;
  const int blk = ptile & 31;
  float mv[8];
  int mi[8];
#pragma unroll
  for (int fp = 0; fp < 2; ++fp)
#pragma unroll
    for (int c = 0; c < 4; ++c) {
      const int f = fp * 4 + c;
      const int cl = 64 * fp + 4 * h + c;
      const float sc = s[q0 + cl];
      const float bc = bi[q0 + cl];
      mv[f] = -1.f;
      mi[f] = 0;
#pragma unroll
      for (int ep = 0; ep < 2; ++ep)
#pragma unroll
        for (int pi = 0; pi < 4; ++pi) {
          const v2f a2 = acc2[ep][fp][pi][c >> 1];
          const float a = (c & 1) ? a2.y : a2.x;
          const float v = fmaxf(addrn(mulrn(sc, a), bc), 0.f);
          if (v > mv[f]) { mv[f] = v; mi[f] = 64 * ep + 4 * g + pi; }
        }
    }
  __syncthreads();
  float* smv = smem;                       // 2112 floats
  int* smi = (int*)(smem + 16 * 132);      // next 2112 ints
#pragma unroll
  for (int fp = 0; fp < 2; ++fp)
#pragma unroll
    for (int c = 0; c < 4; ++c) {
      const int cl = 64 * fp + 4 * h + c;
      smv[g * 132 + cl] = mv[fp * 4 + c];
      smi[g * 132 + cl] = mi[fp * 4 + c];
    }
  __syncthreads();
  if (t < 128) {
    float best = smv[t];
    int bidx = smi[t];
    for (int gg = 1; gg < 16; ++gg) {
      const float v = smv[gg * 132 + t];
      const int vi = smi[gg * 132 + t];
      // candidates g-interleaved: ties resolve to SMALLEST point idx
      if (v > best || (v == best && vi < bidx)) { best = v; bidx = vi; }
    }
    const int n_l = blk * 128 + bidx;
    const size_t po = ((size_t)bb * 1024 + q0 + t) * 32 + blk;
    pval[po] = best;
    pidx[po] = n_l;
  }
}

__global__ __launch_bounds__(256) void final_reduce(
    const float* __restrict__ pval, const int* __restrict__ pidx,
    float* __restrict__ glob, float* __restrict__ oidx) {
  const int o = blockIdx.x * 256 + threadIdx.x;  // 8192 = B*1024
  const float* pv = pval + (size_t)o * 32;
  const int* pi = pidx + (size_t)o * 32;
  float best = pv[0];
  int bi = pi[0];
  for (int k = 1; k < 32; ++k) {
    const float v = pv[k];
    // tiles are ascending disjoint point ranges: strict > = first occurrence
    if (v > best) { best = v; bi = pi[k]; }
  }
  glob[o] = best;
  oidx[o] = (float)bi;
}

template <int KIN, int OUTS>
__global__ __launch_bounds__(256) void dense_wave(
    const float* __restrict__ in, const float* __restrict__ w,
    const float* __restrict__ s, const float* __restrict__ bi,
    float* __restrict__ out) {
  const int wid = (blockIdx.x * 256 + threadIdx.x) >> 6;
  const int lane = threadIdx.x & 63;
  const int b = wid / OUTS;
  const int o = wid % OUTS;
  const float* ip = in + (size_t)b * KIN;
  const float* wr = w + (size_t)o * KIN;
  float acc = 0.f;
  for (int k = lane; k < KIN; k += 64) acc = fmaf(wr[k], ip[k], acc);
#pragma unroll
  for (int off = 32; off; off >>= 1) acc += __shfl_down(acc, off);
  if (lane == 0) out[(size_t)b * OUTS + o] = fmaxf(fmaf(s[o], acc, bi[o]), 0.f);
}

extern "C" void kernel_launch(void* const* d_in, const int* in_sizes, int n_in,
                              void* d_out, int out_size, void* d_ws, size_t ws_size,
                              hipStream_t stream) {
  (void)in_sizes; (void)n_in; (void)out_size; (void)ws_size;
  const float* pts = (const float*)d_in[0];
  const float* ec_w[4] = {(const float*)d_in[1], (const float*)d_in[4],
                          (const float*)d_in[7], (const float*)d_in[10]};
  const float* ec_s[4] = {(const float*)d_in[2], (const float*)d_in[5],
                          (const float*)d_in[8], (const float*)d_in[11]};
  const float* ec_b[4] = {(const float*)d_in[3], (const float*)d_in[6],
                          (const float*)d_in[9], (const float*)d_in[12]};
  const float* local_w = (const float*)d_in[13];
  const float* local_s = (const float*)d_in[14];
  const float* local_b = (const float*)d_in[15];
  const float* g_w0 = (const float*)d_in[16];
  const float* g_s0 = (const float*)d_in[17];
  const float* g_b0 = (const float*)d_in[18];
  const float* g_w1 = (const float*)d_in[19];
  const float* g_s1 = (const float*)d_in[20];
  const float* g_b1 = (const float*)d_in[21];

  char* ws = (char*)d_ws;
  int* idxbuf = (int*)(ws + OFF_IDX);
  float* cat = (float*)(ws + OFF_CAT);
  float* pv = (float*)(ws + OFF_PV);
  int* pi = (int*)(ws + OFF_PI);
  float* glob = (float*)(ws + OFF_GLOB);
  float* hbuf = (float*)(ws + OFF_H);
  float* listd = (float*)(ws + OFF_LD);
  int* listj = (int*)(ws + OFF_LJ);
  int* counts = (int*)(ws + OFF_CNT);
  float* outv = (float*)d_out;   // [8][256]  fp32
  float* oidx = outv + 2048;     // [8][1024] fp32 (indices as floats)

  knn_scan<<<dim3(32, 2, 8), 256, 0, stream>>>(pts, listd, listj, counts);
  knn_merge<<<dim3(512), 256, 0, stream>>>(listd, listj, counts, idxbuf);

  // layer 1 (3 -> 64)
  ec_layer1<<<dim3(1024, 8), 256, 0, stream>>>(pts, idxbuf, ec_w[0], ec_s[0], ec_b[0], cat);
  // layer 2 (64 -> 64)
  ec_edge<1><<<dim3(512, 8), 256, 0, stream>>>(cat, 0, idxbuf, ec_w[1], ec_s[1], ec_b[1], cat, 64);
  // layer 3 (64 -> 64)
  ec_edge<1><<<dim3(512, 8), 256, 0, stream>>>(cat, 64, idxbuf, ec_w[2], ec_s[2], ec_b[2], cat, 128);
  // layer 4 (64 -> 128), fused both output halves, e staged once
  ec_edge<2><<<dim3(512, 8), 256, 0, stream>>>(cat, 128, idxbuf, ec_w[3], ec_s[3], ec_b[3], cat, 192);

  // transposed grid: ptile fastest -> same-ptile q-tiles co-located per XCD
  local_gemm<<<dim3(256, 8), 256, 0, stream>>>(cat, local_w, local_s, local_b, pv, pi);
  final_reduce<<<dim3(32), 256, 0, stream>>>(pv, pi, glob, oidx);
  dense_wave<1024, 512><<<dim3(1024), 256, 0, stream>>>(glob, g_w0, g_s0, g_b0, hbuf);
  dense_wave<512, 256><<<dim3(512), 256, 0, stream>>>(hbuf, g_w1, g_s1, g_b1, outv);
}

// Round 9
// 1263.312 us; speedup vs baseline: 1.1010x; 1.0403x over previous
//
#include <hip/hip_runtime.h>
#include <hip/hip_bf16.h>

namespace {
constexpr int B = 8;
constexpr int N = 4096;
constexpr int KNN = 20;
constexpr int NSEG = 4;
constexpr int SEGLEN = N / NSEG;   // 1024
constexpr int HSEG = SEGLEN / 2;   // 512: half-segment per thread
constexpr int CAP = 24;
constexpr int SLOTS = NSEG * CAP;  // 96

// workspace layout (bytes)
constexpr size_t OFF_IDX  = 0;                          // int [B][N][KNN]
constexpr size_t SZ_IDX   = (size_t)B * N * KNN * 4;
constexpr size_t OFF_T    = OFF_IDX + SZ_IDX;           // knn scratch region
constexpr size_t SZ_T     = (size_t)B * N * 128 * 4;
constexpr size_t OFF_CAT  = OFF_T + SZ_T;               // float [B][N][320]
constexpr size_t SZ_CAT   = (size_t)B * N * 320 * 4;
constexpr size_t OFF_PV   = OFF_CAT + SZ_CAT;           // float [B][1024][32]
constexpr size_t SZ_PV    = (size_t)B * 1024 * 32 * 4;
constexpr size_t OFF_PI   = OFF_PV + SZ_PV;             // int   [B][1024][32]
constexpr size_t OFF_GLOB = OFF_PI + SZ_PV;             // float [B][1024]
constexpr size_t OFF_H    = OFF_GLOB + (size_t)B * 1024 * 4;  // float [B][512]
// knn scratch overlaid on T + head of CAT (dead once merge completes):
constexpr size_t OFF_LD   = OFF_T;                      // float [B*N][SLOTS]
constexpr size_t SZ_LD    = (size_t)B * N * SLOTS * 4;
constexpr size_t OFF_LJ   = OFF_LD + SZ_LD;             // int   [B*N][SLOTS]
constexpr size_t OFF_CNT  = OFF_LJ + SZ_LD;             // int   [B*N][NSEG]
}  // namespace

typedef float v2f __attribute__((ext_vector_type(2)));

// Non-contractable fp32 ops: bit-exact match to np's mul-then-add serial loops.
__device__ __forceinline__ float mulrn(float a, float b) {
#pragma clang fp contract(off)
  return a * b;
}
__device__ __forceinline__ float addrn(float a, float b) {
#pragma clang fp contract(off)
  return a + b;
}
__device__ __forceinline__ float subrn(float a, float b) {
#pragma clang fp contract(off)
  return a - b;
}
// Packed (v_pk_mul_f32 / v_pk_add_f32): per-element IEEE rn == scalar ops.
__device__ __forceinline__ v2f mulrn2(v2f a, v2f b) {
#pragma clang fp contract(off)
  return a * b;
}
__device__ __forceinline__ v2f addrn2(v2f a, v2f b) {
#pragma clang fp contract(off)
  return a + b;
}

// Fused packed MAC, VOP3P with op_sel broadcast of the x-half (semantics
// hardware-validated: per-element IEEE rn mul + rn add, same as scalar).
// acc tied "+v" (no result copy), scratch early-clobber, inputs are aligned
// v2f pairs loaded directly from LDS (no repack movs).
__device__ __forceinline__ void pkmac_lo(v2f& acc, v2f w, v2f x) {
  v2f t;
  asm("v_pk_mul_f32 %1, %2, %3 op_sel:[0,0] op_sel_hi:[1,0]\n\t"
      "v_pk_add_f32 %0, %0, %1"
      : "+v"(acc), "=&v"(t) : "v"(w), "v"(x));
}
__device__ __forceinline__ void pkmac_hi(v2f& acc, v2f w, v2f x) {
  v2f t;
  asm("v_pk_mul_f32 %1, %2, %3 op_sel:[0,1] op_sel_hi:[1,1]\n\t"
      "v_pk_add_f32 %0, %0, %1"
      : "+v"(acc), "=&v"(t) : "v"(w), "v"(x));
}

// ---------------------------------------------------------------------------
// kNN, quarter-parallel: 1 row per thread (scalar distance; per-element ops
// identical to the previous packed path -> bit-same d2). Wave = 32 rows x 2
// halves (partner lane^32); block = 4 waves = 128 rows x 1 seg, 16 KB LDS.
// 4096 waves total (4/SIMD) vs 2048 before: covers the ds_read->dist->insert
// dependency chain. Sorted-20 bubble per (row, half); exact segment 20th =
// Batcher merge theta = max_i min(a_i, b_{19-i}) via shfl_xor(.,32) (pure
// selection -> bit-identical). Recovery appends front (half 0) / back
// (half 1) into the shared CAP-slot region; counts = front | back<<16.
// ---------------------------------------------------------------------------
__global__ __launch_bounds__(256) void knn_scan(
    const float* __restrict__ pts,
    float* __restrict__ listd, int* __restrict__ listj, int* __restrict__ counts) {
  __shared__ float4 sp[SEGLEN];  // 16 KB: (x, y, z, sq) for 1 segment
  const int b = blockIdx.z;
  const int tid = threadIdx.x;
  const float* px = pts + (size_t)b * 3 * N;
  const int seg = blockIdx.y;
  const int cb0 = seg * SEGLEN;  // candidate base
  for (int i = tid; i < SEGLEN; i += 256) {
    const float x = px[cb0 + i];
    const float y = px[N + cb0 + i];
    const float z = px[2 * N + cb0 + i];
    const float sq = addrn(addrn(mulrn(x, x), mulrn(y, y)), mulrn(z, z));
    sp[i] = make_float4(x, y, z, sq);
  }
  __syncthreads();
  const int lane = tid & 63;
  const int rl = lane & 31;            // row lane
  const int h2 = lane >> 5;            // half of the segment
  const int wid = tid >> 6;            // wave 0..3
  const int row = blockIdx.x * 128 + wid * 32 + rl;
  // query from global (identical arithmetic to staging -> bit-same sq)
  const float ax = px[row], ay = px[N + row], az = px[2 * N + row];
  const float qw = addrn(addrn(mulrn(ax, ax), mulrn(ay, ay)), mulrn(az, az));
  float da[KNN];
#pragma unroll
  for (int t = 0; t < KNN; ++t) da[t] = 3.0e38f;
  const int j0 = h2 * HSEG;  // LDS-local candidate base
#pragma unroll 2
  for (int jj = 0; jj < HSEG; ++jj) {
    const float4 c = sp[j0 + jj];
    float t0 = mulrn(ax, c.x);
    t0 = addrn(t0, mulrn(ay, c.y));
    t0 = addrn(t0, mulrn(az, c.z));
    const float d2 = subrn(addrn(qw, c.w), mulrn(2.0f, t0));
    if (d2 < da[KNN - 1]) {
      float cur = d2;
#pragma unroll
      for (int t = 0; t < KNN; ++t) {
        const float lo = fminf(cur, da[t]);
        cur = fmaxf(cur, da[t]);
        da[t] = lo;
      }
    }
  }
  // exact segment 20th via bitonic cross-half merge (partner = lane ^ 32);
  // pure min/max selection over the same multiset -> both lanes get the same
  // bit pattern, equal to the single-scan 20th.
  float tha = -3.0e38f;
#pragma unroll
  for (int i = 0; i < KNN; ++i)
    tha = fmaxf(tha, fminf(da[i], __shfl_xor(da[KNN - 1 - i], 32)));
  float* lda = listd + (size_t)(b * N + row) * SLOTS + seg * CAP;
  int* lja = listj + (size_t)(b * N + row) * SLOTS + seg * CAP;
  const int jg0 = cb0 + j0;  // global candidate index base
  int ca = 0;
#pragma unroll 2
  for (int jj = 0; jj < HSEG; ++jj) {
    const float4 c = sp[j0 + jj];
    float t0 = mulrn(ax, c.x);
    t0 = addrn(t0, mulrn(ay, c.y));
    t0 = addrn(t0, mulrn(az, c.z));
    const float d2 = subrn(addrn(qw, c.w), mulrn(2.0f, t0));
    if (d2 <= tha && ca < CAP) {
      const int sl = h2 ? (CAP - 1 - ca) : ca;
      lda[sl] = d2;
      lja[sl] = jg0 + jj;
      ++ca;
    }
  }
  const int oa = __shfl_xor(ca, 32);
  if (h2 == 0)  // pack: front count | back count << 16
    counts[(b * N + row) * NSEG + seg] = ca | (oa << 16);
}

// Merge: per row, select 20 lexicographically-smallest (dist, j) from <=96
// candidates via monotone uint64 keys. counts packed front|back<<16; valid
// slots are [0, front) u [CAP-back, CAP).
// 4-thread-per-row cooperative selection: threads 4rr..4rr+3 (same wave) each
// scan a 24-slot strip; global min via 2x shfl_xor u64-min (associative, keys
// unique -> identical selection sequence to the serial scan); unique owner
// marks its slot (in-wave DS program order makes the mark visible to the next
// iteration without barriers). 256-thread blocks: 2 waves/SIMD vs 0.5 before.
__global__ __launch_bounds__(256) void knn_merge(
    const float* __restrict__ listd, const int* __restrict__ listj,
    const int* __restrict__ counts, int* __restrict__ idxout) {
  __shared__ unsigned long long keys[64][SLOTS + 1];  // 49,664 B
  const int r0 = blockIdx.x * 64;
  const int t = threadIdx.x;
  for (int i = t; i < 64 * SLOTS; i += 256) {
    const int rr = i / SLOTS;
    const int sl = i % SLOTS;
    const int seg = sl / CAP;
    const int e = sl % CAP;
    const int row = r0 + rr;
    unsigned long long key = 0xFFFFFFFE00000000ULL | (unsigned)row;  // fallback: self
    const int cp = counts[row * NSEG + seg];
    if (e < (cp & 0xFFFF) || e >= CAP - (cp >> 16)) {
      const float d = listd[(size_t)row * SLOTS + sl];
      unsigned ub = __float_as_uint(d);
      ub ^= (ub & 0x80000000u) ? 0xFFFFFFFFu : 0x80000000u;
      key = ((unsigned long long)ub << 32) | (unsigned)listj[(size_t)row * SLOTS + sl];
    }
    keys[rr][sl] = key;
  }
  __syncthreads();
  const int g4 = t & 3;        // strip within row
  const int rr = t >> 2;       // row slot 0..63
  const int sbase = g4 * 24;   // 4 strips x 24 = 96 slots
  int* outp = idxout + (size_t)(r0 + rr) * KNN;
  for (int sel = 0; sel < KNN; ++sel) {
    unsigned long long best = ~0ULL;
    int bs = sbase;
#pragma unroll
    for (int e = 0; e < 24; ++e) {
      const unsigned long long k2 = keys[rr][sbase + e];
      if (k2 < best) { best = k2; bs = sbase + e; }
    }
    unsigned long long m = best;
    {
      const unsigned long long o1 = __shfl_xor(m, 1);
      m = (o1 < m) ? o1 : m;
      const unsigned long long o2 = __shfl_xor(m, 2);
      m = (o2 < m) ? o2 : m;
    }
    if (best == m) keys[rr][bs] = ~0ULL;  // keys unique -> single owner
    if (g4 == 0) outp[sel] = (int)(m & 0xFFFFFFFFu);
  }
}

// ---------------------------------------------------------------------------
// EdgeConv, BIT-EXACT serial semantics per (o, n, k):
//   y = sum_c W1[o,c]*x_i[c]  (prefix P)  then  += W2[o,c]*(x_j[c]-x_i[c]).
// ---------------------------------------------------------------------------

// Layer 1 (cin=3): wave per point, lane = output o.
__global__ __launch_bounds__(256) void ec_layer1(
    const float* __restrict__ pts, const int* __restrict__ idx,
    const float* __restrict__ w, const float* __restrict__ s,
    const float* __restrict__ bi, float* __restrict__ cat) {
  const int b = blockIdx.y;
  const int n = blockIdx.x * 4 + (threadIdx.x >> 6);
  const int o = threadIdx.x & 63;
  const float* p = pts + (size_t)b * 3 * N;
  const float xix = p[n], xiy = p[N + n], xiz = p[2 * N + n];
  const float* wr = w + o * 6;
  const float w0 = wr[0], w1 = wr[1], w2 = wr[2], w3 = wr[3], w4 = wr[4], w5 = wr[5];
  float P = mulrn(w0, xix);
  P = addrn(P, mulrn(w1, xiy));
  P = addrn(P, mulrn(w2, xiz));
  const float so = s[o], bo = bi[o];
  const int* ip = idx + ((size_t)b * N + n) * KNN;
  float m = 0.0f;
#pragma unroll 4
  for (int k = 0; k < KNN; ++k) {
    int j = ip[k];
    if ((unsigned)j >= (unsigned)N) j = n;
    const float ex = subrn(p[j], xix);
    const float ey = subrn(p[N + j], xiy);
    const float ez = subrn(p[2 * N + j], xiz);
    float acc = addrn(P, mulrn(w3, ex));
    acc = addrn(acc, mulrn(w4, ey));
    acc = addrn(acc, mulrn(w5, ez));
    m = fmaxf(m, addrn(mulrn(so, acc), bo));
  }
  cat[((size_t)b * N + n) * 320 + o] = m;
}

// 64-in EdgeConv as edge-GEMM: 8 points x 20 slots = 160 edges (no dups),
// OH output halves (1 -> 64 outs; 2 -> fused 128 outs, e staged ONCE).
// Edge frags: i=0,1 quads (edge=64i+4g+e) + i=2 pairs (edge=128+2g+e).
// MAC loop: fused-asm pkmac with op_sel broadcast; e-frags and W read as
// aligned v2f pairs (no broadcast-construction movs). Per-accumulator op
// order unchanged (ascending kc, k; mul-then-add) -> bit-exact.
// gmax epilogue at pair granularity: row = edge>>1 (80 rows), point p owns
// rows 10p..10p+9.
template <int OH>
__global__ __launch_bounds__(256) void ec_edge(
    const float* __restrict__ cat, int inoff, const int* __restrict__ idx,
    const float* __restrict__ w, const float* __restrict__ s,
    const float* __restrict__ bi, float* __restrict__ catout, int outoff) {
  constexpr int EST = 164;         // e-chunk row stride
  constexpr int RS = 68;           // gmax row stride
  constexpr int PS = 64 * OH + 4;  // Pt row stride
  constexpr int WS = 64 * OH + 4;  // Wl2 row stride
  __shared__ float U[80 * RS];     // 21.76 KB multi-purpose (W1 / e-chunk / gmax)
  __shared__ float xis[8][64];     // 2 KB
  __shared__ float Pt[8 * PS];
  __shared__ float Wl2[16 * WS];
  __shared__ int jl[160];
  const int t = threadIdx.x;
  const int b = blockIdx.y;
  const int n0 = blockIdx.x * 8;
  const size_t bN = (size_t)b * N;

  // stage xis + jl
#pragma unroll
  for (int q = 0; q < 2; ++q) {
    const int p = (t >> 6) + 4 * q;
    const int c = t & 63;
    xis[p][c] = cat[(bN + n0 + p) * 320 + inoff + c];
  }
  if (t < 160) {
    const int p = t / 20;
    const int k = t % 20;
    int j = idx[(bN + n0 + p) * KNN + k];
    if ((unsigned)j >= (unsigned)N) j = n0 + p;  // firewall
    jl[t] = j;
  }
  __syncthreads();

  // prefix P per output-half (W1 staged through U, stride 66 -> float2 reads)
#pragma unroll
  for (int ho = 0; ho < OH; ++ho) {
#pragma unroll
    for (int q = 0; q < 16; ++q) {
      const int l = t + 256 * q;
      U[(l >> 6) * 66 + (l & 63)] = w[(ho * 64 + (l >> 6)) * 128 + (l & 63)];
    }
    __syncthreads();
    {
      const int o = t & 63;
      const int p0 = t >> 6;
      const float2* wq = (const float2*)&U[o * 66];
      const float2* x0 = (const float2*)&xis[p0][0];
      const float2* x1 = (const float2*)&xis[p0 + 4][0];
      float2 wv = wq[0];
      float2 a0 = x0[0];
      float2 a1 = x1[0];
      float P0 = mulrn(wv.x, a0.x);
      float P1 = mulrn(wv.x, a1.x);
      P0 = addrn(P0, mulrn(wv.y, a0.y));
      P1 = addrn(P1, mulrn(wv.y, a1.y));
#pragma unroll
      for (int c2 = 1; c2 < 32; ++c2) {
        wv = wq[c2];
        a0 = x0[c2];
        a1 = x1[c2];
        P0 = addrn(P0, mulrn(wv.x, a0.x));
        P1 = addrn(P1, mulrn(wv.x, a1.x));
        P0 = addrn(P0, mulrn(wv.y, a0.y));
        P1 = addrn(P1, mulrn(wv.y, a1.y));
      }
      Pt[p0 * PS + ho * 64 + o] = P0;
      Pt[(p0 + 4) * PS + ho * 64 + o] = P1;
    }
    __syncthreads();
  }

  const int g = t & 15;  // edge-frag lane
  const int h = t >> 4;  // output-frag lane: outputs 64*ho + 4h + u
  v2f a4[2][4][2 * OH];  // quad frags (i=0,1)
  v2f a2p[2][2 * OH];    // pair frag (i=2)
#pragma unroll
  for (int i = 0; i < 2; ++i) {
    const int p = (64 * i + 4 * g) / 20;
#pragma unroll
    for (int ho = 0; ho < OH; ++ho) {
      const float4 Pv = *(const float4*)&Pt[p * PS + ho * 64 + 4 * h];
#pragma unroll
      for (int e = 0; e < 4; ++e) {
        a4[i][e][2 * ho] = (v2f){Pv.x, Pv.y};
        a4[i][e][2 * ho + 1] = (v2f){Pv.z, Pv.w};
      }
    }
  }
  {
    const int p = (128 + 2 * g) / 20;
#pragma unroll
    for (int ho = 0; ho < OH; ++ho) {
      const float4 Pv = *(const float4*)&Pt[p * PS + ho * 64 + 4 * h];
#pragma unroll
      for (int e = 0; e < 2; ++e) {
        a2p[e][2 * ho] = (v2f){Pv.x, Pv.y};
        a2p[e][2 * ho + 1] = (v2f){Pv.z, Pv.w};
      }
    }
  }

  // K chunks: stage Wl2 + e-chunk, then pure MAC phase (ascending c)
  for (int kc = 0; kc < 64; kc += 16) {
#pragma unroll
    for (int ho = 0; ho < OH; ++ho) {
      const int o = t >> 2;
      const int cq = t & 3;
      const float4 wv = *(const float4*)&w[(ho * 64 + o) * 128 + 64 + kc + 4 * cq];
      Wl2[(4 * cq + 0) * WS + ho * 64 + o] = wv.x;
      Wl2[(4 * cq + 1) * WS + ho * 64 + o] = wv.y;
      Wl2[(4 * cq + 2) * WS + ho * 64 + o] = wv.z;
      Wl2[(4 * cq + 3) * WS + ho * 64 + o] = wv.w;
    }
#pragma unroll
    for (int q = 0; q < 3; ++q) {
      const int sl = 64 * q + (t >> 2);
      const int cq = t & 3;
      if (sl < 160) {
        const int p = sl / 20;
        const int j = jl[sl];
        const float4 xj = *(const float4*)&cat[(bN + j) * 320 + inoff + kc + 4 * cq];
        const float4 xv = *(const float4*)&xis[p][kc + 4 * cq];
        U[(4 * cq + 0) * EST + sl] = subrn(xj.x, xv.x);
        U[(4 * cq + 1) * EST + sl] = subrn(xj.y, xv.y);
        U[(4 * cq + 2) * EST + sl] = subrn(xj.z, xv.z);
        U[(4 * cq + 3) * EST + sl] = subrn(xj.w, xv.w);
      }
    }
    __syncthreads();
#pragma unroll
    for (int k = 0; k < 16; ++k) {
      // e-fragments as aligned v2f pairs (edge pairs {4g,4g+1} / {4g+2,4g+3})
      const v2f e0lo = *(const v2f*)&U[k * EST + 4 * g];
      const v2f e0hi = *(const v2f*)&U[k * EST + 4 * g + 2];
      const v2f e1lo = *(const v2f*)&U[k * EST + 64 + 4 * g];
      const v2f e1hi = *(const v2f*)&U[k * EST + 64 + 4 * g + 2];
      const v2f e2 = *(const v2f*)&U[k * EST + 128 + 2 * g];
#pragma unroll
      for (int ho = 0; ho < OH; ++ho) {
        const v2f w01 = *(const v2f*)&Wl2[k * WS + ho * 64 + 4 * h];
        const v2f w23 = *(const v2f*)&Wl2[k * WS + ho * 64 + 4 * h + 2];
        // i=0: edges 4g..4g+3 -> lo/hi broadcasts of e0lo, e0hi
        pkmac_lo(a4[0][0][2 * ho], w01, e0lo);
        pkmac_lo(a4[0][0][2 * ho + 1], w23, e0lo);
        pkmac_hi(a4[0][1][2 * ho], w01, e0lo);
        pkmac_hi(a4[0][1][2 * ho + 1], w23, e0lo);
        pkmac_lo(a4[0][2][2 * ho], w01, e0hi);
        pkmac_lo(a4[0][2][2 * ho + 1], w23, e0hi);
        pkmac_hi(a4[0][3][2 * ho], w01, e0hi);
        pkmac_hi(a4[0][3][2 * ho + 1], w23, e0hi);
        // i=1: edges 64+4g..64+4g+3
        pkmac_lo(a4[1][0][2 * ho], w01, e1lo);
        pkmac_lo(a4[1][0][2 * ho + 1], w23, e1lo);
        pkmac_hi(a4[1][1][2 * ho], w01, e1lo);
        pkmac_hi(a4[1][1][2 * ho + 1], w23, e1lo);
        pkmac_lo(a4[1][2][2 * ho], w01, e1hi);
        pkmac_lo(a4[1][2][2 * ho + 1], w23, e1hi);
        pkmac_hi(a4[1][3][2 * ho], w01, e1hi);
        pkmac_hi(a4[1][3][2 * ho + 1], w23, e1hi);
        // i=2: edges 128+2g, 128+2g+1
        pkmac_lo(a2p[0][2 * ho], w01, e2);
        pkmac_lo(a2p[0][2 * ho + 1], w23, e2);
        pkmac_hi(a2p[1][2 * ho], w01, e2);
        pkmac_hi(a2p[1][2 * ho + 1], w23, e2);
      }
    }
    __syncthreads();  // U readers done before restage / gmax
  }

  // epilogue per half: relu(s*acc+b) per edge, pair-max rows, point reduce
#pragma unroll
  for (int ho = 0; ho < OH; ++ho) {
    const float4 sv = *(const float4*)&s[ho * 64 + 4 * h];
    const float4 bv = *(const float4*)&bi[ho * 64 + 4 * h];
    const float sc[4] = {sv.x, sv.y, sv.z, sv.w};
    const float bc[4] = {bv.x, bv.y, bv.z, bv.w};
#pragma unroll
    for (int i = 0; i < 2; ++i) {
#pragma unroll
      for (int ep = 0; ep < 2; ++ep) {
        const int row = 32 * i + 2 * g + ep;
        float gm[4] = {0.f, 0.f, 0.f, 0.f};
#pragma unroll
        for (int ee = 0; ee < 2; ++ee) {
          const int e = 2 * ep + ee;
#pragma unroll
          for (int u = 0; u < 4; ++u) {
            const v2f a = a4[i][e][2 * ho + (u >> 1)];
            const float av = (u & 1) ? a.y : a.x;
            gm[u] = fmaxf(gm[u], fmaxf(addrn(mulrn(sc[u], av), bc[u]), 0.f));
          }
        }
        *(float4*)&U[row * RS + 4 * h] = make_float4(gm[0], gm[1], gm[2], gm[3]);
      }
    }
    {
      const int row = 64 + g;
      float gm[4] = {0.f, 0.f, 0.f, 0.f};
#pragma unroll
      for (int e = 0; e < 2; ++e) {
#pragma unroll
        for (int u = 0; u < 4; ++u) {
          const v2f a = a2p[e][2 * ho + (u >> 1)];
          const float av = (u & 1) ? a.y : a.x;
          gm[u] = fmaxf(gm[u], fmaxf(addrn(mulrn(sc[u], av), bc[u]), 0.f));
        }
      }
      *(float4*)&U[row * RS + 4 * h] = make_float4(gm[0], gm[1], gm[2], gm[3]);
    }
    __syncthreads();
#pragma unroll
    for (int q = 0; q < 2; ++q) {
      const int o = t & 63;
      const int p = (t >> 6) + 4 * q;
      const float* ur = &U[(10 * p) * RS + o];
      float m = ur[0];
#pragma unroll
      for (int r = 1; r < 10; ++r) m = fmaxf(m, ur[r * RS]);
      catout[(bN + n0 + p) * 320 + outoff + ho * 64 + o] = m;
    }
    if (ho + 1 < OH) __syncthreads();  // pass 2 rewrites U
  }
}

// ---------------------------------------------------------------------------
// Local layer: loc[o][n] = relu(s*<W[o,:],cat[n,:]>+b), serial ascending c.
// KC=16, DOUBLE-BUFFERED LDS (1 barrier/chunk; stage-write overlapped after
// MAC) + fused-asm packed MACs (tied acc, op_sel broadcast) + direct v2f LDS
// loads at pm-unswizzled offsets. Grid transposed (ptile fastest) so the 8
// q-tile readers of each cat ptile land on the same XCD L2.
// ---------------------------------------------------------------------------
__global__ __launch_bounds__(256) void local_gemm(
    const float* __restrict__ cat, const float* __restrict__ w,
    const float* __restrict__ s, const float* __restrict__ bi,
    float* __restrict__ pval, int* __restrict__ pidx) {
  constexpr int KC = 16;
  constexpr int XS = 132;
  constexpr int BUF = KC * XS * 2;     // floats per buffer (xs + wsd)
  __shared__ float smem[2 * BUF];      // 33,792 B (double-buffered)
  const int t = threadIdx.x;
  const int q0 = blockIdx.y * 128;     // transposed grid: y = q-tile
  const int ptile = blockIdx.x;        //                  x = point tile
  const size_t pt0 = (size_t)ptile * 128;
  const int g = t & 15;
  const int h = t >> 4;
  v2f acc2[2][2][4][2];
#pragma unroll
  for (int ep = 0; ep < 2; ++ep)
#pragma unroll
    for (int fp = 0; fp < 2; ++fp)
#pragma unroll
      for (int pi = 0; pi < 4; ++pi)
#pragma unroll
        for (int u = 0; u < 2; ++u) acc2[ep][fp][pi][u] = (v2f){0.f, 0.f};

  const int lk = t & 15;               // k-row within chunk
  const int lp = t >> 4;               // column group 0..15
  const int px = ((lk >> 3) & 1) << 1;  // store swizzle: 0 or 2
  const float* catp = cat + pt0 * 320 + lk;
  const float* wp = w + (size_t)q0 * 320 + lk;
  float rx[8], rw[8];
#pragma unroll
  for (int i = 0; i < 8; ++i) rx[i] = catp[(size_t)(lp + 16 * i) * 320];
#pragma unroll
  for (int i = 0; i < 8; ++i) rw[i] = wp[(size_t)(lp + 16 * i) * 320];
  // prologue: stage chunk 0 into buffer 0
  {
    float* xs0 = smem;
    float* ws0 = smem + KC * XS;
#pragma unroll
    for (int i = 0; i < 8; ++i) xs0[lk * XS + ((lp + 16 * i) ^ px)] = rx[i];
#pragma unroll
    for (int i = 0; i < 8; ++i) ws0[lk * XS + ((lp + 16 * i) ^ px)] = rw[i];
  }

#pragma unroll 2
  for (int ch = 0; ch < 20; ++ch) {
    const int par = ch & 1;
    const float* xsr = smem + par * BUF;
    const float* wsr = xsr + KC * XS;
    if (ch + 1 < 20) {  // issue next-chunk global loads (land during MAC)
      const int ko = (ch + 1) * KC;
#pragma unroll
      for (int i = 0; i < 8; ++i) rx[i] = catp[(size_t)(lp + 16 * i) * 320 + ko];
#pragma unroll
      for (int i = 0; i < 8; ++i) rw[i] = wp[(size_t)(lp + 16 * i) * 320 + ko];
    }
    __syncthreads();  // buf[par] writes (prev iter / prologue) visible
#pragma unroll
    for (int k = 0; k < KC; ++k) {
      const int pm2 = ((k >> 3) & 1) << 1;  // 0 or 2, compile-time under unroll
      const float* wrow = &wsr[k * XS];
      const float* xrow = &xsr[k * XS];
      // logical pairs at pm-unswizzled physical offsets (aligned v2f loads)
      v2f wA[2], wB[2];  // wA -> acc u=0 (logical cols 4h,4h+1), wB -> u=1
#pragma unroll
      for (int fp = 0; fp < 2; ++fp) {
        wA[fp] = *(const v2f*)&wrow[64 * fp + 4 * h + pm2];
        wB[fp] = *(const v2f*)&wrow[64 * fp + 4 * h + (2 - pm2)];
      }
#pragma unroll
      for (int ep = 0; ep < 2; ++ep) {
        const v2f xq0 = *(const v2f*)&xrow[64 * ep + 4 * g + pm2];        // pts 0,1
        const v2f xq1 = *(const v2f*)&xrow[64 * ep + 4 * g + (2 - pm2)];  // pts 2,3
#pragma unroll
        for (int fp = 0; fp < 2; ++fp) {
          pkmac_lo(acc2[ep][fp][0][0], wA[fp], xq0);
          pkmac_lo(acc2[ep][fp][0][1], wB[fp], xq0);
          pkmac_hi(acc2[ep][fp][1][0], wA[fp], xq0);
          pkmac_hi(acc2[ep][fp][1][1], wB[fp], xq0);
          pkmac_lo(acc2[ep][fp][2][0], wA[fp], xq1);
          pkmac_lo(acc2[ep][fp][2][1], wB[fp], xq1);
          pkmac_hi(acc2[ep][fp][3][0], wA[fp], xq1);
          pkmac_hi(acc2[ep][fp][3][1], wB[fp], xq1);
        }
      }
    }
    if (ch + 1 < 20) {  // stage next chunk into the other buffer (no barrier:
      float* xsw = smem + (par ^ 1) * BUF;  // readers of buf[par^1] finished
      float* wsw = xsw + KC * XS;           // before barrier at top of ch)
#pragma unroll
      for (int i = 0; i < 8; ++i) xsw[lk * XS + ((lp + 16 * i) ^ px)] = rx[i];
#pragma unroll
      for (int i = 0; i < 8; ++i) wsw[lk * XS + ((lp + 16 * i) ^ px)] = rw[i];
    }
  }
  // epilogue: relu(s*acc+b), per-thread argmax over 8 points ascending
  const int bb = ptile >> 5;
  const int blk = ptile & 31;
  float mv[8];
  int mi[8];
#pragma unroll
  for (int fp = 0; fp < 2; ++fp)
#pragma unroll
    for (int c = 0; c < 4; ++c) {
      const int f = fp * 4 + c;
      const int cl = 64 * fp + 4 * h + c;
      const float sc = s[q0 + cl];
      const float bc = bi[q0 + cl];
      mv[f] = -1.f;
      mi[f] = 0;
#pragma unroll
      for (int ep = 0; ep < 2; ++ep)
#pragma unroll
        for (int pi = 0; pi < 4; ++pi) {
          const v2f a2 = acc2[ep][fp][pi][c >> 1];
          const float a = (c & 1) ? a2.y : a2.x;
          const float v = fmaxf(addrn(mulrn(sc, a), bc), 0.f);
          if (v > mv[f]) { mv[f] = v; mi[f] = 64 * ep + 4 * g + pi; }
        }
    }
  __syncthreads();
  float* smv = smem;                       // 2112 floats
  int* smi = (int*)(smem + 16 * 132);      // next 2112 ints
#pragma unroll
  for (int fp = 0; fp < 2; ++fp)
#pragma unroll
    for (int c = 0; c < 4; ++c) {
      const int cl = 64 * fp + 4 * h + c;
      smv[g * 132 + cl] = mv[fp * 4 + c];
      smi[g * 132 + cl] = mi[fp * 4 + c];
    }
  __syncthreads();
  if (t < 128) {
    float best = smv[t];
    int bidx = smi[t];
    for (int gg = 1; gg < 16; ++gg) {
      const float v = smv[gg * 132 + t];
      const int vi = smi[gg * 132 + t];
      // candidates g-interleaved: ties resolve to SMALLEST point idx
      if (v > best || (v == best && vi < bidx)) { best = v; bidx = vi; }
    }
    const int n_l = blk * 128 + bidx;
    const size_t po = ((size_t)bb * 1024 + q0 + t) * 32 + blk;
    pval[po] = best;
    pidx[po] = n_l;
  }
}

__global__ __launch_bounds__(256) void final_reduce(
    const float* __restrict__ pval, const int* __restrict__ pidx,
    float* __restrict__ glob, float* __restrict__ oidx) {
  const int o = blockIdx.x * 256 + threadIdx.x;  // 8192 = B*1024
  const float* pv = pval + (size_t)o * 32;
  const int* pi = pidx + (size_t)o * 32;
  float best = pv[0];
  int bi = pi[0];
  for (int k = 1; k < 32; ++k) {
    const float v = pv[k];
    // tiles are ascending disjoint point ranges: strict > = first occurrence
    if (v > best) { best = v; bi = pi[k]; }
  }
  glob[o] = best;
  oidx[o] = (float)bi;
}

template <int KIN, int OUTS>
__global__ __launch_bounds__(256) void dense_wave(
    const float* __restrict__ in, const float* __restrict__ w,
    const float* __restrict__ s, const float* __restrict__ bi,
    float* __restrict__ out) {
  const int wid = (blockIdx.x * 256 + threadIdx.x) >> 6;
  const int lane = threadIdx.x & 63;
  const int b = wid / OUTS;
  const int o = wid % OUTS;
  const float* ip = in + (size_t)b * KIN;
  const float* wr = w + (size_t)o * KIN;
  float acc = 0.f;
  for (int k = lane; k < KIN; k += 64) acc = fmaf(wr[k], ip[k], acc);
#pragma unroll
  for (int off = 32; off; off >>= 1) acc += __shfl_down(acc, off);
  if (lane == 0) out[(size_t)b * OUTS + o] = fmaxf(fmaf(s[o], acc, bi[o]), 0.f);
}

extern "C" void kernel_launch(void* const* d_in, const int* in_sizes, int n_in,
                              void* d_out, int out_size, void* d_ws, size_t ws_size,
                              hipStream_t stream) {
  (void)in_sizes; (void)n_in; (void)out_size; (void)ws_size;
  const float* pts = (const float*)d_in[0];
  const float* ec_w[4] = {(const float*)d_in[1], (const float*)d_in[4],
                          (const float*)d_in[7], (const float*)d_in[10]};
  const float* ec_s[4] = {(const float*)d_in[2], (const float*)d_in[5],
                          (const float*)d_in[8], (const float*)d_in[11]};
  const float* ec_b[4] = {(const float*)d_in[3], (const float*)d_in[6],
                          (const float*)d_in[9], (const float*)d_in[12]};
  const float* local_w = (const float*)d_in[13];
  const float* local_s = (const float*)d_in[14];
  const float* local_b = (const float*)d_in[15];
  const float* g_w0 = (const float*)d_in[16];
  const float* g_s0 = (const float*)d_in[17];
  const float* g_b0 = (const float*)d_in[18];
  const float* g_w1 = (const float*)d_in[19];
  const float* g_s1 = (const float*)d_in[20];
  const float* g_b1 = (const float*)d_in[21];

  char* ws = (char*)d_ws;
  int* idxbuf = (int*)(ws + OFF_IDX);
  float* cat = (float*)(ws + OFF_CAT);
  float* pv = (float*)(ws + OFF_PV);
  int* pi = (int*)(ws + OFF_PI);
  float* glob = (float*)(ws + OFF_GLOB);
  float* hbuf = (float*)(ws + OFF_H);
  float* listd = (float*)(ws + OFF_LD);
  int* listj = (int*)(ws + OFF_LJ);
  int* counts = (int*)(ws + OFF_CNT);
  float* outv = (float*)d_out;   // [8][256]  fp32
  float* oidx = outv + 2048;     // [8][1024] fp32 (indices as floats)

  knn_scan<<<dim3(32, 4, 8), 256, 0, stream>>>(pts, listd, listj, counts);
  knn_merge<<<dim3(512), 256, 0, stream>>>(listd, listj, counts, idxbuf);

  // layer 1 (3 -> 64)
  ec_layer1<<<dim3(1024, 8), 256, 0, stream>>>(pts, idxbuf, ec_w[0], ec_s[0], ec_b[0], cat);
  // layer 2 (64 -> 64)
  ec_edge<1><<<dim3(512, 8), 256, 0, stream>>>(cat, 0, idxbuf, ec_w[1], ec_s[1], ec_b[1], cat, 64);
  // layer 3 (64 -> 64)
  ec_edge<1><<<dim3(512, 8), 256, 0, stream>>>(cat, 64, idxbuf, ec_w[2], ec_s[2], ec_b[2], cat, 128);
  // layer 4 (64 -> 128), fused both output halves, e staged once
  ec_edge<2><<<dim3(512, 8), 256, 0, stream>>>(cat, 128, idxbuf, ec_w[3], ec_s[3], ec_b[3], cat, 192);

  // transposed grid: ptile fastest -> same-ptile q-tiles co-located per XCD
  local_gemm<<<dim3(256, 8), 256, 0, stream>>>(cat, local_w, local_s, local_b, pv, pi);
  final_reduce<<<dim3(32), 256, 0, stream>>>(pv, pi, glob, oidx);
  dense_wave<1024, 512><<<dim3(1024), 256, 0, stream>>>(glob, g_w0, g_s0, g_b0, hbuf);
  dense_wave<512, 256><<<dim3(512), 256, 0, stream>>>(hbuf, g_w1, g_s1, g_b1, outv);
}

// Round 10
// 1199.078 us; speedup vs baseline: 1.1600x; 1.0536x over previous
//
#include <hip/hip_runtime.h>
#include <hip/hip_bf16.h>

namespace {
constexpr int B = 8;
constexpr int N = 4096;
constexpr int KNN = 20;
constexpr int NSEG = 4;
constexpr int SEGLEN = N / NSEG;   // 1024
constexpr int HSEG = SEGLEN / 2;   // 512: half-segment per thread
constexpr int CAP = 24;
constexpr int SLOTS = NSEG * CAP;  // 96

// workspace layout (bytes)
constexpr size_t OFF_IDX  = 0;                          // int [B][N][KNN]
constexpr size_t SZ_IDX   = (size_t)B * N * KNN * 4;
constexpr size_t OFF_T    = OFF_IDX + SZ_IDX;           // knn scratch region
constexpr size_t SZ_T     = (size_t)B * N * 128 * 4;
constexpr size_t OFF_CAT  = OFF_T + SZ_T;               // float [B][N][320]
constexpr size_t SZ_CAT   = (size_t)B * N * 320 * 4;
constexpr size_t OFF_PV   = OFF_CAT + SZ_CAT;           // float [B][1024][32]
constexpr size_t SZ_PV    = (size_t)B * 1024 * 32 * 4;
constexpr size_t OFF_PI   = OFF_PV + SZ_PV;             // int   [B][1024][32]
constexpr size_t OFF_GLOB = OFF_PI + SZ_PV;             // float [B][1024]
constexpr size_t OFF_H    = OFF_GLOB + (size_t)B * 1024 * 4;  // float [B][512]
// knn scratch overlaid on T + head of CAT (dead once merge completes):
constexpr size_t OFF_LD   = OFF_T;                      // float [B*N][SLOTS]
constexpr size_t SZ_LD    = (size_t)B * N * SLOTS * 4;
constexpr size_t OFF_LJ   = OFF_LD + SZ_LD;             // int   [B*N][SLOTS]
constexpr size_t OFF_CNT  = OFF_LJ + SZ_LD;             // int   [B*N][NSEG]
}  // namespace

typedef float v2f __attribute__((ext_vector_type(2)));

// Non-contractable fp32 ops: bit-exact match to np's mul-then-add serial loops.
__device__ __forceinline__ float mulrn(float a, float b) {
#pragma clang fp contract(off)
  return a * b;
}
__device__ __forceinline__ float addrn(float a, float b) {
#pragma clang fp contract(off)
  return a + b;
}
__device__ __forceinline__ float subrn(float a, float b) {
#pragma clang fp contract(off)
  return a - b;
}
// Packed (v_pk_mul_f32 / v_pk_add_f32): per-element IEEE rn == scalar ops.
__device__ __forceinline__ v2f mulrn2(v2f a, v2f b) {
#pragma clang fp contract(off)
  return a * b;
}
__device__ __forceinline__ v2f addrn2(v2f a, v2f b) {
#pragma clang fp contract(off)
  return a + b;
}

// Fused packed MAC, VOP3P with op_sel broadcast of the x-half (semantics
// hardware-validated: per-element IEEE rn mul + rn add, same as scalar).
// acc tied "+v" (no result copy), scratch early-clobber, inputs are aligned
// v2f pairs loaded directly from LDS (no repack movs).
__device__ __forceinline__ void pkmac_lo(v2f& acc, v2f w, v2f x) {
  v2f t;
  asm("v_pk_mul_f32 %1, %2, %3 op_sel:[0,0] op_sel_hi:[1,0]\n\t"
      "v_pk_add_f32 %0, %0, %1"
      : "+v"(acc), "=&v"(t) : "v"(w), "v"(x));
}
__device__ __forceinline__ void pkmac_hi(v2f& acc, v2f w, v2f x) {
  v2f t;
  asm("v_pk_mul_f32 %1, %2, %3 op_sel:[0,1] op_sel_hi:[1,1]\n\t"
      "v_pk_add_f32 %0, %0, %1"
      : "+v"(acc), "=&v"(t) : "v"(w), "v"(x));
}

// ---------------------------------------------------------------------------
// kNN, quarter-parallel: 1 row per thread (scalar distance; per-element ops
// identical to the previous packed path -> bit-same d2). Wave = 32 rows x 2
// halves (partner lane^32); block = 4 waves = 128 rows x 1 seg, 16 KB LDS.
// Sorted-20 maintained via a v_med3_f32 insertion network: for sorted-asc
// da[] and candidate v, new da[t] = med3(v, da[t-1], da[t]) (t descending),
// da[0] = min(v, da[0]) -- exact selection identity (verified all cases incl.
// v >= da[19] no-op and duplicates; med3 returns one of its inputs, and d2
// can never be -0.0 under rn-subtract, so bit patterns are preserved).
// 20 independent ops/insert vs the 40-op serial bubble. Exact segment 20th =
// Batcher merge theta = max_i min(a_i, b_{19-i}) via shfl_xor(.,32) (pure
// selection -> bit-identical). Recovery appends front (half 0) / back
// (half 1) into the shared CAP-slot region; counts = front | back<<16.
// ---------------------------------------------------------------------------
__global__ __launch_bounds__(256) void knn_scan(
    const float* __restrict__ pts,
    float* __restrict__ listd, int* __restrict__ listj, int* __restrict__ counts) {
  __shared__ float4 sp[SEGLEN];  // 16 KB: (x, y, z, sq) for 1 segment
  const int b = blockIdx.z;
  const int tid = threadIdx.x;
  const float* px = pts + (size_t)b * 3 * N;
  const int seg = blockIdx.y;
  const int cb0 = seg * SEGLEN;  // candidate base
  for (int i = tid; i < SEGLEN; i += 256) {
    const float x = px[cb0 + i];
    const float y = px[N + cb0 + i];
    const float z = px[2 * N + cb0 + i];
    const float sq = addrn(addrn(mulrn(x, x), mulrn(y, y)), mulrn(z, z));
    sp[i] = make_float4(x, y, z, sq);
  }
  __syncthreads();
  const int lane = tid & 63;
  const int rl = lane & 31;            // row lane
  const int h2 = lane >> 5;            // half of the segment
  const int wid = tid >> 6;            // wave 0..3
  const int row = blockIdx.x * 128 + wid * 32 + rl;
  // query from global (identical arithmetic to staging -> bit-same sq)
  const float ax = px[row], ay = px[N + row], az = px[2 * N + row];
  const float qw = addrn(addrn(mulrn(ax, ax), mulrn(ay, ay)), mulrn(az, az));
  float da[KNN];
#pragma unroll
  for (int t = 0; t < KNN; ++t) da[t] = 3.0e38f;
  const int j0 = h2 * HSEG;  // LDS-local candidate base
#pragma unroll 2
  for (int jj = 0; jj < HSEG; ++jj) {
    const float4 c = sp[j0 + jj];
    float t0 = mulrn(ax, c.x);
    t0 = addrn(t0, mulrn(ay, c.y));
    t0 = addrn(t0, mulrn(az, c.z));
    const float d2 = subrn(addrn(qw, c.w), mulrn(2.0f, t0));
    if (d2 < da[KNN - 1]) {
      // med3 insertion network: descending t uses original da[t-1]; all ops
      // independent given d2 (no serial chain).
#pragma unroll
      for (int t = KNN - 1; t >= 1; --t)
        da[t] = __builtin_amdgcn_fmed3f(d2, da[t - 1], da[t]);
      da[0] = fminf(d2, da[0]);
    }
  }
  // exact segment 20th via bitonic cross-half merge (partner = lane ^ 32);
  // pure min/max selection over the same multiset -> both lanes get the same
  // bit pattern, equal to the single-scan 20th.
  float tha = -3.0e38f;
#pragma unroll
  for (int i = 0; i < KNN; ++i)
    tha = fmaxf(tha, fminf(da[i], __shfl_xor(da[KNN - 1 - i], 32)));
  float* lda = listd + (size_t)(b * N + row) * SLOTS + seg * CAP;
  int* lja = listj + (size_t)(b * N + row) * SLOTS + seg * CAP;
  const int jg0 = cb0 + j0;  // global candidate index base
  int ca = 0;
#pragma unroll 2
  for (int jj = 0; jj < HSEG; ++jj) {
    const float4 c = sp[j0 + jj];
    float t0 = mulrn(ax, c.x);
    t0 = addrn(t0, mulrn(ay, c.y));
    t0 = addrn(t0, mulrn(az, c.z));
    const float d2 = subrn(addrn(qw, c.w), mulrn(2.0f, t0));
    if (d2 <= tha && ca < CAP) {
      const int sl = h2 ? (CAP - 1 - ca) : ca;
      lda[sl] = d2;
      lja[sl] = jg0 + jj;
      ++ca;
    }
  }
  const int oa = __shfl_xor(ca, 32);
  if (h2 == 0)  // pack: front count | back count << 16
    counts[(b * N + row) * NSEG + seg] = ca | (oa << 16);
}

// Merge: per row, select 20 lexicographically-smallest (dist, j) from <=96
// candidates via monotone uint64 keys. counts packed front|back<<16; valid
// slots are [0, front) u [CAP-back, CAP).
// 4-thread-per-row cooperative selection: threads 4rr..4rr+3 (same wave) each
// scan a 24-slot strip; global min via 2x shfl_xor u64-min (associative, keys
// unique -> identical selection sequence to the serial scan); unique owner
// marks its slot (in-wave DS program order makes the mark visible to the next
// iteration without barriers). 256-thread blocks: 2 waves/SIMD vs 0.5 before.
__global__ __launch_bounds__(256) void knn_merge(
    const float* __restrict__ listd, const int* __restrict__ listj,
    const int* __restrict__ counts, int* __restrict__ idxout) {
  __shared__ unsigned long long keys[64][SLOTS + 1];  // 49,664 B
  const int r0 = blockIdx.x * 64;
  const int t = threadIdx.x;
  for (int i = t; i < 64 * SLOTS; i += 256) {
    const int rr = i / SLOTS;
    const int sl = i % SLOTS;
    const int seg = sl / CAP;
    const int e = sl % CAP;
    const int row = r0 + rr;
    unsigned long long key = 0xFFFFFFFE00000000ULL | (unsigned)row;  // fallback: self
    const int cp = counts[row * NSEG + seg];
    if (e < (cp & 0xFFFF) || e >= CAP - (cp >> 16)) {
      const float d = listd[(size_t)row * SLOTS + sl];
      unsigned ub = __float_as_uint(d);
      ub ^= (ub & 0x80000000u) ? 0xFFFFFFFFu : 0x80000000u;
      key = ((unsigned long long)ub << 32) | (unsigned)listj[(size_t)row * SLOTS + sl];
    }
    keys[rr][sl] = key;
  }
  __syncthreads();
  const int g4 = t & 3;        // strip within row
  const int rr = t >> 2;       // row slot 0..63
  const int sbase = g4 * 24;   // 4 strips x 24 = 96 slots
  int* outp = idxout + (size_t)(r0 + rr) * KNN;
  for (int sel = 0; sel < KNN; ++sel) {
    unsigned long long best = ~0ULL;
    int bs = sbase;
#pragma unroll
    for (int e = 0; e < 24; ++e) {
      const unsigned long long k2 = keys[rr][sbase + e];
      if (k2 < best) { best = k2; bs = sbase + e; }
    }
    unsigned long long m = best;
    {
      const unsigned long long o1 = __shfl_xor(m, 1);
      m = (o1 < m) ? o1 : m;
      const unsigned long long o2 = __shfl_xor(m, 2);
      m = (o2 < m) ? o2 : m;
    }
    if (best == m) keys[rr][bs] = ~0ULL;  // keys unique -> single owner
    if (g4 == 0) outp[sel] = (int)(m & 0xFFFFFFFFu);
  }
}

// ---------------------------------------------------------------------------
// EdgeConv, BIT-EXACT serial semantics per (o, n, k):
//   y = sum_c W1[o,c]*x_i[c]  (prefix P)  then  += W2[o,c]*(x_j[c]-x_i[c]).
// ---------------------------------------------------------------------------

// Layer 1 (cin=3): wave per point, lane = output o.
__global__ __launch_bounds__(256) void ec_layer1(
    const float* __restrict__ pts, const int* __restrict__ idx,
    const float* __restrict__ w, const float* __restrict__ s,
    const float* __restrict__ bi, float* __restrict__ cat) {
  const int b = blockIdx.y;
  const int n = blockIdx.x * 4 + (threadIdx.x >> 6);
  const int o = threadIdx.x & 63;
  const float* p = pts + (size_t)b * 3 * N;
  const float xix = p[n], xiy = p[N + n], xiz = p[2 * N + n];
  const float* wr = w + o * 6;
  const float w0 = wr[0], w1 = wr[1], w2 = wr[2], w3 = wr[3], w4 = wr[4], w5 = wr[5];
  float P = mulrn(w0, xix);
  P = addrn(P, mulrn(w1, xiy));
  P = addrn(P, mulrn(w2, xiz));
  const float so = s[o], bo = bi[o];
  const int* ip = idx + ((size_t)b * N + n) * KNN;
  float m = 0.0f;
#pragma unroll 4
  for (int k = 0; k < KNN; ++k) {
    int j = ip[k];
    if ((unsigned)j >= (unsigned)N) j = n;
    const float ex = subrn(p[j], xix);
    const float ey = subrn(p[N + j], xiy);
    const float ez = subrn(p[2 * N + j], xiz);
    float acc = addrn(P, mulrn(w3, ex));
    acc = addrn(acc, mulrn(w4, ey));
    acc = addrn(acc, mulrn(w5, ez));
    m = fmaxf(m, addrn(mulrn(so, acc), bo));
  }
  cat[((size_t)b * N + n) * 320 + o] = m;
}

// 64-in EdgeConv as edge-GEMM: 8 points x 20 slots = 160 edges (no dups),
// OH output halves (1 -> 64 outs; 2 -> fused 128 outs, e staged ONCE).
// Edge frags: i=0,1 quads (edge=64i+4g+e) + i=2 pairs (edge=128+2g+e).
// MAC loop: fused-asm pkmac with op_sel broadcast; e-frags and W read as
// aligned v2f pairs (no broadcast-construction movs). Per-accumulator op
// order unchanged (ascending kc, k; mul-then-add) -> bit-exact.
// gmax epilogue at pair granularity: row = edge>>1 (80 rows), point p owns
// rows 10p..10p+9.
template <int OH>
__global__ __launch_bounds__(256) void ec_edge(
    const float* __restrict__ cat, int inoff, const int* __restrict__ idx,
    const float* __restrict__ w, const float* __restrict__ s,
    const float* __restrict__ bi, float* __restrict__ catout, int outoff) {
  constexpr int EST = 164;         // e-chunk row stride
  constexpr int RS = 68;           // gmax row stride
  constexpr int PS = 64 * OH + 4;  // Pt row stride
  constexpr int WS = 64 * OH + 4;  // Wl2 row stride
  __shared__ float U[80 * RS];     // 21.76 KB multi-purpose (W1 / e-chunk / gmax)
  __shared__ float xis[8][64];     // 2 KB
  __shared__ float Pt[8 * PS];
  __shared__ float Wl2[16 * WS];
  __shared__ int jl[160];
  const int t = threadIdx.x;
  const int b = blockIdx.y;
  const int n0 = blockIdx.x * 8;
  const size_t bN = (size_t)b * N;

  // stage xis + jl
#pragma unroll
  for (int q = 0; q < 2; ++q) {
    const int p = (t >> 6) + 4 * q;
    const int c = t & 63;
    xis[p][c] = cat[(bN + n0 + p) * 320 + inoff + c];
  }
  if (t < 160) {
    const int p = t / 20;
    const int k = t % 20;
    int j = idx[(bN + n0 + p) * KNN + k];
    if ((unsigned)j >= (unsigned)N) j = n0 + p;  // firewall
    jl[t] = j;
  }
  __syncthreads();

  // prefix P per output-half (W1 staged through U, stride 66 -> float2 reads)
#pragma unroll
  for (int ho = 0; ho < OH; ++ho) {
#pragma unroll
    for (int q = 0; q < 16; ++q) {
      const int l = t + 256 * q;
      U[(l >> 6) * 66 + (l & 63)] = w[(ho * 64 + (l >> 6)) * 128 + (l & 63)];
    }
    __syncthreads();
    {
      const int o = t & 63;
      const int p0 = t >> 6;
      const float2* wq = (const float2*)&U[o * 66];
      const float2* x0 = (const float2*)&xis[p0][0];
      const float2* x1 = (const float2*)&xis[p0 + 4][0];
      float2 wv = wq[0];
      float2 a0 = x0[0];
      float2 a1 = x1[0];
      float P0 = mulrn(wv.x, a0.x);
      float P1 = mulrn(wv.x, a1.x);
      P0 = addrn(P0, mulrn(wv.y, a0.y));
      P1 = addrn(P1, mulrn(wv.y, a1.y));
#pragma unroll
      for (int c2 = 1; c2 < 32; ++c2) {
        wv = wq[c2];
        a0 = x0[c2];
        a1 = x1[c2];
        P0 = addrn(P0, mulrn(wv.x, a0.x));
        P1 = addrn(P1, mulrn(wv.x, a1.x));
        P0 = addrn(P0, mulrn(wv.y, a0.y));
        P1 = addrn(P1, mulrn(wv.y, a1.y));
      }
      Pt[p0 * PS + ho * 64 + o] = P0;
      Pt[(p0 + 4) * PS + ho * 64 + o] = P1;
    }
    __syncthreads();
  }

  const int g = t & 15;  // edge-frag lane
  const int h = t >> 4;  // output-frag lane: outputs 64*ho + 4h + u
  v2f a4[2][4][2 * OH];  // quad frags (i=0,1)
  v2f a2p[2][2 * OH];    // pair frag (i=2)
#pragma unroll
  for (int i = 0; i < 2; ++i) {
    const int p = (64 * i + 4 * g) / 20;
#pragma unroll
    for (int ho = 0; ho < OH; ++ho) {
      const float4 Pv = *(const float4*)&Pt[p * PS + ho * 64 + 4 * h];
#pragma unroll
      for (int e = 0; e < 4; ++e) {
        a4[i][e][2 * ho] = (v2f){Pv.x, Pv.y};
        a4[i][e][2 * ho + 1] = (v2f){Pv.z, Pv.w};
      }
    }
  }
  {
    const int p = (128 + 2 * g) / 20;
#pragma unroll
    for (int ho = 0; ho < OH; ++ho) {
      const float4 Pv = *(const float4*)&Pt[p * PS + ho * 64 + 4 * h];
#pragma unroll
      for (int e = 0; e < 2; ++e) {
        a2p[e][2 * ho] = (v2f){Pv.x, Pv.y};
        a2p[e][2 * ho + 1] = (v2f){Pv.z, Pv.w};
      }
    }
  }

  // K chunks: stage Wl2 + e-chunk, then pure MAC phase (ascending c)
  for (int kc = 0; kc < 64; kc += 16) {
#pragma unroll
    for (int ho = 0; ho < OH; ++ho) {
      const int o = t >> 2;
      const int cq = t & 3;
      const float4 wv = *(const float4*)&w[(ho * 64 + o) * 128 + 64 + kc + 4 * cq];
      Wl2[(4 * cq + 0) * WS + ho * 64 + o] = wv.x;
      Wl2[(4 * cq + 1) * WS + ho * 64 + o] = wv.y;
      Wl2[(4 * cq + 2) * WS + ho * 64 + o] = wv.z;
      Wl2[(4 * cq + 3) * WS + ho * 64 + o] = wv.w;
    }
#pragma unroll
    for (int q = 0; q < 3; ++q) {
      const int sl = 64 * q + (t >> 2);
      const int cq = t & 3;
      if (sl < 160) {
        const int p = sl / 20;
        const int j = jl[sl];
        const float4 xj = *(const float4*)&cat[(bN + j) * 320 + inoff + kc + 4 * cq];
        const float4 xv = *(const float4*)&xis[p][kc + 4 * cq];
        U[(4 * cq + 0) * EST + sl] = subrn(xj.x, xv.x);
        U[(4 * cq + 1) * EST + sl] = subrn(xj.y, xv.y);
        U[(4 * cq + 2) * EST + sl] = subrn(xj.z, xv.z);
        U[(4 * cq + 3) * EST + sl] = subrn(xj.w, xv.w);
      }
    }
    __syncthreads();
#pragma unroll
    for (int k = 0; k < 16; ++k) {
      // e-fragments as aligned v2f pairs (edge pairs {4g,4g+1} / {4g+2,4g+3})
      const v2f e0lo = *(const v2f*)&U[k * EST + 4 * g];
      const v2f e0hi = *(const v2f*)&U[k * EST + 4 * g + 2];
      const v2f e1lo = *(const v2f*)&U[k * EST + 64 + 4 * g];
      const v2f e1hi = *(const v2f*)&U[k * EST + 64 + 4 * g + 2];
      const v2f e2 = *(const v2f*)&U[k * EST + 128 + 2 * g];
#pragma unroll
      for (int ho = 0; ho < OH; ++ho) {
        const v2f w01 = *(const v2f*)&Wl2[k * WS + ho * 64 + 4 * h];
        const v2f w23 = *(const v2f*)&Wl2[k * WS + ho * 64 + 4 * h + 2];
        // i=0: edges 4g..4g+3 -> lo/hi broadcasts of e0lo, e0hi
        pkmac_lo(a4[0][0][2 * ho], w01, e0lo);
        pkmac_lo(a4[0][0][2 * ho + 1], w23, e0lo);
        pkmac_hi(a4[0][1][2 * ho], w01, e0lo);
        pkmac_hi(a4[0][1][2 * ho + 1], w23, e0lo);
        pkmac_lo(a4[0][2][2 * ho], w01, e0hi);
        pkmac_lo(a4[0][2][2 * ho + 1], w23, e0hi);
        pkmac_hi(a4[0][3][2 * ho], w01, e0hi);
        pkmac_hi(a4[0][3][2 * ho + 1], w23, e0hi);
        // i=1: edges 64+4g..64+4g+3
        pkmac_lo(a4[1][0][2 * ho], w01, e1lo);
        pkmac_lo(a4[1][0][2 * ho + 1], w23, e1lo);
        pkmac_hi(a4[1][1][2 * ho], w01, e1lo);
        pkmac_hi(a4[1][1][2 * ho + 1], w23, e1lo);
        pkmac_lo(a4[1][2][2 * ho], w01, e1hi);
        pkmac_lo(a4[1][2][2 * ho + 1], w23, e1hi);
        pkmac_hi(a4[1][3][2 * ho], w01, e1hi);
        pkmac_hi(a4[1][3][2 * ho + 1], w23, e1hi);
        // i=2: edges 128+2g, 128+2g+1
        pkmac_lo(a2p[0][2 * ho], w01, e2);
        pkmac_lo(a2p[0][2 * ho + 1], w23, e2);
        pkmac_hi(a2p[1][2 * ho], w01, e2);
        pkmac_hi(a2p[1][2 * ho + 1], w23, e2);
      }
    }
    __syncthreads();  // U readers done before restage / gmax
  }

  // epilogue per half: relu(s*acc+b) per edge, pair-max rows, point reduce
#pragma unroll
  for (int ho = 0; ho < OH; ++ho) {
    const float4 sv = *(const float4*)&s[ho * 64 + 4 * h];
    const float4 bv = *(const float4*)&bi[ho * 64 + 4 * h];
    const float sc[4] = {sv.x, sv.y, sv.z, sv.w};
    const float bc[4] = {bv.x, bv.y, bv.z, bv.w};
#pragma unroll
    for (int i = 0; i < 2; ++i) {
#pragma unroll
      for (int ep = 0; ep < 2; ++ep) {
        const int row = 32 * i + 2 * g + ep;
        float gm[4] = {0.f, 0.f, 0.f, 0.f};
#pragma unroll
        for (int ee = 0; ee < 2; ++ee) {
          const int e = 2 * ep + ee;
#pragma unroll
          for (int u = 0; u < 4; ++u) {
            const v2f a = a4[i][e][2 * ho + (u >> 1)];
            const float av = (u & 1) ? a.y : a.x;
            gm[u] = fmaxf(gm[u], fmaxf(addrn(mulrn(sc[u], av), bc[u]), 0.f));
          }
        }
        *(float4*)&U[row * RS + 4 * h] = make_float4(gm[0], gm[1], gm[2], gm[3]);
      }
    }
    {
      const int row = 64 + g;
      float gm[4] = {0.f, 0.f, 0.f, 0.f};
#pragma unroll
      for (int e = 0; e < 2; ++e) {
#pragma unroll
        for (int u = 0; u < 4; ++u) {
          const v2f a = a2p[e][2 * ho + (u >> 1)];
          const float av = (u & 1) ? a.y : a.x;
          gm[u] = fmaxf(gm[u], fmaxf(addrn(mulrn(sc[u], av), bc[u]), 0.f));
        }
      }
      *(float4*)&U[row * RS + 4 * h] = make_float4(gm[0], gm[1], gm[2], gm[3]);
    }
    __syncthreads();
#pragma unroll
    for (int q = 0; q < 2; ++q) {
      const int o = t & 63;
      const int p = (t >> 6) + 4 * q;
      const float* ur = &U[(10 * p) * RS + o];
      float m = ur[0];
#pragma unroll
      for (int r = 1; r < 10; ++r) m = fmaxf(m, ur[r * RS]);
      catout[(bN + n0 + p) * 320 + outoff + ho * 64 + o] = m;
    }
    if (ho + 1 < OH) __syncthreads();  // pass 2 rewrites U
  }
}

// ---------------------------------------------------------------------------
// Local layer: loc[o][n] = relu(s*<W[o,:],cat[n,:]>+b), serial ascending c.
// KC=16, DOUBLE-BUFFERED LDS (1 barrier/chunk; stage-write overlapped after
// MAC) + fused-asm packed MACs (tied acc, op_sel broadcast) + direct v2f LDS
// loads at pm-unswizzled offsets. Grid transposed (ptile fastest) so the 8
// q-tile readers of each cat ptile land on the same XCD L2.
// ---------------------------------------------------------------------------
__global__ __launch_bounds__(256) void local_gemm(
    const float* __restrict__ cat, const float* __restrict__ w,
    const float* __restrict__ s, const float* __restrict__ bi,
    float* __restrict__ pval, int* __restrict__ pidx) {
  constexpr int KC = 16;
  constexpr int XS = 132;
  constexpr int BUF = KC * XS * 2;     // floats per buffer (xs + wsd)
  __shared__ float smem[2 * BUF];      // 33,792 B (double-buffered)
  const int t = threadIdx.x;
  const int q0 = blockIdx.y * 128;     // transposed grid: y = q-tile
  const int ptile = blockIdx.x;        //                  x = point tile
  const size_t pt0 = (size_t)ptile * 128;
  const int g = t & 15;
  const int h = t >> 4;
  v2f acc2[2][2][4][2];
#pragma unroll
  for (int ep = 0; ep < 2; ++ep)
#pragma unroll
    for (int fp = 0; fp < 2; ++fp)
#pragma unroll
      for (int pi = 0; pi < 4; ++pi)
#pragma unroll
        for (int u = 0; u < 2; ++u) acc2[ep][fp][pi][u] = (v2f){0.f, 0.f};

  const int lk = t & 15;               // k-row within chunk
  const int lp = t >> 4;               // column group 0..15
  const int px = ((lk >> 3) & 1) << 1;  // store swizzle: 0 or 2
  const float* catp = cat + pt0 * 320 + lk;
  const float* wp = w + (size_t)q0 * 320 + lk;
  float rx[8], rw[8];
#pragma unroll
  for (int i = 0; i < 8; ++i) rx[i] = catp[(size_t)(lp + 16 * i) * 320];
#pragma unroll
  for (int i = 0; i < 8; ++i) rw[i] = wp[(size_t)(lp + 16 * i) * 320];
  // prologue: stage chunk 0 into buffer 0
  {
    float* xs0 = smem;
    float* ws0 = smem + KC * XS;
#pragma unroll
    for (int i = 0; i < 8; ++i) xs0[lk * XS + ((lp + 16 * i) ^ px)] = rx[i];
#pragma unroll
    for (int i = 0; i < 8; ++i) ws0[lk * XS + ((lp + 16 * i) ^ px)] = rw[i];
  }

#pragma unroll 2
  for (int ch = 0; ch < 20; ++ch) {
    const int par = ch & 1;
    const float* xsr = smem + par * BUF;
    const float* wsr = xsr + KC * XS;
    if (ch + 1 < 20) {  // issue next-chunk global loads (land during MAC)
      const int ko = (ch + 1) * KC;
#pragma unroll
      for (int i = 0; i < 8; ++i) rx[i] = catp[(size_t)(lp + 16 * i) * 320 + ko];
#pragma unroll
      for (int i = 0; i < 8; ++i) rw[i] = wp[(size_t)(lp + 16 * i) * 320 + ko];
    }
    __syncthreads();  // buf[par] writes (prev iter / prologue) visible
#pragma unroll
    for (int k = 0; k < KC; ++k) {
      const int pm2 = ((k >> 3) & 1) << 1;  // 0 or 2, compile-time under unroll
      const float* wrow = &wsr[k * XS];
      const float* xrow = &xsr[k * XS];
      // logical pairs at pm-unswizzled physical offsets (aligned v2f loads)
      v2f wA[2], wB[2];  // wA -> acc u=0 (logical cols 4h,4h+1), wB -> u=1
#pragma unroll
      for (int fp = 0; fp < 2; ++fp) {
        wA[fp] = *(const v2f*)&wrow[64 * fp + 4 * h + pm2];
        wB[fp] = *(const v2f*)&wrow[64 * fp + 4 * h + (2 - pm2)];
      }
#pragma unroll
      for (int ep = 0; ep < 2; ++ep) {
        const v2f xq0 = *(const v2f*)&xrow[64 * ep + 4 * g + pm2];        // pts 0,1
        const v2f xq1 = *(const v2f*)&xrow[64 * ep + 4 * g + (2 - pm2)];  // pts 2,3
#pragma unroll
        for (int fp = 0; fp < 2; ++fp) {
          pkmac_lo(acc2[ep][fp][0][0], wA[fp], xq0);
          pkmac_lo(acc2[ep][fp][0][1], wB[fp], xq0);
          pkmac_hi(acc2[ep][fp][1][0], wA[fp], xq0);
          pkmac_hi(acc2[ep][fp][1][1], wB[fp], xq0);
          pkmac_lo(acc2[ep][fp][2][0], wA[fp], xq1);
          pkmac_lo(acc2[ep][fp][2][1], wB[fp], xq1);
          pkmac_hi(acc2[ep][fp][3][0], wA[fp], xq1);
          pkmac_hi(acc2[ep][fp][3][1], wB[fp], xq1);
        }
      }
    }
    if (ch + 1 < 20) {  // stage next chunk into the other buffer (no barrier:
      float* xsw = smem + (par ^ 1) * BUF;  // readers of buf[par^1] finished
      float* wsw = xsw + KC * XS;           // before barrier at top of ch)
#pragma unroll
      for (int i = 0; i < 8; ++i) xsw[lk * XS + ((lp + 16 * i) ^ px)] = rx[i];
#pragma unroll
      for (int i = 0; i < 8; ++i) wsw[lk * XS + ((lp + 16 * i) ^ px)] = rw[i];
    }
  }
  // epilogue: relu(s*acc+b), per-thread argmax over 8 points ascending
  const int bb = ptile >> 5;
  const int blk = ptile & 31;
  float mv[8];
  int mi[8];
#pragma unroll
  for (int fp = 0; fp < 2; ++fp)
#pragma unroll
    for (int c = 0; c < 4; ++c) {
      const int f = fp * 4 + c;
      const int cl = 64 * fp + 4 * h + c;
      const float sc = s[q0 + cl];
      const float bc = bi[q0 + cl];
      mv[f] = -1.f;
      mi[f] = 0;
#pragma unroll
      for (int ep = 0; ep < 2; ++ep)
#pragma unroll
        for (int pi = 0; pi < 4; ++pi) {
          const v2f a2 = acc2[ep][fp][pi][c >> 1];
          const float a = (c & 1) ? a2.y : a2.x;
          const float v = fmaxf(addrn(mulrn(sc, a), bc), 0.f);
          if (v > mv[f]) { mv[f] = v; mi[f] = 64 * ep + 4 * g + pi; }
        }
    }
  __syncthreads();
  float* smv = smem;                       // 2112 floats
  int* smi = (int*)(smem + 16 * 132);      // next 2112 ints
#pragma unroll
  for (int fp = 0; fp < 2; ++fp)
#pragma unroll
    for (int c = 0; c < 4; ++c) {
      const int cl = 64 * fp + 4 * h + c;
      smv[g * 132 + cl] = mv[fp * 4 + c];
      smi[g * 132 + cl] = mi[fp * 4 + c];
    }
  __syncthreads();
  if (t < 128) {
    float best = smv[t];
    int bidx = smi[t];
    for (int gg = 1; gg < 16; ++gg) {
      const float v = smv[gg * 132 + t];
      const int vi = smi[gg * 132 + t];
      // candidates g-interleaved: ties resolve to SMALLEST point idx
      if (v > best || (v == best && vi < bidx)) { best = v; bidx = vi; }
    }
    const int n_l = blk * 128 + bidx;
    const size_t po = ((size_t)bb * 1024 + q0 + t) * 32 + blk;
    pval[po] = best;
    pidx[po] = n_l;
  }
}

__global__ __launch_bounds__(256) void final_reduce(
    const float* __restrict__ pval, const int* __restrict__ pidx,
    float* __restrict__ glob, float* __restrict__ oidx) {
  const int o = blockIdx.x * 256 + threadIdx.x;  // 8192 = B*1024
  const float* pv = pval + (size_t)o * 32;
  const int* pi = pidx + (size_t)o * 32;
  float best = pv[0];
  int bi = pi[0];
  for (int k = 1; k < 32; ++k) {
    const float v = pv[k];
    // tiles are ascending disjoint point ranges: strict > = first occurrence
    if (v > best) { best = v; bi = pi[k]; }
  }
  glob[o] = best;
  oidx[o] = (float)bi;
}

template <int KIN, int OUTS>
__global__ __launch_bounds__(256) void dense_wave(
    const float* __restrict__ in, const float* __restrict__ w,
    const float* __restrict__ s, const float* __restrict__ bi,
    float* __restrict__ out) {
  const int wid = (blockIdx.x * 256 + threadIdx.x) >> 6;
  const int lane = threadIdx.x & 63;
  const int b = wid / OUTS;
  const int o = wid % OUTS;
  const float* ip = in + (size_t)b * KIN;
  const float* wr = w + (size_t)o * KIN;
  float acc = 0.f;
  for (int k = lane; k < KIN; k += 64) acc = fmaf(wr[k], ip[k], acc);
#pragma unroll
  for (int off = 32; off; off >>= 1) acc += __shfl_down(acc, off);
  if (lane == 0) out[(size_t)b * OUTS + o] = fmaxf(fmaf(s[o], acc, bi[o]), 0.f);
}

extern "C" void kernel_launch(void* const* d_in, const int* in_sizes, int n_in,
                              void* d_out, int out_size, void* d_ws, size_t ws_size,
                              hipStream_t stream) {
  (void)in_sizes; (void)n_in; (void)out_size; (void)ws_size;
  const float* pts = (const float*)d_in[0];
  const float* ec_w[4] = {(const float*)d_in[1], (const float*)d_in[4],
                          (const float*)d_in[7], (const float*)d_in[10]};
  const float* ec_s[4] = {(const float*)d_in[2], (const float*)d_in[5],
                          (const float*)d_in[8], (const float*)d_in[11]};
  const float* ec_b[4] = {(const float*)d_in[3], (const float*)d_in[6],
                          (const float*)d_in[9], (const float*)d_in[12]};
  const float* local_w = (const float*)d_in[13];
  const float* local_s = (const float*)d_in[14];
  const float* local_b = (const float*)d_in[15];
  const float* g_w0 = (const float*)d_in[16];
  const float* g_s0 = (const float*)d_in[17];
  const float* g_b0 = (const float*)d_in[18];
  const float* g_w1 = (const float*)d_in[19];
  const float* g_s1 = (const float*)d_in[20];
  const float* g_b1 = (const float*)d_in[21];

  char* ws = (char*)d_ws;
  int* idxbuf = (int*)(ws + OFF_IDX);
  float* cat = (float*)(ws + OFF_CAT);
  float* pv = (float*)(ws + OFF_PV);
  int* pi = (int*)(ws + OFF_PI);
  float* glob = (float*)(ws + OFF_GLOB);
  float* hbuf = (float*)(ws + OFF_H);
  float* listd = (float*)(ws + OFF_LD);
  int* listj = (int*)(ws + OFF_LJ);
  int* counts = (int*)(ws + OFF_CNT);
  float* outv = (float*)d_out;   // [8][256]  fp32
  float* oidx = outv + 2048;     // [8][1024] fp32 (indices as floats)

  knn_scan<<<dim3(32, 4, 8), 256, 0, stream>>>(pts, listd, listj, counts);
  knn_merge<<<dim3(512), 256, 0, stream>>>(listd, listj, counts, idxbuf);

  // layer 1 (3 -> 64)
  ec_layer1<<<dim3(1024, 8), 256, 0, stream>>>(pts, idxbuf, ec_w[0], ec_s[0], ec_b[0], cat);
  // layer 2 (64 -> 64)
  ec_edge<1><<<dim3(512, 8), 256, 0, stream>>>(cat, 0, idxbuf, ec_w[1], ec_s[1], ec_b[1], cat, 64);
  // layer 3 (64 -> 64)
  ec_edge<1><<<dim3(512, 8), 256, 0, stream>>>(cat, 64, idxbuf, ec_w[2], ec_s[2], ec_b[2], cat, 128);
  // layer 4 (64 -> 128), fused both output halves, e staged once
  ec_edge<2><<<dim3(512, 8), 256, 0, stream>>>(cat, 128, idxbuf, ec_w[3], ec_s[3], ec_b[3], cat, 192);

  // transposed grid: ptile fastest -> same-ptile q-tiles co-located per XCD
  local_gemm<<<dim3(256, 8), 256, 0, stream>>>(cat, local_w, local_s, local_b, pv, pi);
  final_reduce<<<dim3(32), 256, 0, stream>>>(pv, pi, glob, oidx);
  dense_wave<1024, 512><<<dim3(1024), 256, 0, stream>>>(glob, g_w0, g_s0, g_b0, hbuf);
  dense_wave<512, 256><<<dim3(512), 256, 0, stream>>>(hbuf, g_w1, g_s1, g_b1, outv);
}

// Round 11
// 1105.551 us; speedup vs baseline: 1.2581x; 1.0846x over previous
//
#include <hip/hip_runtime.h>
#include <hip/hip_bf16.h>

namespace {
constexpr int B = 8;
constexpr int N = 4096;
constexpr int KNN = 20;
constexpr int NSEG = 4;
constexpr int SEGLEN = N / NSEG;   // 1024
constexpr int HSEG = SEGLEN / 2;   // 512: half-segment per thread
constexpr int CAP = 24;
constexpr int SLOTS = NSEG * CAP;  // 96

// workspace layout (bytes)
constexpr size_t OFF_IDX  = 0;                          // int [B][N][KNN]
constexpr size_t SZ_IDX   = (size_t)B * N * KNN * 4;
constexpr size_t OFF_T    = OFF_IDX + SZ_IDX;           // knn scratch region
constexpr size_t SZ_T     = (size_t)B * N * 128 * 4;
constexpr size_t OFF_CAT  = OFF_T + SZ_T;               // float [B][N][320]
constexpr size_t SZ_CAT   = (size_t)B * N * 320 * 4;
constexpr size_t OFF_PV   = OFF_CAT + SZ_CAT;           // float [B][1024][32]
constexpr size_t SZ_PV    = (size_t)B * 1024 * 32 * 4;
constexpr size_t OFF_PI   = OFF_PV + SZ_PV;             // int   [B][1024][32]
constexpr size_t OFF_GLOB = OFF_PI + SZ_PV;             // float [B][1024]
constexpr size_t OFF_H    = OFF_GLOB + (size_t)B * 1024 * 4;  // float [B][512]
// knn scratch overlaid on T + head of CAT (dead once merge completes):
constexpr size_t OFF_LD   = OFF_T;                      // float [B*N][SLOTS]
constexpr size_t SZ_LD    = (size_t)B * N * SLOTS * 4;
constexpr size_t OFF_LJ   = OFF_LD + SZ_LD;             // int   [B*N][SLOTS]
constexpr size_t OFF_CNT  = OFF_LJ + SZ_LD;             // int   [B*N][NSEG]
}  // namespace

typedef float v2f __attribute__((ext_vector_type(2)));

// Non-contractable fp32 ops: bit-exact match to np's mul-then-add serial loops.
__device__ __forceinline__ float mulrn(float a, float b) {
#pragma clang fp contract(off)
  return a * b;
}
__device__ __forceinline__ float addrn(float a, float b) {
#pragma clang fp contract(off)
  return a + b;
}
__device__ __forceinline__ float subrn(float a, float b) {
#pragma clang fp contract(off)
  return a - b;
}
// Packed (v_pk_mul_f32 / v_pk_add_f32): per-element IEEE rn == scalar ops.
__device__ __forceinline__ v2f mulrn2(v2f a, v2f b) {
#pragma clang fp contract(off)
  return a * b;
}
__device__ __forceinline__ v2f addrn2(v2f a, v2f b) {
#pragma clang fp contract(off)
  return a + b;
}

// Fused packed MAC, VOP3P with op_sel broadcast of the x-half (semantics
// hardware-validated: per-element IEEE rn mul + rn add, same as scalar).
// acc tied "+v" (no result copy), scratch early-clobber, inputs are aligned
// v2f pairs loaded directly from LDS (no repack movs).
__device__ __forceinline__ void pkmac_lo(v2f& acc, v2f w, v2f x) {
  v2f t;
  asm("v_pk_mul_f32 %1, %2, %3 op_sel:[0,0] op_sel_hi:[1,0]\n\t"
      "v_pk_add_f32 %0, %0, %1"
      : "+v"(acc), "=&v"(t) : "v"(w), "v"(x));
}
__device__ __forceinline__ void pkmac_hi(v2f& acc, v2f w, v2f x) {
  v2f t;
  asm("v_pk_mul_f32 %1, %2, %3 op_sel:[0,1] op_sel_hi:[1,1]\n\t"
      "v_pk_add_f32 %0, %0, %1"
      : "+v"(acc), "=&v"(t) : "v"(w), "v"(x));
}

// ---------------------------------------------------------------------------
// kNN, quarter-parallel: 1 row per thread (scalar distance; per-element ops
// identical to the previous packed path -> bit-same d2). Wave = 32 rows x 2
// halves (partner lane^32); block = 4 waves = 128 rows x 1 seg, 16 KB LDS.
// Sorted-20 maintained via an UNCONDITIONAL v_med3_f32 insertion network:
// new da[t] = med3(d2, da[t-1], da[t]) (t descending), da[0] = min(d2,da[0]).
// When d2 >= da[19] the whole network is a bit-exact no-op (med3 returns
// da[t] since d2 >= da[19] >= da[t] >= da[t-1]), so the wave-any guard --
// taken ~98% of iterations anyway -- is deleted: straight-line 27-instr body,
// no exec-mask save/restore, and unroll-4 lets the scheduler interleave 4
// independent d2 chains with the per-t-parallel med3 lattice. d2 can never be
// -0.0 (rn-subtract yields +0) or NaN -> med3 selection is bit-preserving.
// Exact segment 20th = Batcher merge theta = max_i min(a_i, b_{19-i}) via
// shfl_xor(.,32) (pure selection -> bit-identical). Recovery appends front
// (half 0) / back (half 1) into the shared CAP-slot region;
// counts = front | back<<16.
// ---------------------------------------------------------------------------
__global__ __launch_bounds__(256) void knn_scan(
    const float* __restrict__ pts,
    float* __restrict__ listd, int* __restrict__ listj, int* __restrict__ counts) {
  __shared__ float4 sp[SEGLEN];  // 16 KB: (x, y, z, sq) for 1 segment
  const int b = blockIdx.z;
  const int tid = threadIdx.x;
  const float* px = pts + (size_t)b * 3 * N;
  const int seg = blockIdx.y;
  const int cb0 = seg * SEGLEN;  // candidate base
  for (int i = tid; i < SEGLEN; i += 256) {
    const float x = px[cb0 + i];
    const float y = px[N + cb0 + i];
    const float z = px[2 * N + cb0 + i];
    const float sq = addrn(addrn(mulrn(x, x), mulrn(y, y)), mulrn(z, z));
    sp[i] = make_float4(x, y, z, sq);
  }
  __syncthreads();
  const int lane = tid & 63;
  const int rl = lane & 31;            // row lane
  const int h2 = lane >> 5;            // half of the segment
  const int wid = tid >> 6;            // wave 0..3
  const int row = blockIdx.x * 128 + wid * 32 + rl;
  // query from global (identical arithmetic to staging -> bit-same sq)
  const float ax = px[row], ay = px[N + row], az = px[2 * N + row];
  const float qw = addrn(addrn(mulrn(ax, ax), mulrn(ay, ay)), mulrn(az, az));
  float da[KNN];
#pragma unroll
  for (int t = 0; t < KNN; ++t) da[t] = 3.0e38f;
  const int j0 = h2 * HSEG;  // LDS-local candidate base
#pragma unroll 4
  for (int jj = 0; jj < HSEG; ++jj) {
    const float4 c = sp[j0 + jj];
    float t0 = mulrn(ax, c.x);
    t0 = addrn(t0, mulrn(ay, c.y));
    t0 = addrn(t0, mulrn(az, c.z));
    const float d2 = subrn(addrn(qw, c.w), mulrn(2.0f, t0));
    // unconditional med3 insertion (no-op when d2 >= da[19], bit-exact)
#pragma unroll
    for (int t = KNN - 1; t >= 1; --t)
      da[t] = __builtin_amdgcn_fmed3f(d2, da[t - 1], da[t]);
    da[0] = fminf(d2, da[0]);
  }
  // exact segment 20th via bitonic cross-half merge (partner = lane ^ 32);
  // pure min/max selection over the same multiset -> both lanes get the same
  // bit pattern, equal to the single-scan 20th.
  float tha = -3.0e38f;
#pragma unroll
  for (int i = 0; i < KNN; ++i)
    tha = fmaxf(tha, fminf(da[i], __shfl_xor(da[KNN - 1 - i], 32)));
  float* lda = listd + (size_t)(b * N + row) * SLOTS + seg * CAP;
  int* lja = listj + (size_t)(b * N + row) * SLOTS + seg * CAP;
  const int jg0 = cb0 + j0;  // global candidate index base
  int ca = 0;
#pragma unroll 2
  for (int jj = 0; jj < HSEG; ++jj) {
    const float4 c = sp[j0 + jj];
    float t0 = mulrn(ax, c.x);
    t0 = addrn(t0, mulrn(ay, c.y));
    t0 = addrn(t0, mulrn(az, c.z));
    const float d2 = subrn(addrn(qw, c.w), mulrn(2.0f, t0));
    if (d2 <= tha && ca < CAP) {
      const int sl = h2 ? (CAP - 1 - ca) : ca;
      lda[sl] = d2;
      lja[sl] = jg0 + jj;
      ++ca;
    }
  }
  const int oa = __shfl_xor(ca, 32);
  if (h2 == 0)  // pack: front count | back count << 16
    counts[(b * N + row) * NSEG + seg] = ca | (oa << 16);
}

// Merge: per row, select 20 lexicographically-smallest (dist, j) from <=96
// candidates via monotone uint64 keys. counts packed front|back<<16; valid
// slots are [0, front) u [CAP-back, CAP).
// 4-thread-per-row cooperative selection: threads 4rr..4rr+3 (same wave) each
// scan a 24-slot strip; global min via 2x shfl_xor u64-min (associative, keys
// unique -> identical selection sequence to the serial scan); unique owner
// marks its slot (in-wave DS program order makes the mark visible to the next
// iteration without barriers). 256-thread blocks: 2 waves/SIMD vs 0.5 before.
__global__ __launch_bounds__(256) void knn_merge(
    const float* __restrict__ listd, const int* __restrict__ listj,
    const int* __restrict__ counts, int* __restrict__ idxout) {
  __shared__ unsigned long long keys[64][SLOTS + 1];  // 49,664 B
  const int r0 = blockIdx.x * 64;
  const int t = threadIdx.x;
  for (int i = t; i < 64 * SLOTS; i += 256) {
    const int rr = i / SLOTS;
    const int sl = i % SLOTS;
    const int seg = sl / CAP;
    const int e = sl % CAP;
    const int row = r0 + rr;
    unsigned long long key = 0xFFFFFFFE00000000ULL | (unsigned)row;  // fallback: self
    const int cp = counts[row * NSEG + seg];
    if (e < (cp & 0xFFFF) || e >= CAP - (cp >> 16)) {
      const float d = listd[(size_t)row * SLOTS + sl];
      unsigned ub = __float_as_uint(d);
      ub ^= (ub & 0x80000000u) ? 0xFFFFFFFFu : 0x80000000u;
      key = ((unsigned long long)ub << 32) | (unsigned)listj[(size_t)row * SLOTS + sl];
    }
    keys[rr][sl] = key;
  }
  __syncthreads();
  const int g4 = t & 3;        // strip within row
  const int rr = t >> 2;       // row slot 0..63
  const int sbase = g4 * 24;   // 4 strips x 24 = 96 slots
  int* outp = idxout + (size_t)(r0 + rr) * KNN;
  for (int sel = 0; sel < KNN; ++sel) {
    unsigned long long best = ~0ULL;
    int bs = sbase;
#pragma unroll
    for (int e = 0; e < 24; ++e) {
      const unsigned long long k2 = keys[rr][sbase + e];
      if (k2 < best) { best = k2; bs = sbase + e; }
    }
    unsigned long long m = best;
    {
      const unsigned long long o1 = __shfl_xor(m, 1);
      m = (o1 < m) ? o1 : m;
      const unsigned long long o2 = __shfl_xor(m, 2);
      m = (o2 < m) ? o2 : m;
    }
    if (best == m) keys[rr][bs] = ~0ULL;  // keys unique -> single owner
    if (g4 == 0) outp[sel] = (int)(m & 0xFFFFFFFFu);
  }
}

// ---------------------------------------------------------------------------
// EdgeConv, BIT-EXACT serial semantics per (o, n, k):
//   y = sum_c W1[o,c]*x_i[c]  (prefix P)  then  += W2[o,c]*(x_j[c]-x_i[c]).
// ---------------------------------------------------------------------------

// Layer 1 (cin=3): wave per point, lane = output o.
__global__ __launch_bounds__(256) void ec_layer1(
    const float* __restrict__ pts, const int* __restrict__ idx,
    const float* __restrict__ w, const float* __restrict__ s,
    const float* __restrict__ bi, float* __restrict__ cat) {
  const int b = blockIdx.y;
  const int n = blockIdx.x * 4 + (threadIdx.x >> 6);
  const int o = threadIdx.x & 63;
  const float* p = pts + (size_t)b * 3 * N;
  const float xix = p[n], xiy = p[N + n], xiz = p[2 * N + n];
  const float* wr = w + o * 6;
  const float w0 = wr[0], w1 = wr[1], w2 = wr[2], w3 = wr[3], w4 = wr[4], w5 = wr[5];
  float P = mulrn(w0, xix);
  P = addrn(P, mulrn(w1, xiy));
  P = addrn(P, mulrn(w2, xiz));
  const float so = s[o], bo = bi[o];
  const int* ip = idx + ((size_t)b * N + n) * KNN;
  float m = 0.0f;
#pragma unroll 4
  for (int k = 0; k < KNN; ++k) {
    int j = ip[k];
    if ((unsigned)j >= (unsigned)N) j = n;
    const float ex = subrn(p[j], xix);
    const float ey = subrn(p[N + j], xiy);
    const float ez = subrn(p[2 * N + j], xiz);
    float acc = addrn(P, mulrn(w3, ex));
    acc = addrn(acc, mulrn(w4, ey));
    acc = addrn(acc, mulrn(w5, ez));
    m = fmaxf(m, addrn(mulrn(so, acc), bo));
  }
  cat[((size_t)b * N + n) * 320 + o] = m;
}

// 64-in EdgeConv as edge-GEMM: 8 points x 20 slots = 160 edges (no dups),
// OH output halves (1 -> 64 outs; 2 -> fused 128 outs, e staged ONCE).
// Edge frags: i=0,1 quads (edge=64i+4g+e) + i=2 pairs (edge=128+2g+e).
// MAC loop: fused-asm pkmac with op_sel broadcast; e-frags and W read as
// aligned v2f pairs (no broadcast-construction movs). Per-accumulator op
// order unchanged (ascending kc, k; mul-then-add) -> bit-exact.
// gmax epilogue at pair granularity: row = edge>>1 (80 rows), point p owns
// rows 10p..10p+9.
template <int OH>
__global__ __launch_bounds__(256) void ec_edge(
    const float* __restrict__ cat, int inoff, const int* __restrict__ idx,
    const float* __restrict__ w, const float* __restrict__ s,
    const float* __restrict__ bi, float* __restrict__ catout, int outoff) {
  constexpr int EST = 164;         // e-chunk row stride
  constexpr int RS = 68;           // gmax row stride
  constexpr int PS = 64 * OH + 4;  // Pt row stride
  constexpr int WS = 64 * OH + 4;  // Wl2 row stride
  __shared__ float U[80 * RS];     // 21.76 KB multi-purpose (W1 / e-chunk / gmax)
  __shared__ float xis[8][64];     // 2 KB
  __shared__ float Pt[8 * PS];
  __shared__ float Wl2[16 * WS];
  __shared__ int jl[160];
  const int t = threadIdx.x;
  const int b = blockIdx.y;
  const int n0 = blockIdx.x * 8;
  const size_t bN = (size_t)b * N;

  // stage xis + jl
#pragma unroll
  for (int q = 0; q < 2; ++q) {
    const int p = (t >> 6) + 4 * q;
    const int c = t & 63;
    xis[p][c] = cat[(bN + n0 + p) * 320 + inoff + c];
  }
  if (t < 160) {
    const int p = t / 20;
    const int k = t % 20;
    int j = idx[(bN + n0 + p) * KNN + k];
    if ((unsigned)j >= (unsigned)N) j = n0 + p;  // firewall
    jl[t] = j;
  }
  __syncthreads();

  // prefix P per output-half (W1 staged through U, stride 66 -> float2 reads)
#pragma unroll
  for (int ho = 0; ho < OH; ++ho) {
#pragma unroll
    for (int q = 0; q < 16; ++q) {
      const int l = t + 256 * q;
      U[(l >> 6) * 66 + (l & 63)] = w[(ho * 64 + (l >> 6)) * 128 + (l & 63)];
    }
    __syncthreads();
    {
      const int o = t & 63;
      const int p0 = t >> 6;
      const float2* wq = (const float2*)&U[o * 66];
      const float2* x0 = (const float2*)&xis[p0][0];
      const float2* x1 = (const float2*)&xis[p0 + 4][0];
      float2 wv = wq[0];
      float2 a0 = x0[0];
      float2 a1 = x1[0];
      float P0 = mulrn(wv.x, a0.x);
      float P1 = mulrn(wv.x, a1.x);
      P0 = addrn(P0, mulrn(wv.y, a0.y));
      P1 = addrn(P1, mulrn(wv.y, a1.y));
#pragma unroll
      for (int c2 = 1; c2 < 32; ++c2) {
        wv = wq[c2];
        a0 = x0[c2];
        a1 = x1[c2];
        P0 = addrn(P0, mulrn(wv.x, a0.x));
        P1 = addrn(P1, mulrn(wv.x, a1.x));
        P0 = addrn(P0, mulrn(wv.y, a0.y));
        P1 = addrn(P1, mulrn(wv.y, a1.y));
      }
      Pt[p0 * PS + ho * 64 + o] = P0;
      Pt[(p0 + 4) * PS + ho * 64 + o] = P1;
    }
    __syncthreads();
  }

  const int g = t & 15;  // edge-frag lane
  const int h = t >> 4;  // output-frag lane: outputs 64*ho + 4h + u
  v2f a4[2][4][2 * OH];  // quad frags (i=0,1)
  v2f a2p[2][2 * OH];    // pair frag (i=2)
#pragma unroll
  for (int i = 0; i < 2; ++i) {
    const int p = (64 * i + 4 * g) / 20;
#pragma unroll
    for (int ho = 0; ho < OH; ++ho) {
      const float4 Pv = *(const float4*)&Pt[p * PS + ho * 64 + 4 * h];
#pragma unroll
      for (int e = 0; e < 4; ++e) {
        a4[i][e][2 * ho] = (v2f){Pv.x, Pv.y};
        a4[i][e][2 * ho + 1] = (v2f){Pv.z, Pv.w};
      }
    }
  }
  {
    const int p = (128 + 2 * g) / 20;
#pragma unroll
    for (int ho = 0; ho < OH; ++ho) {
      const float4 Pv = *(const float4*)&Pt[p * PS + ho * 64 + 4 * h];
#pragma unroll
      for (int e = 0; e < 2; ++e) {
        a2p[e][2 * ho] = (v2f){Pv.x, Pv.y};
        a2p[e][2 * ho + 1] = (v2f){Pv.z, Pv.w};
      }
    }
  }

  // K chunks: stage Wl2 + e-chunk, then pure MAC phase (ascending c)
  for (int kc = 0; kc < 64; kc += 16) {
#pragma unroll
    for (int ho = 0; ho < OH; ++ho) {
      const int o = t >> 2;
      const int cq = t & 3;
      const float4 wv = *(const float4*)&w[(ho * 64 + o) * 128 + 64 + kc + 4 * cq];
      Wl2[(4 * cq + 0) * WS + ho * 64 + o] = wv.x;
      Wl2[(4 * cq + 1) * WS + ho * 64 + o] = wv.y;
      Wl2[(4 * cq + 2) * WS + ho * 64 + o] = wv.z;
      Wl2[(4 * cq + 3) * WS + ho * 64 + o] = wv.w;
    }
#pragma unroll
    for (int q = 0; q < 3; ++q) {
      const int sl = 64 * q + (t >> 2);
      const int cq = t & 3;
      if (sl < 160) {
        const int p = sl / 20;
        const int j = jl[sl];
        const float4 xj = *(const float4*)&cat[(bN + j) * 320 + inoff + kc + 4 * cq];
        const float4 xv = *(const float4*)&xis[p][kc + 4 * cq];
        U[(4 * cq + 0) * EST + sl] = subrn(xj.x, xv.x);
        U[(4 * cq + 1) * EST + sl] = subrn(xj.y, xv.y);
        U[(4 * cq + 2) * EST + sl] = subrn(xj.z, xv.z);
        U[(4 * cq + 3) * EST + sl] = subrn(xj.w, xv.w);
      }
    }
    __syncthreads();
#pragma unroll
    for (int k = 0; k < 16; ++k) {
      // e-fragments as aligned v2f pairs (edge pairs {4g,4g+1} / {4g+2,4g+3})
      const v2f e0lo = *(const v2f*)&U[k * EST + 4 * g];
      const v2f e0hi = *(const v2f*)&U[k * EST + 4 * g + 2];
      const v2f e1lo = *(const v2f*)&U[k * EST + 64 + 4 * g];
      const v2f e1hi = *(const v2f*)&U[k * EST + 64 + 4 * g + 2];
      const v2f e2 = *(const v2f*)&U[k * EST + 128 + 2 * g];
#pragma unroll
      for (int ho = 0; ho < OH; ++ho) {
        const v2f w01 = *(const v2f*)&Wl2[k * WS + ho * 64 + 4 * h];
        const v2f w23 = *(const v2f*)&Wl2[k * WS + ho * 64 + 4 * h + 2];
        // i=0: edges 4g..4g+3 -> lo/hi broadcasts of e0lo, e0hi
        pkmac_lo(a4[0][0][2 * ho], w01, e0lo);
        pkmac_lo(a4[0][0][2 * ho + 1], w23, e0lo);
        pkmac_hi(a4[0][1][2 * ho], w01, e0lo);
        pkmac_hi(a4[0][1][2 * ho + 1], w23, e0lo);
        pkmac_lo(a4[0][2][2 * ho], w01, e0hi);
        pkmac_lo(a4[0][2][2 * ho + 1], w23, e0hi);
        pkmac_hi(a4[0][3][2 * ho], w01, e0hi);
        pkmac_hi(a4[0][3][2 * ho + 1], w23, e0hi);
        // i=1: edges 64+4g..64+4g+3
        pkmac_lo(a4[1][0][2 * ho], w01, e1lo);
        pkmac_lo(a4[1][0][2 * ho + 1], w23, e1lo);
        pkmac_hi(a4[1][1][2 * ho], w01, e1lo);
        pkmac_hi(a4[1][1][2 * ho + 1], w23, e1lo);
        pkmac_lo(a4[1][2][2 * ho], w01, e1hi);
        pkmac_lo(a4[1][2][2 * ho + 1], w23, e1hi);
        pkmac_hi(a4[1][3][2 * ho], w01, e1hi);
        pkmac_hi(a4[1][3][2 * ho + 1], w23, e1hi);
        // i=2: edges 128+2g, 128+2g+1
        pkmac_lo(a2p[0][2 * ho], w01, e2);
        pkmac_lo(a2p[0][2 * ho + 1], w23, e2);
        pkmac_hi(a2p[1][2 * ho], w01, e2);
        pkmac_hi(a2p[1][2 * ho + 1], w23, e2);
      }
    }
    __syncthreads();  // U readers done before restage / gmax
  }

  // epilogue per half: relu(s*acc+b) per edge, pair-max rows, point reduce
#pragma unroll
  for (int ho = 0; ho < OH; ++ho) {
    const float4 sv = *(const float4*)&s[ho * 64 + 4 * h];
    const float4 bv = *(const float4*)&bi[ho * 64 + 4 * h];
    const float sc[4] = {sv.x, sv.y, sv.z, sv.w};
    const float bc[4] = {bv.x, bv.y, bv.z, bv.w};
#pragma unroll
    for (int i = 0; i < 2; ++i) {
#pragma unroll
      for (int ep = 0; ep < 2; ++ep) {
        const int row = 32 * i + 2 * g + ep;
        float gm[4] = {0.f, 0.f, 0.f, 0.f};
#pragma unroll
        for (int ee = 0; ee < 2; ++ee) {
          const int e = 2 * ep + ee;
#pragma unroll
          for (int u = 0; u < 4; ++u) {
            const v2f a = a4[i][e][2 * ho + (u >> 1)];
            const float av = (u & 1) ? a.y : a.x;
            gm[u] = fmaxf(gm[u], fmaxf(addrn(mulrn(sc[u], av), bc[u]), 0.f));
          }
        }
        *(float4*)&U[row * RS + 4 * h] = make_float4(gm[0], gm[1], gm[2], gm[3]);
      }
    }
    {
      const int row = 64 + g;
      float gm[4] = {0.f, 0.f, 0.f, 0.f};
#pragma unroll
      for (int e = 0; e < 2; ++e) {
#pragma unroll
        for (int u = 0; u < 4; ++u) {
          const v2f a = a2p[e][2 * ho + (u >> 1)];
          const float av = (u & 1) ? a.y : a.x;
          gm[u] = fmaxf(gm[u], fmaxf(addrn(mulrn(sc[u], av), bc[u]), 0.f));
        }
      }
      *(float4*)&U[row * RS + 4 * h] = make_float4(gm[0], gm[1], gm[2], gm[3]);
    }
    __syncthreads();
#pragma unroll
    for (int q = 0; q < 2; ++q) {
      const int o = t & 63;
      const int p = (t >> 6) + 4 * q;
      const float* ur = &U[(10 * p) * RS + o];
      float m = ur[0];
#pragma unroll
      for (int r = 1; r < 10; ++r) m = fmaxf(m, ur[r * RS]);
      catout[(bN + n0 + p) * 320 + outoff + ho * 64 + o] = m;
    }
    if (ho + 1 < OH) __syncthreads();  // pass 2 rewrites U
  }
}

// ---------------------------------------------------------------------------
// Local layer: loc[o][n] = relu(s*<W[o,:],cat[n,:]>+b), serial ascending c.
// KC=16, DOUBLE-BUFFERED LDS (1 barrier/chunk; stage-write overlapped after
// MAC) + fused-asm packed MACs (tied acc, op_sel broadcast) + direct v2f LDS
// loads at pm-unswizzled offsets. Grid transposed (ptile fastest) so the 8
// q-tile readers of each cat ptile land on the same XCD L2.
// ---------------------------------------------------------------------------
__global__ __launch_bounds__(256) void local_gemm(
    const float* __restrict__ cat, const float* __restrict__ w,
    const float* __restrict__ s, const float* __restrict__ bi,
    float* __restrict__ pval, int* __restrict__ pidx) {
  constexpr int KC = 16;
  constexpr int XS = 132;
  constexpr int BUF = KC * XS * 2;     // floats per buffer (xs + wsd)
  __shared__ float smem[2 * BUF];      // 33,792 B (double-buffered)
  const int t = threadIdx.x;
  const int q0 = blockIdx.y * 128;     // transposed grid: y = q-tile
  const int ptile = blockIdx.x;        //                  x = point tile
  const size_t pt0 = (size_t)ptile * 128;
  const int g = t & 15;
  const int h = t >> 4;
  v2f acc2[2][2][4][2];
#pragma unroll
  for (int ep = 0; ep < 2; ++ep)
#pragma unroll
    for (int fp = 0; fp < 2; ++fp)
#pragma unroll
      for (int pi = 0; pi < 4; ++pi)
#pragma unroll
        for (int u = 0; u < 2; ++u) acc2[ep][fp][pi][u] = (v2f){0.f, 0.f};

  const int lk = t & 15;               // k-row within chunk
  const int lp = t >> 4;               // column group 0..15
  const int px = ((lk >> 3) & 1) << 1;  // store swizzle: 0 or 2
  const float* catp = cat + pt0 * 320 + lk;
  const float* wp = w + (size_t)q0 * 320 + lk;
  float rx[8], rw[8];
#pragma unroll
  for (int i = 0; i < 8; ++i) rx[i] = catp[(size_t)(lp + 16 * i) * 320];
#pragma unroll
  for (int i = 0; i < 8; ++i) rw[i] = wp[(size_t)(lp + 16 * i) * 320];
  // prologue: stage chunk 0 into buffer 0
  {
    float* xs0 = smem;
    float* ws0 = smem + KC * XS;
#pragma unroll
    for (int i = 0; i < 8; ++i) xs0[lk * XS + ((lp + 16 * i) ^ px)] = rx[i];
#pragma unroll
    for (int i = 0; i < 8; ++i) ws0[lk * XS + ((lp + 16 * i) ^ px)] = rw[i];
  }

#pragma unroll 2
  for (int ch = 0; ch < 20; ++ch) {
    const int par = ch & 1;
    const float* xsr = smem + par * BUF;
    const float* wsr = xsr + KC * XS;
    if (ch + 1 < 20) {  // issue next-chunk global loads (land during MAC)
      const int ko = (ch + 1) * KC;
#pragma unroll
      for (int i = 0; i < 8; ++i) rx[i] = catp[(size_t)(lp + 16 * i) * 320 + ko];
#pragma unroll
      for (int i = 0; i < 8; ++i) rw[i] = wp[(size_t)(lp + 16 * i) * 320 + ko];
    }
    __syncthreads();  // buf[par] writes (prev iter / prologue) visible
#pragma unroll
    for (int k = 0; k < KC; ++k) {
      const int pm2 = ((k >> 3) & 1) << 1;  // 0 or 2, compile-time under unroll
      const float* wrow = &wsr[k * XS];
      const float* xrow = &xsr[k * XS];
      // logical pairs at pm-unswizzled physical offsets (aligned v2f loads)
      v2f wA[2], wB[2];  // wA -> acc u=0 (logical cols 4h,4h+1), wB -> u=1
#pragma unroll
      for (int fp = 0; fp < 2; ++fp) {
        wA[fp] = *(const v2f*)&wrow[64 * fp + 4 * h + pm2];
        wB[fp] = *(const v2f*)&wrow[64 * fp + 4 * h + (2 - pm2)];
      }
#pragma unroll
      for (int ep = 0; ep < 2; ++ep) {
        const v2f xq0 = *(const v2f*)&xrow[64 * ep + 4 * g + pm2];        // pts 0,1
        const v2f xq1 = *(const v2f*)&xrow[64 * ep + 4 * g + (2 - pm2)];  // pts 2,3
#pragma unroll
        for (int fp = 0; fp < 2; ++fp) {
          pkmac_lo(acc2[ep][fp][0][0], wA[fp], xq0);
          pkmac_lo(acc2[ep][fp][0][1], wB[fp], xq0);
          pkmac_hi(acc2[ep][fp][1][0], wA[fp], xq0);
          pkmac_hi(acc2[ep][fp][1][1], wB[fp], xq0);
          pkmac_lo(acc2[ep][fp][2][0], wA[fp], xq1);
          pkmac_lo(acc2[ep][fp][2][1], wB[fp], xq1);
          pkmac_hi(acc2[ep][fp][3][0], wA[fp], xq1);
          pkmac_hi(acc2[ep][fp][3][1], wB[fp], xq1);
        }
      }
    }
    if (ch + 1 < 20) {  // stage next chunk into the other buffer (no barrier:
      float* xsw = smem + (par ^ 1) * BUF;  // readers of buf[par^1] finished
      float* wsw = xsw + KC * XS;           // before barrier at top of ch)
#pragma unroll
      for (int i = 0; i < 8; ++i) xsw[lk * XS + ((lp + 16 * i) ^ px)] = rx[i];
#pragma unroll
      for (int i = 0; i < 8; ++i) wsw[lk * XS + ((lp + 16 * i) ^ px)] = rw[i];
    }
  }
  // epilogue: relu(s*acc+b), per-thread argmax over 8 points ascending
  const int bb = ptile >> 5;
  const int blk = ptile & 31;
  float mv[8];
  int mi[8];
#pragma unroll
  for (int fp = 0; fp < 2; ++fp)
#pragma unroll
    for (int c = 0; c < 4; ++c) {
      const int f = fp * 4 + c;
      const int cl = 64 * fp + 4 * h + c;
      const float sc = s[q0 + cl];
      const float bc = bi[q0 + cl];
      mv[f] = -1.f;
      mi[f] = 0;
#pragma unroll
      for (int ep = 0; ep < 2; ++ep)
#pragma unroll
        for (int pi = 0; pi < 4; ++pi) {
          const v2f a2 = acc2[ep][fp][pi][c >> 1];
          const float a = (c & 1) ? a2.y : a2.x;
          const float v = fmaxf(addrn(mulrn(sc, a), bc), 0.f);
          if (v > mv[f]) { mv[f] = v; mi[f] = 64 * ep + 4 * g + pi; }
        }
    }
  __syncthreads();
  float* smv = smem;                       // 2112 floats
  int* smi = (int*)(smem + 16 * 132);      // next 2112 ints
#pragma unroll
  for (int fp = 0; fp < 2; ++fp)
#pragma unroll
    for (int c = 0; c < 4; ++c) {
      const int cl = 64 * fp + 4 * h + c;
      smv[g * 132 + cl] = mv[fp * 4 + c];
      smi[g * 132 + cl] = mi[fp * 4 + c];
    }
  __syncthreads();
  if (t < 128) {
    float best = smv[t];
    int bidx = smi[t];
    for (int gg = 1; gg < 16; ++gg) {
      const float v = smv[gg * 132 + t];
      const int vi = smi[gg * 132 + t];
      // candidates g-interleaved: ties resolve to SMALLEST point idx
      if (v > best || (v == best && vi < bidx)) { best = v; bidx = vi; }
    }
    const int n_l = blk * 128 + bidx;
    const size_t po = ((size_t)bb * 1024 + q0 + t) * 32 + blk;
    pval[po] = best;
    pidx[po] = n_l;
  }
}

__global__ __launch_bounds__(256) void final_reduce(
    const float* __restrict__ pval, const int* __restrict__ pidx,
    float* __restrict__ glob, float* __restrict__ oidx) {
  const int o = blockIdx.x * 256 + threadIdx.x;  // 8192 = B*1024
  const float* pv = pval + (size_t)o * 32;
  const int* pi = pidx + (size_t)o * 32;
  float best = pv[0];
  int bi = pi[0];
  for (int k = 1; k < 32; ++k) {
    const float v = pv[k];
    // tiles are ascending disjoint point ranges: strict > = first occurrence
    if (v > best) { best = v; bi = pi[k]; }
  }
  glob[o] = best;
  oidx[o] = (float)bi;
}

template <int KIN, int OUTS>
__global__ __launch_bounds__(256) void dense_wave(
    const float* __restrict__ in, const float* __restrict__ w,
    const float* __restrict__ s, const float* __restrict__ bi,
    float* __restrict__ out) {
  const int wid = (blockIdx.x * 256 + threadIdx.x) >> 6;
  const int lane = threadIdx.x & 63;
  const int b = wid / OUTS;
  const int o = wid % OUTS;
  const float* ip = in + (size_t)b * KIN;
  const float* wr = w + (size_t)o * KIN;
  float acc = 0.f;
  for (int k = lane; k < KIN; k += 64) acc = fmaf(wr[k], ip[k], acc);
#pragma unroll
  for (int off = 32; off; off >>= 1) acc += __shfl_down(acc, off);
  if (lane == 0) out[(size_t)b * OUTS + o] = fmaxf(fmaf(s[o], acc, bi[o]), 0.f);
}

extern "C" void kernel_launch(void* const* d_in, const int* in_sizes, int n_in,
                              void* d_out, int out_size, void* d_ws, size_t ws_size,
                              hipStream_t stream) {
  (void)in_sizes; (void)n_in; (void)out_size; (void)ws_size;
  const float* pts = (const float*)d_in[0];
  const float* ec_w[4] = {(const float*)d_in[1], (const float*)d_in[4],
                          (const float*)d_in[7], (const float*)d_in[10]};
  const float* ec_s[4] = {(const float*)d_in[2], (const float*)d_in[5],
                          (const float*)d_in[8], (const float*)d_in[11]};
  const float* ec_b[4] = {(const float*)d_in[3], (const float*)d_in[6],
                          (const float*)d_in[9], (const float*)d_in[12]};
  const float* local_w = (const float*)d_in[13];
  const float* local_s = (const float*)d_in[14];
  const float* local_b = (const float*)d_in[15];
  const float* g_w0 = (const float*)d_in[16];
  const float* g_s0 = (const float*)d_in[17];
  const float* g_b0 = (const float*)d_in[18];
  const float* g_w1 = (const float*)d_in[19];
  const float* g_s1 = (const float*)d_in[20];
  const float* g_b1 = (const float*)d_in[21];

  char* ws = (char*)d_ws;
  int* idxbuf = (int*)(ws + OFF_IDX);
  float* cat = (float*)(ws + OFF_CAT);
  float* pv = (float*)(ws + OFF_PV);
  int* pi = (int*)(ws + OFF_PI);
  float* glob = (float*)(ws + OFF_GLOB);
  float* hbuf = (float*)(ws + OFF_H);
  float* listd = (float*)(ws + OFF_LD);
  int* listj = (int*)(ws + OFF_LJ);
  int* counts = (int*)(ws + OFF_CNT);
  float* outv = (float*)d_out;   // [8][256]  fp32
  float* oidx = outv + 2048;     // [8][1024] fp32 (indices as floats)

  knn_scan<<<dim3(32, 4, 8), 256, 0, stream>>>(pts, listd, listj, counts);
  knn_merge<<<dim3(512), 256, 0, stream>>>(listd, listj, counts, idxbuf);

  // layer 1 (3 -> 64)
  ec_layer1<<<dim3(1024, 8), 256, 0, stream>>>(pts, idxbuf, ec_w[0], ec_s[0], ec_b[0], cat);
  // layer 2 (64 -> 64)
  ec_edge<1><<<dim3(512, 8), 256, 0, stream>>>(cat, 0, idxbuf, ec_w[1], ec_s[1], ec_b[1], cat, 64);
  // layer 3 (64 -> 64)
  ec_edge<1><<<dim3(512, 8), 256, 0, stream>>>(cat, 64, idxbuf, ec_w[2], ec_s[2], ec_b[2], cat, 128);
  // layer 4 (64 -> 128), fused both output halves, e staged once
  ec_edge<2><<<dim3(512, 8), 256, 0, stream>>>(cat, 128, idxbuf, ec_w[3], ec_s[3], ec_b[3], cat, 192);

  // transposed grid: ptile fastest -> same-ptile q-tiles co-located per XCD
  local_gemm<<<dim3(256, 8), 256, 0, stream>>>(cat, local_w, local_s, local_b, pv, pi);
  final_reduce<<<dim3(32), 256, 0, stream>>>(pv, pi, glob, oidx);
  dense_wave<1024, 512><<<dim3(1024), 256, 0, stream>>>(glob, g_w0, g_s0, g_b0, hbuf);
  dense_wave<512, 256><<<dim3(512), 256, 0, stream>>>(hbuf, g_w1, g_s1, g_b1, outv);
}